// Round 7
// baseline (372.911 us; speedup 1.0000x reference)
//
#include <hip/hip_runtime.h>

typedef unsigned short u16;
typedef unsigned int u32;
typedef _Float16 f16;
typedef __attribute__((ext_vector_type(2))) _Float16 f16x2;
typedef __attribute__((ext_vector_type(4))) _Float16 f16x4;
typedef __attribute__((ext_vector_type(4))) float f32x4;

// Problem constants: B=8, N=256, F=64, C=16, K=2
#define EPSV 1e-4f

// Output element offsets: h_out [0,131072) coord_out [131072,229376) category [229376,1277952)
// Category out-region is scratch: HA[2048*192] | HBJ[2048*192] | h16[2048*64] (f16)
// until the epilogue copies category in.  1.75 MB < 2 MB (bf16 case). OK.

// ---------------- ws layout (fp32 slots) -----------------------------------
static constexpr int WS_FLAG = 0;                     // +16
static constexpr int WS_ATT  = 16;                    // [2048][16]
static constexpr int WS_CT   = 32784;                 // [8][48][256] coord^T fp32
static constexpr int WS_AGG  = 131088;                // [2048][64]
static constexpr int WS_CAC  = 262160;                // [2048][48]
static constexpr int WS_WN1T = 360464;                // [128 k][64 f] fp32
static constexpr int WS_WN2T = 368656;                // [64 o][64 f] fp32
static constexpr int WS_BN1  = 372752;                // [64]
static constexpr int WS_BN2  = 372816;                // [64]
static constexpr int WS_BIAS = 372880;                // be2[64]|bc2[32]|bf1[16]|bf2[16]
static constexpr int WS_GWD  = 373008;                // f16 [192 o'][16 c]   (1536 slots)
static constexpr int WS_GWE2 = 374544;                // f16 [64 f][64 o]     (2048)
static constexpr int WS_GWC2 = 376592;                // f16 [32 mc][64 o]    (1024)
static constexpr int WS_GWF1 = 377616;                // f16 [16][16]         (128)
static constexpr int WS_GWF2 = 377744;                // f16 [16][16]         (128)
static constexpr int WS_GW1  = 377872;                // f16 [400 out][68 k]  (13600 slots)
static constexpr int WS_B400 = 391472;                // [400] layer-1 bias (0 for B-part)
// total 391872 f32 = 1.57 MB

static __device__ __forceinline__ float bfld(u16 v) {
  return __uint_as_float(((unsigned)v) << 16);
}
static __device__ __forceinline__ u16 f2b(float x) {  // RNE
  unsigned u = __float_as_uint(x);
  u += 0x7FFFu + ((u >> 16) & 1u);
  return (u16)(u >> 16);
}
static __device__ __forceinline__ float ldv(const void* p, int i, int flag) {
  return flag ? bfld(((const u16*)p)[i]) : ((const float*)p)[i];
}
static __device__ __forceinline__ void stv(void* p, int i, float v, int flag) {
  if (flag) ((u16*)p)[i] = f2b(v);
  else      ((float*)p)[i] = v;
}
static __device__ __forceinline__ f16* scratchHA(void* outv, int flag) {
  return (f16*)((char*)outv + (size_t)229376 * (flag ? 2 : 4));
}
static __device__ __forceinline__ int sniff_flag(const void* h) {
  const u16* hu = (const u16*)h;
  int cnt = 0;
  for (int i = 0; i < 128; ++i) {
    unsigned e = (hu[i] >> 7) & 0xFFu;
    if ((e >= 100u && e <= 150u) || hu[i] == 0) ++cnt;
  }
  return (cnt >= 112) ? 1 : 0;
}
static __device__ __forceinline__ f16x4 pack4(float a, float b, float c, float d) {
  const f16x2 lo = __builtin_bit_cast(f16x2, __builtin_amdgcn_cvt_pkrtz(a, b));
  const f16x2 hi = __builtin_bit_cast(f16x2, __builtin_amdgcn_cvt_pkrtz(c, d));
  f16x4 r; r[0] = lo[0]; r[1] = lo[1]; r[2] = hi[0]; r[3] = hi[1]; return r;
}

// ---------------- K0: all table builds, fully parallel (64 x 256) -----------
__global__ __launch_bounds__(256) void k_prep_w(
    const void* __restrict__ h, const void* __restrict__ coord,
    const void* __restrict__ We1, const void* __restrict__ Wc1,
    const void* __restrict__ We2, const void* __restrict__ Wc2,
    const void* __restrict__ Wf1, const void* __restrict__ Wf2,
    const void* __restrict__ Wn1, const void* __restrict__ Wn2,
    const void* __restrict__ Wqm,
    const void* __restrict__ be1, const void* __restrict__ bc1,
    const void* __restrict__ bqm, const void* __restrict__ be2,
    const void* __restrict__ bc2, const void* __restrict__ bf1,
    const void* __restrict__ bf2, const void* __restrict__ bn1,
    const void* __restrict__ bn2,
    float* __restrict__ ws, void* __restrict__ outv) {
  const int t = blockIdx.x * 256 + threadIdx.x;
  const int STR = 16384;
  __shared__ int sflag;
  if (threadIdx.x == 0) {
    sflag = sniff_flag(h);
    if (blockIdx.x == 0) ((int*)ws)[WS_FLAG] = sflag;
  }
  __syncthreads();
  const int flag = sflag;

  // GW1: stacked layer-1 weights as [400 out][68 k] f16
  f16* gw1 = (f16*)(ws + WS_GW1);
  for (int idx = t; idx < 25600; idx += STR) {
    const int row = idx >> 6, k = idx & 63;
    float v;
    if (row < 64)       v = ldv(We1, row * 144 + k, flag);
    else if (row < 192) v = ldv(Wc1, (row - 64) * 144 + k, flag);
    else if (row < 384) {
      const int ro = row - 192;
      v = (ro < 64) ? ldv(We1, ro * 144 + 64 + k, flag)
                    : ldv(Wc1, (ro - 64) * 144 + 64 + k, flag);
    } else              v = ldv(Wqm, (row - 384) * 64 + k, flag);
    gw1[row * 68 + k] = (f16)v;
  }
  if (t < 400) {
    float v = (t < 64) ? ldv(be1, t, flag)
            : (t < 192) ? ldv(bc1, t - 64, flag)
            : (t < 384) ? 0.f : ldv(bqm, t - 384, flag);
    ws[WS_B400 + t] = v;
  }
  f16* h16 = scratchHA(outv, flag) + 2048 * 384;
  for (int idx = t; idx < 131072; idx += STR) h16[idx] = (f16)ldv(h, idx, flag);
  for (int idx = t; idx < 98304; idx += STR) {  // coord^T [b][cd][n]
    const int bq = idx / 12288, rem = idx - bq * 12288;
    const int cd = rem >> 8, n = rem & 255;
    ws[WS_CT + idx] = ldv(coord, (bq * 256 + n) * 48 + cd, flag);
  }
  f16* gwd  = (f16*)(ws + WS_GWD);
  f16* gwe2 = (f16*)(ws + WS_GWE2);
  f16* gwc2 = (f16*)(ws + WS_GWC2);
  f16* gwf1 = (f16*)(ws + WS_GWF1);
  f16* gwf2 = (f16*)(ws + WS_GWF2);
  for (int idx = t; idx < 3072; idx += STR) {  // [o'][c] <- cols 128..143
    const int o = idx >> 4, c = idx & 15;
    const void* src = (o < 64) ? We1 : Wc1;
    const int row = (o < 64) ? o : (o - 64);
    gwd[idx] = (f16)ldv(src, row * 144 + 128 + c, flag);
  }
  for (int idx = t; idx < 4096; idx += STR) gwe2[idx] = (f16)ldv(We2, idx, flag);
  for (int idx = t; idx < 2048; idx += STR) gwc2[idx] = (f16)ldv(Wc2, idx, flag);
  if (t < 256) { gwf1[t] = (f16)ldv(Wf1, t, flag); gwf2[t] = (f16)ldv(Wf2, t, flag); }
  for (int idx = t; idx < 8192; idx += STR) {  // Wn1T[k][f]
    const int k = idx >> 6, f = idx & 63;
    ws[WS_WN1T + idx] = ldv(Wn1, f * 128 + k, flag);
  }
  for (int idx = t; idx < 4096; idx += STR) {  // Wn2T[o][f]
    const int o = idx >> 6, f = idx & 63;
    ws[WS_WN2T + idx] = ldv(Wn2, f * 64 + o, flag);
  }
  if (t < 64)  ws[WS_BN1 + t] = ldv(bn1, t, flag);
  if (t >= 64 && t < 128) ws[WS_BN2 + t - 64] = ldv(bn2, t - 64, flag);
  if (t >= 128 && t < 192) ws[WS_BIAS + t - 128] = ldv(be2, t - 128, flag);
  if (t >= 192 && t < 224) ws[WS_BIAS + 64 + t - 192] = ldv(bc2, t - 192, flag);
  if (t >= 224 && t < 240) ws[WS_BIAS + 96 + t - 224] = ldv(bf1, t - 224, flag);
  if (t >= 240 && t < 256) ws[WS_BIAS + 112 + t - 240] = ldv(bf2, t - 240, flag);
}

// ---------------- K0b: layer-1 MFMA GEMM -> HA/HBJ/ATT (160 x 256) ----------
__global__ __launch_bounds__(256) void k_gemm(float* __restrict__ ws,
                                              void* __restrict__ outv) {
  const int flag = ((const int*)ws)[WS_FLAG];
  const int nt = blockIdx.x / 5, grp = blockIdx.x % 5;
  const int tid = threadIdx.x, w = tid >> 6, lane = tid & 63;
  const int q = lane >> 4, l15 = lane & 15;
  f16* HA16 = scratchHA(outv, flag);
  f16* HBJ  = HA16 + 2048 * 192;
  const f16* h16 = HA16 + 2048 * 384;
  __shared__ __align__(16) f16 sW[80 * 68];
  __shared__ float sBias[80];
  const u32* gw1 = (const u32*)(ws + WS_GW1);
  for (int idx = tid; idx < 2720; idx += 256) {
    const int r = idx / 34, c = idx - r * 34;
    *(u32*)&sW[r * 68 + c * 2] = gw1[(grp * 80 + r) * 34 + c];
  }
  if (tid < 80) sBias[tid] = ws[WS_B400 + grp * 80 + tid];
  __syncthreads();
  const int nodeA = nt * 64 + w * 16 + l15;
  f16x4 Af[4];
#pragma unroll
  for (int ks = 0; ks < 4; ++ks)
    Af[ks] = *(const f16x4*)(h16 + nodeA * 64 + ks * 16 + q * 4);
#pragma unroll
  for (int ot = 0; ot < 5; ++ot) {
    const float bv = sBias[ot * 16 + l15];
    f32x4 acc = (f32x4){bv, bv, bv, bv};
#pragma unroll
    for (int ks = 0; ks < 4; ++ks) {
      const f16x4 Bf = *(const f16x4*)&sW[(ot * 16 + l15) * 68 + ks * 16 + q * 4];
      acc = __builtin_amdgcn_mfma_f32_16x16x16f16(Af[ks], Bf, acc, 0, 0, 0);
    }
    const int out = grp * 80 + ot * 16 + l15;
    const int nodeD = nt * 64 + w * 16 + q * 4;
#pragma unroll
    for (int r = 0; r < 4; ++r) {
      const int node = nodeD + r;
      if (out < 192)      HA16[node * 192 + out] = (f16)acc[r];
      else if (out < 384) HBJ[node * 192 + out - 192] = (f16)acc[r];
      else                ws[WS_ATT + node * 16 + out - 384] = fmaxf(acc[r], 0.f);
    }
  }
}

// ---------------- K1: MFMA edge kernel (2048 blocks x 256) ------------------
// j-tiles processed in 2 serialized halves (2 j-subtiles each) so live
// accumulators stay under the 128-reg cap of (256,4) -> no scratch spill.
__global__ __launch_bounds__(256, 4) void k_edge(const void* __restrict__ cat,
                                                 float* __restrict__ ws,
                                                 void* __restrict__ outv) {
  const int node = blockIdx.x, b = node >> 8, i = node & 255;
  const int tid = threadIdx.x;
  const int w = tid >> 6, lane = tid & 63, q = lane >> 4, l15 = lane & 15;
  const int flag = ((const int*)ws)[WS_FLAG];
  const f16* HA16 = scratchHA(outv, flag);
  const f16* HBJ  = HA16 + 2048 * 192;
  const float* __restrict__ cTb = ws + WS_CT + b * 48 * 256;

  __shared__ __align__(16) f16 sWd[192 * 20];
  __shared__ __align__(16) f16 sWe2[64 * 76];
  __shared__ __align__(16) f16 sWc2[32 * 76];
  __shared__ __align__(16) f16 sWf1[16 * 20];
  __shared__ __align__(16) f16 sWf2[16 * 20];
  __shared__ __align__(16) f16 distS[256 * 20];
  __shared__ float sHa[192];
  __shared__ float sB[128];
  __shared__ __align__(16) float red[256];

  {  // stage weight tables
    const u32* gwd = (const u32*)(ws + WS_GWD);
    for (int idx = tid; idx < 1536; idx += 256) {
      const int r = idx >> 3, c = idx & 7;
      *(u32*)&sWd[r * 20 + c * 2] = gwd[idx];
    }
    const u32* gwe = (const u32*)(ws + WS_GWE2);
    for (int idx = tid; idx < 2048; idx += 256) {
      const int r = idx >> 5, c = idx & 31;
      *(u32*)&sWe2[r * 76 + c * 2] = gwe[idx];
    }
    const u32* gwc = (const u32*)(ws + WS_GWC2);
    for (int idx = tid; idx < 1024; idx += 256) {
      const int r = idx >> 5, c = idx & 31;
      *(u32*)&sWc2[r * 76 + c * 2] = gwc[idx];
    }
    if (tid < 128) {
      const int r = tid >> 3, c = tid & 7;
      *(u32*)&sWf1[r * 20 + c * 2] = ((const u32*)(ws + WS_GWF1))[tid];
      *(u32*)&sWf2[r * 20 + c * 2] = ((const u32*)(ws + WS_GWF2))[tid];
    }
    if (tid < 192) sHa[tid] = (float)HA16[node * 192 + tid];
    if (tid < 128) sB[tid] = ws[WS_BIAS + tid];
  }
  {  // distances
    float dr[16];
#pragma unroll
    for (int c = 0; c < 16; ++c) {
      float s = 0.f;
#pragma unroll
      for (int d = 0; d < 3; ++d) {
        const int cd = c * 3 + d;
        const float df = cTb[cd * 256 + i] - cTb[cd * 256 + tid];
        s += df * df;
      }
      dr[c] = sqrtf(s);
    }
#pragma unroll
    for (int kk = 0; kk < 4; ++kk)
      *(f16x4*)&distS[tid * 20 + kk * 4] =
          pack4(dr[4 * kk], dr[4 * kk + 1], dr[4 * kk + 2], dr[4 * kk + 3]);
  }
  __syncthreads();

  float civ[12];
#pragma unroll
  for (int r = 0; r < 4; ++r)
#pragma unroll
    for (int d = 0; d < 3; ++d) civ[r * 3 + d] = cTb[(3 * (q * 4 + r) + d) * 256 + i];

  float sacc[4][4];  // agg accumulator [ft][r], lives across halves
#pragma unroll
  for (int ft = 0; ft < 4; ++ft)
#pragma unroll
    for (int r = 0; r < 4; ++r) sacc[ft][r] = 0.f;
  float ca[12] = {};  // coord accumulator

#pragma unroll 1
  for (int half = 0; half < 2; ++half) {
    int jj[2]; float mjt[2]; f16x4 dfr[2];
#pragma unroll
    for (int jl = 0; jl < 2; ++jl) {
      const int jt = half * 2 + jl;
      jj[jl] = w * 64 + jt * 16 + l15;
      mjt[jl] = (jj[jl] == i) ? 0.f : 1.f;
      dfr[jl] = *(const f16x4*)&distS[jj[jl] * 20 + q * 4];
    }

    // ---- phase 1: e2 GEMM chain, C2[f][j-sub] over K=64 ----
    f32x4 C2[4][2];
#pragma unroll
    for (int ft = 0; ft < 4; ++ft)
#pragma unroll
      for (int jl = 0; jl < 2; ++jl) C2[ft][jl] = (f32x4){0.f, 0.f, 0.f, 0.f};
#pragma unroll
    for (int og = 0; og < 4; ++og) {
      const f16x4 wd = *(const f16x4*)&sWd[(og * 16 + l15) * 20 + q * 4];
      f16x4 af[2];
#pragma unroll
      for (int jl = 0; jl < 2; ++jl) {
        const f16x4 hb = *(const f16x4*)(HBJ + (b * 256 + jj[jl]) * 192 + og * 16 + q * 4);
        f32x4 a;
#pragma unroll
        for (int r = 0; r < 4; ++r) a[r] = sHa[og * 16 + q * 4 + r] + (float)hb[r];
        a = __builtin_amdgcn_mfma_f32_16x16x16f16(wd, dfr[jl], a, 0, 0, 0);
        af[jl] = pack4(fmaxf(a[0], 0.f), fmaxf(a[1], 0.f), fmaxf(a[2], 0.f), fmaxf(a[3], 0.f));
      }
#pragma unroll
      for (int ft = 0; ft < 4; ++ft) {
        const f16x4 we = *(const f16x4*)&sWe2[(ft * 16 + l15) * 76 + og * 16 + q * 4];
#pragma unroll
        for (int jl = 0; jl < 2; ++jl)
          C2[ft][jl] = __builtin_amdgcn_mfma_f32_16x16x16f16(we, af[jl], C2[ft][jl], 0, 0, 0);
      }
    }
#pragma unroll
    for (int ft = 0; ft < 4; ++ft)
#pragma unroll
      for (int jl = 0; jl < 2; ++jl)
#pragma unroll
        for (int r = 0; r < 4; ++r)
          sacc[ft][r] += fmaxf(C2[ft][jl][r] + sB[ft * 16 + q * 4 + r], 0.f) * mjt[jl];

    // ---- phase 2: category chains -> factors ----
    float fac[2][4] = {};
#pragma unroll
    for (int m = 0; m < 2; ++m) {
      float cv[2];
#pragma unroll
      for (int jl = 0; jl < 2; ++jl) {
        if (flag) {
          const u32 p = ((const u32*)cat)[node * 256 + jj[jl]];
          cv[jl] = bfld((u16)(m ? (p >> 16) : (p & 0xFFFFu)));
        } else {
          cv[jl] = ((const float*)cat)[(node * 256 + jj[jl]) * 2 + m];
        }
      }
      f32x4 C3[2];
#pragma unroll
      for (int jl = 0; jl < 2; ++jl) C3[jl] = (f32x4){0.f, 0.f, 0.f, 0.f};
#pragma unroll
      for (int og2 = 0; og2 < 4; ++og2) {
        const int og = 4 + m * 4 + og2;
        const f16x4 wd = *(const f16x4*)&sWd[(og * 16 + l15) * 20 + q * 4];
        const f16x4 wc = *(const f16x4*)&sWc2[(m * 16 + l15) * 76 + og2 * 16 + q * 4];
#pragma unroll
        for (int jl = 0; jl < 2; ++jl) {
          const f16x4 hb = *(const f16x4*)(HBJ + (b * 256 + jj[jl]) * 192 + og * 16 + q * 4);
          f32x4 a;
#pragma unroll
          for (int r = 0; r < 4; ++r) a[r] = sHa[og * 16 + q * 4 + r] + (float)hb[r];
          a = __builtin_amdgcn_mfma_f32_16x16x16f16(wd, dfr[jl], a, 0, 0, 0);
          const f16x4 af = pack4(fmaxf(a[0], 0.f), fmaxf(a[1], 0.f),
                                 fmaxf(a[2], 0.f), fmaxf(a[3], 0.f));
          C3[jl] = __builtin_amdgcn_mfma_f32_16x16x16f16(wc, af, C3[jl], 0, 0, 0);
        }
      }
#pragma unroll
      for (int jl = 0; jl < 2; ++jl)
#pragma unroll
        for (int r = 0; r < 4; ++r)
          fac[jl][r] += cv[jl] * fmaxf(C3[jl][r] + sB[64 + m * 16 + q * 4 + r], 0.f);
    }

    // ---- factors MLP + coord aggregation for this half ----
    const f16x4 w1 = *(const f16x4*)&sWf1[l15 * 20 + q * 4];
    const f16x4 w2 = *(const f16x4*)&sWf2[l15 * 20 + q * 4];
#pragma unroll
    for (int jl = 0; jl < 2; ++jl) {
      const f16x4 fF = pack4(fac[jl][0], fac[jl][1], fac[jl][2], fac[jl][3]);
      const f32x4 z = {0.f, 0.f, 0.f, 0.f};
      f32x4 G = __builtin_amdgcn_mfma_f32_16x16x16f16(w1, fF, z, 0, 0, 0);
      const f16x4 gF = pack4(fmaxf(G[0] + sB[96 + q * 4 + 0], 0.f),
                             fmaxf(G[1] + sB[96 + q * 4 + 1], 0.f),
                             fmaxf(G[2] + sB[96 + q * 4 + 2], 0.f),
                             fmaxf(G[3] + sB[96 + q * 4 + 3], 0.f));
      f32x4 F2 = __builtin_amdgcn_mfma_f32_16x16x16f16(w2, gF, z, 0, 0, 0);
#pragma unroll
      for (int r = 0; r < 4; ++r) {
        const float fv = fmaxf(F2[r] + sB[112 + q * 4 + r], 0.f);
#pragma unroll
        for (int d = 0; d < 3; ++d) {
          const float cj = cTb[(3 * (q * 4 + r) + d) * 256 + jj[jl]];
          ca[r * 3 + d] += fv * (civ[r * 3 + d] - cj);  // j==i contributes 0
        }
      }
    }
  }

  // ---- block reductions (16-lane groups share identical out-rows) ----
#pragma unroll
  for (int st = 1; st < 16; st <<= 1)
#pragma unroll
    for (int ft = 0; ft < 4; ++ft)
#pragma unroll
      for (int r = 0; r < 4; ++r) sacc[ft][r] += __shfl_xor(sacc[ft][r], st, 64);
  if (l15 == 0) {
#pragma unroll
    for (int ft = 0; ft < 4; ++ft)
#pragma unroll
      for (int r = 0; r < 4; ++r) red[w * 64 + ft * 16 + q * 4 + r] = sacc[ft][r];
  }
  __syncthreads();
  if (tid < 64)
    ws[WS_AGG + node * 64 + tid] = red[tid] + red[64 + tid] + red[128 + tid] + red[192 + tid];
  __syncthreads();
#pragma unroll
  for (int st = 1; st < 16; st <<= 1)
#pragma unroll
    for (int u = 0; u < 12; ++u) ca[u] += __shfl_xor(ca[u], st, 64);
  if (l15 == 0) {
#pragma unroll
    for (int u = 0; u < 12; ++u) red[w * 64 + q * 12 + u] = ca[u];
  }
  __syncthreads();
  if (tid < 48)
    ws[WS_CAC + node * 48 + tid] = red[tid] + red[64 + tid] + red[128 + tid] + red[192 + tid];
}

// ---------------- K2: fused epilogue (1544 blocks x 256) --------------------
__global__ __launch_bounds__(256) void k_epilogue(const void* __restrict__ h,
                                                  const void* __restrict__ coord,
                                                  const void* __restrict__ vel,
                                                  const void* __restrict__ cat,
                                                  const void* __restrict__ Wcv,
                                                  const void* __restrict__ Wql,
                                                  const void* __restrict__ Wkl,
                                                  const float* __restrict__ ws,
                                                  void* __restrict__ outv) {
  const int blk = blockIdx.x, tid = threadIdx.x;
  const int flag = ((const int*)ws)[WS_FLAG];
  if (blk < 512) {  // node model: 4 nodes/block, LDS-staged weights
    const int sub = tid >> 6, f = tid & 63;
    const int node = blk * 4 + sub;
    __shared__ float sWn1[128 * 64];
    __shared__ float sWn2[64 * 64];
    __shared__ float sbn[128];
    __shared__ float x[4][128];
    __shared__ float hid[4][64];
    for (int idx = tid; idx < 8192; idx += 256) sWn1[idx] = ws[WS_WN1T + idx];
    for (int idx = tid; idx < 4096; idx += 256) sWn2[idx] = ws[WS_WN2T + idx];
    if (tid < 128) sbn[tid] = (tid < 64) ? ws[WS_BN1 + tid] : ws[WS_BN2 + tid - 64];
    const float hv = ldv(h, node * 64 + f, flag);
    x[sub][f] = hv;
    x[sub][64 + f] = ws[WS_AGG + node * 64 + f];
    __syncthreads();
    float s = sbn[f];
    for (int k = 0; k < 128; ++k) s += sWn1[k * 64 + f] * x[sub][k];
    hid[sub][f] = fmaxf(s, 0.f);
    __syncthreads();
    float s2 = sbn[64 + f];
    for (int o = 0; o < 64; ++o) s2 += sWn2[o * 64 + f] * hid[sub][o];
    stv(outv, node * 64 + f, hv + s2, flag);
  } else if (blk < 520) {  // coord pipeline, b = blk-512
    const int b = blk - 512;
    const int n = tid, node = b * 256 + n;
    const int wave = n >> 6, lane = n & 63;
    __shared__ float wcv[256], wql[256], wkl[256];
    __shared__ float redm[16];
    wcv[n] = ldv(Wcv, n, flag);
    wql[n] = ldv(Wql, n, flag);
    wkl[n] = ldv(Wkl, n, flag);
    float cf[48];
#pragma unroll
    for (int cd = 0; cd < 48; ++cd) cf[cd] = ldv(coord, node * 48 + cd, flag);
    float s0 = 0.f, s1 = 0.f, s2 = 0.f;
#pragma unroll
    for (int c = 0; c < 16; ++c) { s0 += cf[c*3]; s1 += cf[c*3+1]; s2 += cf[c*3+2]; }
    for (int s = 1; s < 64; s <<= 1) {
      s0 += __shfl_xor(s0, s, 64); s1 += __shfl_xor(s1, s, 64); s2 += __shfl_xor(s2, s, 64);
    }
    if (lane == 0) { redm[wave*4] = s0; redm[wave*4+1] = s1; redm[wave*4+2] = s2; }
    __syncthreads();
    const float m0 = (redm[0]+redm[4]+redm[8]+redm[12]) * (1.f/4096.f);
    const float m1 = (redm[1]+redm[5]+redm[9]+redm[13]) * (1.f/4096.f);
    const float m2 = (redm[2]+redm[6]+redm[10]+redm[14]) * (1.f/4096.f);
    __syncthreads();
    float velf[48];
#pragma unroll
    for (int cd = 0; cd < 48; ++cd) velf[cd] = ldv(vel, node * 48 + cd, flag);
    float c3[48];
#pragma unroll
    for (int c = 0; c < 16; ++c) {
      const float at = ws[WS_ATT + node * 16 + c];
#pragma unroll
      for (int d = 0; d < 3; ++d) {
        const int cd = c * 3 + d;
        const float md = (d == 0) ? m0 : ((d == 1) ? m1 : m2);
        float cc = at * (cf[cd] - md) + cf[cd];
        cc += ws[WS_CAC + node * 48 + cd];
        float a = cc;
#pragma unroll
        for (int cp = 0; cp < 16; ++cp) a += velf[cp * 3 + d] * wcv[c * 16 + cp];
        c3[cd] = a;
      }
    }
    float t0 = 0.f, t1 = 0.f, t2 = 0.f;
#pragma unroll
    for (int c = 0; c < 16; ++c) { t0 += c3[c*3]; t1 += c3[c*3+1]; t2 += c3[c*3+2]; }
    for (int s = 1; s < 64; s <<= 1) {
      t0 += __shfl_xor(t0, s, 64); t1 += __shfl_xor(t1, s, 64); t2 += __shfl_xor(t2, s, 64);
    }
    if (lane == 0) { redm[wave*4] = t0; redm[wave*4+1] = t1; redm[wave*4+2] = t2; }
    __syncthreads();
    const float cm0 = (redm[0]+redm[4]+redm[8]+redm[12]) * (1.f/4096.f);
    const float cm1 = (redm[1]+redm[5]+redm[9]+redm[13]) * (1.f/4096.f);
    const float cm2 = (redm[2]+redm[6]+redm[10]+redm[14]) * (1.f/4096.f);
    float cc[48];
#pragma unroll
    for (int c = 0; c < 16; ++c) {
      cc[c*3]   = c3[c*3]   - cm0;
      cc[c*3+1] = c3[c*3+1] - cm1;
      cc[c*3+2] = c3[c*3+2] - cm2;
    }
#pragma unroll
    for (int o = 0; o < 16; ++o) {
      float qv[3], kv[3];
#pragma unroll
      for (int d = 0; d < 3; ++d) {
        float sq = 0.f, sk = 0.f;
#pragma unroll
        for (int cp = 0; cp < 16; ++cp) {
          sq += cc[cp * 3 + d] * wql[o * 16 + cp];
          sk += cc[cp * 3 + d] * wkl[o * 16 + cp];
        }
        qv[d] = sq; kv[d] = sk;
      }
      const float prod = qv[0]*kv[0] + qv[1]*kv[1] + qv[2]*kv[2];
      const float kns  = kv[0]*kv[0] + kv[1]*kv[1] + kv[2]*kv[2];
      const float wq = prod / (kns + EPSV);
#pragma unroll
      for (int d = 0; d < 3; ++d) {
        const float cmd = (d == 0) ? cm0 : ((d == 1) ? cm1 : cm2);
        const float val = (prod >= 0.f) ? qv[d] : (qv[d] - wq * kv[d]);
        stv(outv, 131072 + node * 48 + o * 3 + d, val + cmd, flag);
      }
    }
  } else {  // category passthrough (overwrites scratch region)
    const int idx = (blk - 520) * 256 + tid;  // 262144 total
    if (flag) ((uint2*)((char*)outv + 458752))[idx] = ((const uint2*)cat)[idx];
    else      ((uint4*)((char*)outv + 917504))[idx] = ((const uint4*)cat)[idx];
  }
}

// ---------------- launch ----------------------------------------------------
extern "C" void kernel_launch(void* const* d_in, const int* in_sizes, int n_in,
                              void* d_out, int out_size, void* d_ws, size_t ws_size,
                              hipStream_t stream) {
  (void)in_sizes; (void)n_in; (void)out_size; (void)ws_size;
  const void* h    = d_in[0];
  const void* coord= d_in[1];
  const void* vel  = d_in[2];
  const void* cat  = d_in[3];
  const void* Wcv  = d_in[4];
  const void* We1  = d_in[5];
  const void* be1  = d_in[6];
  const void* We2  = d_in[7];
  const void* be2  = d_in[8];
  const void* Wc1  = d_in[9];
  const void* bc1  = d_in[10];
  const void* Wc2  = d_in[11];
  const void* bc2  = d_in[12];
  const void* Wf1  = d_in[13];
  const void* bf1v = d_in[14];
  const void* Wf2  = d_in[15];
  const void* bf2v = d_in[16];
  const void* Wn1  = d_in[17];
  const void* bn1  = d_in[18];
  const void* Wn2  = d_in[19];
  const void* bn2  = d_in[20];
  const void* Wql  = d_in[21];
  const void* Wkl  = d_in[22];
  const void* Wqm  = d_in[23];
  const void* bqm  = d_in[24];
  float* ws = (float*)d_ws;

  k_prep_w<<<64, 256, 0, stream>>>(h, coord, We1, Wc1, We2, Wc2, Wf1, Wf2,
                                   Wn1, Wn2, Wqm, be1, bc1, bqm, be2, bc2,
                                   bf1v, bf2v, bn1, bn2, ws, d_out);
  k_gemm<<<160, 256, 0, stream>>>(ws, d_out);
  k_edge<<<2048, 256, 0, stream>>>(cat, ws, d_out);
  k_epilogue<<<1544, 256, 0, stream>>>(h, coord, vel, cat, Wcv, Wql, Wkl, ws, d_out);
}

// Round 8
// 233.632 us; speedup vs baseline: 1.5961x; 1.5961x over previous
//
#include <hip/hip_runtime.h>

typedef unsigned short u16;
typedef unsigned int u32;
typedef _Float16 f16;
typedef __attribute__((ext_vector_type(2))) _Float16 f16x2;
typedef __attribute__((ext_vector_type(4))) _Float16 f16x4;
typedef __attribute__((ext_vector_type(4))) float f32x4;

// Problem constants: B=8, N=256, F=64, C=16, K=2
#define EPSV 1e-4f

// Output element offsets: h_out [0,131072) coord_out [131072,229376) category [229376,1277952)
// Category out-region is scratch: HA[2048*192] | HBJ[2048*192] | h16[2048*64] (f16)
// until the epilogue copies category in.  1.75 MB < 2 MB (bf16 case). OK.

// ---------------- ws layout (fp32 slots) -----------------------------------
static constexpr int WS_FLAG = 0;                     // +16
static constexpr int WS_ATT  = 16;                    // [2048][16]
static constexpr int WS_CT   = 32784;                 // [8][48][256] coord^T fp32
static constexpr int WS_AGG  = 131088;                // [2048][64]
static constexpr int WS_CAC  = 262160;                // [2048][48]
static constexpr int WS_WN1T = 360464;                // [128 k][64 f] fp32
static constexpr int WS_WN2T = 368656;                // [64 o][64 f] fp32
static constexpr int WS_BN1  = 372752;                // [64]
static constexpr int WS_BN2  = 372816;                // [64]
static constexpr int WS_BIAS = 372880;                // be2[64]|bc2[32]|bf1[16]|bf2[16]
static constexpr int WS_GWD  = 373008;                // f16 [192 o'][16 c]   (1536 slots)
static constexpr int WS_GWE2 = 374544;                // f16 [64 f][64 o]     (2048)
static constexpr int WS_GWC2 = 376592;                // f16 [32 mc][64 o]    (1024)
static constexpr int WS_GWF1 = 377616;                // f16 [16][16]         (128)
static constexpr int WS_GWF2 = 377744;                // f16 [16][16]         (128)
static constexpr int WS_GW1  = 377872;                // f16 [400 out][68 k]  (13600 slots)
static constexpr int WS_B400 = 391472;                // [400] layer-1 bias (0 for B-part)
// total 391872 f32 = 1.57 MB

static __device__ __forceinline__ float bfld(u16 v) {
  return __uint_as_float(((unsigned)v) << 16);
}
static __device__ __forceinline__ u16 f2b(float x) {  // RNE
  unsigned u = __float_as_uint(x);
  u += 0x7FFFu + ((u >> 16) & 1u);
  return (u16)(u >> 16);
}
static __device__ __forceinline__ float ldv(const void* p, int i, int flag) {
  return flag ? bfld(((const u16*)p)[i]) : ((const float*)p)[i];
}
static __device__ __forceinline__ void stv(void* p, int i, float v, int flag) {
  if (flag) ((u16*)p)[i] = f2b(v);
  else      ((float*)p)[i] = v;
}
static __device__ __forceinline__ f16* scratchHA(void* outv, int flag) {
  return (f16*)((char*)outv + (size_t)229376 * (flag ? 2 : 4));
}
static __device__ __forceinline__ int sniff_flag(const void* h) {
  const u16* hu = (const u16*)h;
  int cnt = 0;
  for (int i = 0; i < 128; ++i) {
    unsigned e = (hu[i] >> 7) & 0xFFu;
    if ((e >= 100u && e <= 150u) || hu[i] == 0) ++cnt;
  }
  return (cnt >= 112) ? 1 : 0;
}
static __device__ __forceinline__ f16x4 pack4(float a, float b, float c, float d) {
  const f16x2 lo = __builtin_bit_cast(f16x2, __builtin_amdgcn_cvt_pkrtz(a, b));
  const f16x2 hi = __builtin_bit_cast(f16x2, __builtin_amdgcn_cvt_pkrtz(c, d));
  f16x4 r; r[0] = lo[0]; r[1] = lo[1]; r[2] = hi[0]; r[3] = hi[1]; return r;
}

// ---------------- K0: all table builds, fully parallel (256 x 256) ----------
__global__ __launch_bounds__(256) void k_prep_w(
    const void* __restrict__ h, const void* __restrict__ coord,
    const void* __restrict__ We1, const void* __restrict__ Wc1,
    const void* __restrict__ We2, const void* __restrict__ Wc2,
    const void* __restrict__ Wf1, const void* __restrict__ Wf2,
    const void* __restrict__ Wn1, const void* __restrict__ Wn2,
    const void* __restrict__ Wqm,
    const void* __restrict__ be1, const void* __restrict__ bc1,
    const void* __restrict__ bqm, const void* __restrict__ be2,
    const void* __restrict__ bc2, const void* __restrict__ bf1,
    const void* __restrict__ bf2, const void* __restrict__ bn1,
    const void* __restrict__ bn2,
    float* __restrict__ ws, void* __restrict__ outv) {
  const int t = blockIdx.x * 256 + threadIdx.x;
  const int STR = 65536;
  __shared__ int sflag;
  if (threadIdx.x == 0) {
    sflag = sniff_flag(h);
    if (blockIdx.x == 0) ((int*)ws)[WS_FLAG] = sflag;
  }
  __syncthreads();
  const int flag = sflag;

  // GW1: stacked layer-1 weights as [400 out][68 k] f16
  f16* gw1 = (f16*)(ws + WS_GW1);
  for (int idx = t; idx < 25600; idx += STR) {
    const int row = idx >> 6, k = idx & 63;
    float v;
    if (row < 64)       v = ldv(We1, row * 144 + k, flag);
    else if (row < 192) v = ldv(Wc1, (row - 64) * 144 + k, flag);
    else if (row < 384) {
      const int ro = row - 192;
      v = (ro < 64) ? ldv(We1, ro * 144 + 64 + k, flag)
                    : ldv(Wc1, (ro - 64) * 144 + 64 + k, flag);
    } else              v = ldv(Wqm, (row - 384) * 64 + k, flag);
    gw1[row * 68 + k] = (f16)v;
  }
  if (t < 400) {
    float v = (t < 64) ? ldv(be1, t, flag)
            : (t < 192) ? ldv(bc1, t - 64, flag)
            : (t < 384) ? 0.f : ldv(bqm, t - 384, flag);
    ws[WS_B400 + t] = v;
  }
  f16* h16 = scratchHA(outv, flag) + 2048 * 384;
  for (int idx = t; idx < 131072; idx += STR) h16[idx] = (f16)ldv(h, idx, flag);
  for (int idx = t; idx < 98304; idx += STR) {  // coord^T [b][cd][n]
    const int bq = idx / 12288, rem = idx - bq * 12288;
    const int cd = rem >> 8, n = rem & 255;
    ws[WS_CT + idx] = ldv(coord, (bq * 256 + n) * 48 + cd, flag);
  }
  f16* gwd  = (f16*)(ws + WS_GWD);
  f16* gwe2 = (f16*)(ws + WS_GWE2);
  f16* gwc2 = (f16*)(ws + WS_GWC2);
  f16* gwf1 = (f16*)(ws + WS_GWF1);
  f16* gwf2 = (f16*)(ws + WS_GWF2);
  for (int idx = t; idx < 3072; idx += STR) {  // [o'][c] <- cols 128..143
    const int o = idx >> 4, c = idx & 15;
    const void* src = (o < 64) ? We1 : Wc1;
    const int row = (o < 64) ? o : (o - 64);
    gwd[idx] = (f16)ldv(src, row * 144 + 128 + c, flag);
  }
  for (int idx = t; idx < 4096; idx += STR) gwe2[idx] = (f16)ldv(We2, idx, flag);
  for (int idx = t; idx < 2048; idx += STR) gwc2[idx] = (f16)ldv(Wc2, idx, flag);
  if (t < 256) { gwf1[t] = (f16)ldv(Wf1, t, flag); gwf2[t] = (f16)ldv(Wf2, t, flag); }
  for (int idx = t; idx < 8192; idx += STR) {  // Wn1T[k][f]
    const int k = idx >> 6, f = idx & 63;
    ws[WS_WN1T + idx] = ldv(Wn1, f * 128 + k, flag);
  }
  for (int idx = t; idx < 4096; idx += STR) {  // Wn2T[o][f]
    const int o = idx >> 6, f = idx & 63;
    ws[WS_WN2T + idx] = ldv(Wn2, f * 64 + o, flag);
  }
  if (t < 64)  ws[WS_BN1 + t] = ldv(bn1, t, flag);
  if (t >= 64 && t < 128) ws[WS_BN2 + t - 64] = ldv(bn2, t - 64, flag);
  if (t >= 128 && t < 192) ws[WS_BIAS + t - 128] = ldv(be2, t - 128, flag);
  if (t >= 192 && t < 224) ws[WS_BIAS + 64 + t - 192] = ldv(bc2, t - 192, flag);
  if (t >= 224 && t < 240) ws[WS_BIAS + 96 + t - 224] = ldv(bf1, t - 224, flag);
  if (t >= 240 && t < 256) ws[WS_BIAS + 112 + t - 240] = ldv(bf2, t - 240, flag);
}

// ---------------- K0b: layer-1 MFMA GEMM -> HA/HBJ/ATT (160 x 256) ----------
__global__ __launch_bounds__(256) void k_gemm(float* __restrict__ ws,
                                              void* __restrict__ outv) {
  const int flag = ((const int*)ws)[WS_FLAG];
  const int nt = blockIdx.x / 5, grp = blockIdx.x % 5;
  const int tid = threadIdx.x, w = tid >> 6, lane = tid & 63;
  const int q = lane >> 4, l15 = lane & 15;
  f16* HA16 = scratchHA(outv, flag);
  f16* HBJ  = HA16 + 2048 * 192;
  const f16* h16 = HA16 + 2048 * 384;
  __shared__ __align__(16) f16 sW[80 * 68];
  __shared__ float sBias[80];
  const u32* gw1 = (const u32*)(ws + WS_GW1);
  for (int idx = tid; idx < 2720; idx += 256) {
    const int r = idx / 34, c = idx - r * 34;
    *(u32*)&sW[r * 68 + c * 2] = gw1[(grp * 80 + r) * 34 + c];
  }
  if (tid < 80) sBias[tid] = ws[WS_B400 + grp * 80 + tid];
  __syncthreads();
  const int nodeA = nt * 64 + w * 16 + l15;
  f16x4 Af[4];
#pragma unroll
  for (int ks = 0; ks < 4; ++ks)
    Af[ks] = *(const f16x4*)(h16 + nodeA * 64 + ks * 16 + q * 4);
#pragma unroll
  for (int ot = 0; ot < 5; ++ot) {
    const float bv = sBias[ot * 16 + l15];
    f32x4 acc = (f32x4){bv, bv, bv, bv};
#pragma unroll
    for (int ks = 0; ks < 4; ++ks) {
      const f16x4 Bf = *(const f16x4*)&sW[(ot * 16 + l15) * 68 + ks * 16 + q * 4];
      acc = __builtin_amdgcn_mfma_f32_16x16x16f16(Af[ks], Bf, acc, 0, 0, 0);
    }
    const int out = grp * 80 + ot * 16 + l15;
    const int nodeD = nt * 64 + w * 16 + q * 4;
#pragma unroll
    for (int r = 0; r < 4; ++r) {
      const int node = nodeD + r;
      if (out < 192)      HA16[node * 192 + out] = (f16)acc[r];
      else if (out < 384) HBJ[node * 192 + out - 192] = (f16)acc[r];
      else                ws[WS_ATT + node * 16 + out - 384] = fmaxf(acc[r], 0.f);
    }
  }
}

// ---------------- K1: MFMA edge kernel (2048 blocks x 256) ------------------
// Round-6 monolithic body; (256,3) raises the reg cap to ~170 so the ~150-reg
// live set (C2[4][4] + af/dfr + temps) fits with NO scratch spill. Achieved
// occupancy was already ~3 blocks/CU under (256,4), so nothing is lost.
__global__ __launch_bounds__(256, 3) void k_edge(const void* __restrict__ cat,
                                                 float* __restrict__ ws,
                                                 void* __restrict__ outv) {
  const int node = blockIdx.x, b = node >> 8, i = node & 255;
  const int tid = threadIdx.x;
  const int w = tid >> 6, lane = tid & 63, q = lane >> 4, l15 = lane & 15;
  const int flag = ((const int*)ws)[WS_FLAG];
  const f16* HA16 = scratchHA(outv, flag);
  const f16* HBJ  = HA16 + 2048 * 192;
  const float* __restrict__ cTb = ws + WS_CT + b * 48 * 256;

  __shared__ __align__(16) f16 sWd[192 * 20];
  __shared__ __align__(16) f16 sWe2[64 * 76];
  __shared__ __align__(16) f16 sWc2[32 * 76];
  __shared__ __align__(16) f16 sWf1[16 * 20];
  __shared__ __align__(16) f16 sWf2[16 * 20];
  __shared__ __align__(16) f16 distS[256 * 20];
  __shared__ float sHa[192];
  __shared__ float sB[128];
  __shared__ __align__(16) float red[256];

  {  // stage weight tables
    const u32* gwd = (const u32*)(ws + WS_GWD);
    for (int idx = tid; idx < 1536; idx += 256) {
      const int r = idx >> 3, c = idx & 7;
      *(u32*)&sWd[r * 20 + c * 2] = gwd[idx];
    }
    const u32* gwe = (const u32*)(ws + WS_GWE2);
    for (int idx = tid; idx < 2048; idx += 256) {
      const int r = idx >> 5, c = idx & 31;
      *(u32*)&sWe2[r * 76 + c * 2] = gwe[idx];
    }
    const u32* gwc = (const u32*)(ws + WS_GWC2);
    for (int idx = tid; idx < 1024; idx += 256) {
      const int r = idx >> 5, c = idx & 31;
      *(u32*)&sWc2[r * 76 + c * 2] = gwc[idx];
    }
    if (tid < 128) {
      const int r = tid >> 3, c = tid & 7;
      *(u32*)&sWf1[r * 20 + c * 2] = ((const u32*)(ws + WS_GWF1))[tid];
      *(u32*)&sWf2[r * 20 + c * 2] = ((const u32*)(ws + WS_GWF2))[tid];
    }
    if (tid < 192) sHa[tid] = (float)HA16[node * 192 + tid];
    if (tid < 128) sB[tid] = ws[WS_BIAS + tid];
  }
  {  // distances
    float dr[16];
#pragma unroll
    for (int c = 0; c < 16; ++c) {
      float s = 0.f;
#pragma unroll
      for (int d = 0; d < 3; ++d) {
        const int cd = c * 3 + d;
        const float df = cTb[cd * 256 + i] - cTb[cd * 256 + tid];
        s += df * df;
      }
      dr[c] = sqrtf(s);
    }
#pragma unroll
    for (int kk = 0; kk < 4; ++kk)
      *(f16x4*)&distS[tid * 20 + kk * 4] =
          pack4(dr[4 * kk], dr[4 * kk + 1], dr[4 * kk + 2], dr[4 * kk + 3]);
  }
  __syncthreads();

  int jj[4]; float mjt[4]; f16x4 dfr[4];
#pragma unroll
  for (int jt = 0; jt < 4; ++jt) {
    jj[jt] = w * 64 + jt * 16 + l15;
    mjt[jt] = (jj[jt] == i) ? 0.f : 1.f;
    dfr[jt] = *(const f16x4*)&distS[jj[jt] * 20 + q * 4];
  }

  // ---- phase 1: e2 GEMM chain, C2[f][j] over K=64 ----
  f32x4 C2[4][4];
#pragma unroll
  for (int ft = 0; ft < 4; ++ft)
#pragma unroll
    for (int jt = 0; jt < 4; ++jt) C2[ft][jt] = (f32x4){0.f, 0.f, 0.f, 0.f};
#pragma unroll
  for (int og = 0; og < 4; ++og) {
    const f16x4 wd = *(const f16x4*)&sWd[(og * 16 + l15) * 20 + q * 4];
    f16x4 af[4];
#pragma unroll
    for (int jt = 0; jt < 4; ++jt) {
      const f16x4 hb = *(const f16x4*)(HBJ + (b * 256 + jj[jt]) * 192 + og * 16 + q * 4);
      f32x4 a;
#pragma unroll
      for (int r = 0; r < 4; ++r) a[r] = sHa[og * 16 + q * 4 + r] + (float)hb[r];
      a = __builtin_amdgcn_mfma_f32_16x16x16f16(wd, dfr[jt], a, 0, 0, 0);
      af[jt] = pack4(fmaxf(a[0], 0.f), fmaxf(a[1], 0.f), fmaxf(a[2], 0.f), fmaxf(a[3], 0.f));
    }
#pragma unroll
    for (int ft = 0; ft < 4; ++ft) {
      const f16x4 we = *(const f16x4*)&sWe2[(ft * 16 + l15) * 76 + og * 16 + q * 4];
#pragma unroll
      for (int jt = 0; jt < 4; ++jt)
        C2[ft][jt] = __builtin_amdgcn_mfma_f32_16x16x16f16(we, af[jt], C2[ft][jt], 0, 0, 0);
    }
  }
#pragma unroll
  for (int ft = 0; ft < 4; ++ft) {
    float s[4] = {0.f, 0.f, 0.f, 0.f};
#pragma unroll
    for (int jt = 0; jt < 4; ++jt)
#pragma unroll
      for (int r = 0; r < 4; ++r)
        s[r] += fmaxf(C2[ft][jt][r] + sB[ft * 16 + q * 4 + r], 0.f) * mjt[jt];
#pragma unroll
    for (int st = 1; st < 16; st <<= 1)
#pragma unroll
      for (int r = 0; r < 4; ++r) s[r] += __shfl_xor(s[r], st, 64);
    if (l15 == 0) {
#pragma unroll
      for (int r = 0; r < 4; ++r) red[w * 64 + ft * 16 + q * 4 + r] = s[r];
    }
  }
  __syncthreads();
  if (tid < 64)
    ws[WS_AGG + node * 64 + tid] = red[tid] + red[64 + tid] + red[128 + tid] + red[192 + tid];
  __syncthreads();

  // ---- phase 2: category chains -> factors ----
  float fac[4][4] = {};
#pragma unroll
  for (int m = 0; m < 2; ++m) {
    float cv[4];
#pragma unroll
    for (int jt = 0; jt < 4; ++jt) {
      if (flag) {
        const u32 p = ((const u32*)cat)[node * 256 + jj[jt]];
        cv[jt] = bfld((u16)(m ? (p >> 16) : (p & 0xFFFFu)));
      } else {
        cv[jt] = ((const float*)cat)[(node * 256 + jj[jt]) * 2 + m];
      }
    }
    f32x4 C3[4];
#pragma unroll
    for (int jt = 0; jt < 4; ++jt) C3[jt] = (f32x4){0.f, 0.f, 0.f, 0.f};
#pragma unroll
    for (int og2 = 0; og2 < 4; ++og2) {
      const int og = 4 + m * 4 + og2;
      const f16x4 wd = *(const f16x4*)&sWd[(og * 16 + l15) * 20 + q * 4];
      const f16x4 wc = *(const f16x4*)&sWc2[(m * 16 + l15) * 76 + og2 * 16 + q * 4];
#pragma unroll
      for (int jt = 0; jt < 4; ++jt) {
        const f16x4 hb = *(const f16x4*)(HBJ + (b * 256 + jj[jt]) * 192 + og * 16 + q * 4);
        f32x4 a;
#pragma unroll
        for (int r = 0; r < 4; ++r) a[r] = sHa[og * 16 + q * 4 + r] + (float)hb[r];
        a = __builtin_amdgcn_mfma_f32_16x16x16f16(wd, dfr[jt], a, 0, 0, 0);
        const f16x4 af = pack4(fmaxf(a[0], 0.f), fmaxf(a[1], 0.f),
                               fmaxf(a[2], 0.f), fmaxf(a[3], 0.f));
        C3[jt] = __builtin_amdgcn_mfma_f32_16x16x16f16(wc, af, C3[jt], 0, 0, 0);
      }
    }
#pragma unroll
    for (int jt = 0; jt < 4; ++jt)
#pragma unroll
      for (int r = 0; r < 4; ++r)
        fac[jt][r] += cv[jt] * fmaxf(C3[jt][r] + sB[64 + m * 16 + q * 4 + r], 0.f);
  }

  // ---- factors MLP ----
  const f16x4 w1 = *(const f16x4*)&sWf1[l15 * 20 + q * 4];
  const f16x4 w2 = *(const f16x4*)&sWf2[l15 * 20 + q * 4];
  float ffv[4][4];
#pragma unroll
  for (int jt = 0; jt < 4; ++jt) {
    const f16x4 fF = pack4(fac[jt][0], fac[jt][1], fac[jt][2], fac[jt][3]);
    const f32x4 z = {0.f, 0.f, 0.f, 0.f};
    f32x4 G = __builtin_amdgcn_mfma_f32_16x16x16f16(w1, fF, z, 0, 0, 0);
    const f16x4 gF = pack4(fmaxf(G[0] + sB[96 + q * 4 + 0], 0.f),
                           fmaxf(G[1] + sB[96 + q * 4 + 1], 0.f),
                           fmaxf(G[2] + sB[96 + q * 4 + 2], 0.f),
                           fmaxf(G[3] + sB[96 + q * 4 + 3], 0.f));
    f32x4 F2 = __builtin_amdgcn_mfma_f32_16x16x16f16(w2, gF, z, 0, 0, 0);
#pragma unroll
    for (int r = 0; r < 4; ++r) ffv[jt][r] = fmaxf(F2[r] + sB[112 + q * 4 + r], 0.f);
  }

  // ---- coord aggregation ----
  float civ[12];
#pragma unroll
  for (int r = 0; r < 4; ++r)
#pragma unroll
    for (int d = 0; d < 3; ++d) civ[r * 3 + d] = cTb[(3 * (q * 4 + r) + d) * 256 + i];
  float ca[12] = {};
#pragma unroll
  for (int jt = 0; jt < 4; ++jt)
#pragma unroll
    for (int r = 0; r < 4; ++r) {
      const float fv = ffv[jt][r];
#pragma unroll
      for (int d = 0; d < 3; ++d) {
        const float cj = cTb[(3 * (q * 4 + r) + d) * 256 + jj[jt]];
        ca[r * 3 + d] += fv * (civ[r * 3 + d] - cj);
      }
    }
#pragma unroll
  for (int st = 1; st < 16; st <<= 1)
#pragma unroll
    for (int u = 0; u < 12; ++u) ca[u] += __shfl_xor(ca[u], st, 64);
  if (l15 == 0) {
#pragma unroll
    for (int u = 0; u < 12; ++u) red[w * 64 + q * 12 + u] = ca[u];
  }
  __syncthreads();
  if (tid < 48)
    ws[WS_CAC + node * 48 + tid] = red[tid] + red[64 + tid] + red[128 + tid] + red[192 + tid];
}

// ---------------- K2: fused epilogue (1544 blocks x 256) --------------------
__global__ __launch_bounds__(256) void k_epilogue(const void* __restrict__ h,
                                                  const void* __restrict__ coord,
                                                  const void* __restrict__ vel,
                                                  const void* __restrict__ cat,
                                                  const void* __restrict__ Wcv,
                                                  const void* __restrict__ Wql,
                                                  const void* __restrict__ Wkl,
                                                  const float* __restrict__ ws,
                                                  void* __restrict__ outv) {
  const int blk = blockIdx.x, tid = threadIdx.x;
  const int flag = ((const int*)ws)[WS_FLAG];
  if (blk < 512) {  // node model: 4 nodes/block, LDS-staged weights
    const int sub = tid >> 6, f = tid & 63;
    const int node = blk * 4 + sub;
    __shared__ float sWn1[128 * 64];
    __shared__ float sWn2[64 * 64];
    __shared__ float sbn[128];
    __shared__ float x[4][128];
    __shared__ float hid[4][64];
    for (int idx = tid; idx < 8192; idx += 256) sWn1[idx] = ws[WS_WN1T + idx];
    for (int idx = tid; idx < 4096; idx += 256) sWn2[idx] = ws[WS_WN2T + idx];
    if (tid < 128) sbn[tid] = (tid < 64) ? ws[WS_BN1 + tid] : ws[WS_BN2 + tid - 64];
    const float hv = ldv(h, node * 64 + f, flag);
    x[sub][f] = hv;
    x[sub][64 + f] = ws[WS_AGG + node * 64 + f];
    __syncthreads();
    float s = sbn[f];
    for (int k = 0; k < 128; ++k) s += sWn1[k * 64 + f] * x[sub][k];
    hid[sub][f] = fmaxf(s, 0.f);
    __syncthreads();
    float s2 = sbn[64 + f];
    for (int o = 0; o < 64; ++o) s2 += sWn2[o * 64 + f] * hid[sub][o];
    stv(outv, node * 64 + f, hv + s2, flag);
  } else if (blk < 520) {  // coord pipeline, b = blk-512
    const int b = blk - 512;
    const int n = tid, node = b * 256 + n;
    const int wave = n >> 6, lane = n & 63;
    __shared__ float wcv[256], wql[256], wkl[256];
    __shared__ float redm[16];
    wcv[n] = ldv(Wcv, n, flag);
    wql[n] = ldv(Wql, n, flag);
    wkl[n] = ldv(Wkl, n, flag);
    float cf[48];
#pragma unroll
    for (int cd = 0; cd < 48; ++cd) cf[cd] = ldv(coord, node * 48 + cd, flag);
    float s0 = 0.f, s1 = 0.f, s2 = 0.f;
#pragma unroll
    for (int c = 0; c < 16; ++c) { s0 += cf[c*3]; s1 += cf[c*3+1]; s2 += cf[c*3+2]; }
    for (int s = 1; s < 64; s <<= 1) {
      s0 += __shfl_xor(s0, s, 64); s1 += __shfl_xor(s1, s, 64); s2 += __shfl_xor(s2, s, 64);
    }
    if (lane == 0) { redm[wave*4] = s0; redm[wave*4+1] = s1; redm[wave*4+2] = s2; }
    __syncthreads();
    const float m0 = (redm[0]+redm[4]+redm[8]+redm[12]) * (1.f/4096.f);
    const float m1 = (redm[1]+redm[5]+redm[9]+redm[13]) * (1.f/4096.f);
    const float m2 = (redm[2]+redm[6]+redm[10]+redm[14]) * (1.f/4096.f);
    __syncthreads();
    float velf[48];
#pragma unroll
    for (int cd = 0; cd < 48; ++cd) velf[cd] = ldv(vel, node * 48 + cd, flag);
    float c3[48];
#pragma unroll
    for (int c = 0; c < 16; ++c) {
      const float at = ws[WS_ATT + node * 16 + c];
#pragma unroll
      for (int d = 0; d < 3; ++d) {
        const int cd = c * 3 + d;
        const float md = (d == 0) ? m0 : ((d == 1) ? m1 : m2);
        float cc = at * (cf[cd] - md) + cf[cd];
        cc += ws[WS_CAC + node * 48 + cd];
        float a = cc;
#pragma unroll
        for (int cp = 0; cp < 16; ++cp) a += velf[cp * 3 + d] * wcv[c * 16 + cp];
        c3[cd] = a;
      }
    }
    float t0 = 0.f, t1 = 0.f, t2 = 0.f;
#pragma unroll
    for (int c = 0; c < 16; ++c) { t0 += c3[c*3]; t1 += c3[c*3+1]; t2 += c3[c*3+2]; }
    for (int s = 1; s < 64; s <<= 1) {
      t0 += __shfl_xor(t0, s, 64); t1 += __shfl_xor(t1, s, 64); t2 += __shfl_xor(t2, s, 64);
    }
    if (lane == 0) { redm[wave*4] = t0; redm[wave*4+1] = t1; redm[wave*4+2] = t2; }
    __syncthreads();
    const float cm0 = (redm[0]+redm[4]+redm[8]+redm[12]) * (1.f/4096.f);
    const float cm1 = (redm[1]+redm[5]+redm[9]+redm[13]) * (1.f/4096.f);
    const float cm2 = (redm[2]+redm[6]+redm[10]+redm[14]) * (1.f/4096.f);
    float cc[48];
#pragma unroll
    for (int c = 0; c < 16; ++c) {
      cc[c*3]   = c3[c*3]   - cm0;
      cc[c*3+1] = c3[c*3+1] - cm1;
      cc[c*3+2] = c3[c*3+2] - cm2;
    }
#pragma unroll
    for (int o = 0; o < 16; ++o) {
      float qv[3], kv[3];
#pragma unroll
      for (int d = 0; d < 3; ++d) {
        float sq = 0.f, sk = 0.f;
#pragma unroll
        for (int cp = 0; cp < 16; ++cp) {
          sq += cc[cp * 3 + d] * wql[o * 16 + cp];
          sk += cc[cp * 3 + d] * wkl[o * 16 + cp];
        }
        qv[d] = sq; kv[d] = sk;
      }
      const float prod = qv[0]*kv[0] + qv[1]*kv[1] + qv[2]*kv[2];
      const float kns  = kv[0]*kv[0] + kv[1]*kv[1] + kv[2]*kv[2];
      const float wq = prod / (kns + EPSV);
#pragma unroll
      for (int d = 0; d < 3; ++d) {
        const float cmd = (d == 0) ? cm0 : ((d == 1) ? cm1 : cm2);
        const float val = (prod >= 0.f) ? qv[d] : (qv[d] - wq * kv[d]);
        stv(outv, 131072 + node * 48 + o * 3 + d, val + cmd, flag);
      }
    }
  } else {  // category passthrough (overwrites scratch region)
    const int idx = (blk - 520) * 256 + tid;  // 262144 total
    if (flag) ((uint2*)((char*)outv + 458752))[idx] = ((const uint2*)cat)[idx];
    else      ((uint4*)((char*)outv + 917504))[idx] = ((const uint4*)cat)[idx];
  }
}

// ---------------- launch ----------------------------------------------------
extern "C" void kernel_launch(void* const* d_in, const int* in_sizes, int n_in,
                              void* d_out, int out_size, void* d_ws, size_t ws_size,
                              hipStream_t stream) {
  (void)in_sizes; (void)n_in; (void)out_size; (void)ws_size;
  const void* h    = d_in[0];
  const void* coord= d_in[1];
  const void* vel  = d_in[2];
  const void* cat  = d_in[3];
  const void* Wcv  = d_in[4];
  const void* We1  = d_in[5];
  const void* be1  = d_in[6];
  const void* We2  = d_in[7];
  const void* be2  = d_in[8];
  const void* Wc1  = d_in[9];
  const void* bc1  = d_in[10];
  const void* Wc2  = d_in[11];
  const void* bc2  = d_in[12];
  const void* Wf1  = d_in[13];
  const void* bf1v = d_in[14];
  const void* Wf2  = d_in[15];
  const void* bf2v = d_in[16];
  const void* Wn1  = d_in[17];
  const void* bn1  = d_in[18];
  const void* Wn2  = d_in[19];
  const void* bn2  = d_in[20];
  const void* Wql  = d_in[21];
  const void* Wkl  = d_in[22];
  const void* Wqm  = d_in[23];
  const void* bqm  = d_in[24];
  float* ws = (float*)d_ws;

  k_prep_w<<<256, 256, 0, stream>>>(h, coord, We1, Wc1, We2, Wc2, Wf1, Wf2,
                                    Wn1, Wn2, Wqm, be1, bc1, bqm, be2, bc2,
                                    bf1v, bf2v, bn1, bn2, ws, d_out);
  k_gemm<<<160, 256, 0, stream>>>(ws, d_out);
  k_edge<<<2048, 256, 0, stream>>>(cat, ws, d_out);
  k_epilogue<<<1544, 256, 0, stream>>>(h, coord, vel, cat, Wcv, Wql, Wkl, ws, d_out);
}

// Round 13
// 217.302 us; speedup vs baseline: 1.7161x; 1.0752x over previous
//
#include <hip/hip_runtime.h>

typedef unsigned short u16;
typedef unsigned int u32;
typedef _Float16 f16;
typedef __attribute__((ext_vector_type(2))) _Float16 f16x2;
typedef __attribute__((ext_vector_type(4))) _Float16 f16x4;
typedef __attribute__((ext_vector_type(4))) float f32x4;

// Problem constants: B=8, N=256, F=64, C=16, K=2
#define EPSV 1e-4f

// Output element offsets: h_out [0,131072) coord_out [131072,229376) category [229376,1277952)
// Category out-region is scratch: HA[2048*192] | HBJ[2048*192] | h16[2048*64] (f16)
// until k_copycat (launched last) overwrites it.

// ---------------- ws layout (fp32 slots) -----------------------------------
// HARD CAP: max offset must stay <= 391872 (round 9 overflow corrupted the
// adjacent harness allocation -> replay divergence).
// NOTE f16 tables: slot count = f16_elements / 2 (round 12 bug: GWN1 sized at
// 2048 slots but holds 8192 f16 = 4096 slots -> GWN1/GWN2 aliased -> garbage).
static constexpr int WS_FLAG = 0;                     // +16
static constexpr int WS_ATT  = 16;                    // [2048][16]
static constexpr int WS_CT   = 32784;                 // [8][48][256] coord^T fp32
static constexpr int WS_AGG  = 131088;                // [2048][64]
static constexpr int WS_CAC  = 262160;                // [2048][48]  (ends 360464)
static constexpr int WS_GWN1 = 360464;                // f16 [64 o][128 k] = 4096 slots (ends 364560)
static constexpr int WS_GWN2 = 364560;                // f16 [64 f][64 o]  = 2048 slots (ends 366608)
static constexpr int WS_BN1  = 372752;                // [64]
static constexpr int WS_BN2  = 372816;                // [64]
static constexpr int WS_BIAS = 372880;                // be2[64]|bc2[32]|bf1[16]|bf2[16]
static constexpr int WS_GWD  = 373008;                // f16 [192 o'][16 c]   (1536 slots)
static constexpr int WS_GWE2 = 374544;                // f16 [64 f][64 o]     (2048)
static constexpr int WS_GWC2 = 376592;                // f16 [32 mc][64 o]    (1024)
static constexpr int WS_GWF1 = 377616;                // f16 [16][16]         (128)
static constexpr int WS_GWF2 = 377744;                // f16 [16][16]         (128)
static constexpr int WS_GW1  = 377872;                // f16 [400 out][68 k]  (13600 slots)
static constexpr int WS_B400 = 391472;                // [400] layer-1 bias (ends 391872)

static __device__ __forceinline__ float bfld(u16 v) {
  return __uint_as_float(((unsigned)v) << 16);
}
static __device__ __forceinline__ u16 f2b(float x) {  // RNE
  unsigned u = __float_as_uint(x);
  u += 0x7FFFu + ((u >> 16) & 1u);
  return (u16)(u >> 16);
}
static __device__ __forceinline__ float ldv(const void* p, int i, int flag) {
  return flag ? bfld(((const u16*)p)[i]) : ((const float*)p)[i];
}
static __device__ __forceinline__ void stv(void* p, int i, float v, int flag) {
  if (flag) ((u16*)p)[i] = f2b(v);
  else      ((float*)p)[i] = v;
}
static __device__ __forceinline__ f16* scratchHA(void* outv, int flag) {
  return (f16*)((char*)outv + (size_t)229376 * (flag ? 2 : 4));
}
static __device__ __forceinline__ int sniff_flag(const void* h) {
  const u16* hu = (const u16*)h;
  int cnt = 0;
  for (int i = 0; i < 128; ++i) {
    unsigned e = (hu[i] >> 7) & 0xFFu;
    if ((e >= 100u && e <= 150u) || hu[i] == 0) ++cnt;
  }
  return (cnt >= 112) ? 1 : 0;
}
static __device__ __forceinline__ f16x4 pack4(float a, float b, float c, float d) {
  const f16x2 lo = __builtin_bit_cast(f16x2, __builtin_amdgcn_cvt_pkrtz(a, b));
  const f16x2 hi = __builtin_bit_cast(f16x2, __builtin_amdgcn_cvt_pkrtz(c, d));
  f16x4 r; r[0] = lo[0]; r[1] = lo[1]; r[2] = hi[0]; r[3] = hi[1]; return r;
}
// 48 contiguous input elements -> fp32, vectorized
static __device__ __forceinline__ void load48(const void* p, int node, int flag,
                                              float* dst) {
  if (flag) {
    const uint4* q4 = (const uint4*)((const u16*)p + node * 48);
#pragma unroll
    for (int c = 0; c < 6; ++c) {
      const uint4 v = q4[c];
      const u32 a[4] = {v.x, v.y, v.z, v.w};
#pragma unroll
      for (int e = 0; e < 4; ++e) {
        dst[c * 8 + e * 2]     = bfld((u16)(a[e] & 0xFFFFu));
        dst[c * 8 + e * 2 + 1] = bfld((u16)(a[e] >> 16));
      }
    }
  } else {
    const float4* q4 = (const float4*)((const float*)p + node * 48);
#pragma unroll
    for (int c = 0; c < 12; ++c) {
      const float4 v = q4[c];
      dst[c * 4] = v.x; dst[c * 4 + 1] = v.y; dst[c * 4 + 2] = v.z; dst[c * 4 + 3] = v.w;
    }
  }
}

// ---------------- K0: all table builds, fully parallel (256 x 256) ----------
__global__ __launch_bounds__(256) void k_prep_w(
    const void* __restrict__ h, const void* __restrict__ coord,
    const void* __restrict__ We1, const void* __restrict__ Wc1,
    const void* __restrict__ We2, const void* __restrict__ Wc2,
    const void* __restrict__ Wf1, const void* __restrict__ Wf2,
    const void* __restrict__ Wn1, const void* __restrict__ Wn2,
    const void* __restrict__ Wqm,
    const void* __restrict__ be1, const void* __restrict__ bc1,
    const void* __restrict__ bqm, const void* __restrict__ be2,
    const void* __restrict__ bc2, const void* __restrict__ bf1,
    const void* __restrict__ bf2, const void* __restrict__ bn1,
    const void* __restrict__ bn2,
    float* __restrict__ ws, void* __restrict__ outv) {
  const int t = blockIdx.x * 256 + threadIdx.x;
  const int STR = 65536;
  __shared__ int sflag;
  if (threadIdx.x == 0) {
    sflag = sniff_flag(h);
    if (blockIdx.x == 0) ((int*)ws)[WS_FLAG] = sflag;
  }
  __syncthreads();
  const int flag = sflag;

  // GW1: stacked layer-1 weights as [400 out][68 k] f16
  f16* gw1 = (f16*)(ws + WS_GW1);
  for (int idx = t; idx < 25600; idx += STR) {
    const int row = idx >> 6, k = idx & 63;
    float v;
    if (row < 64)       v = ldv(We1, row * 144 + k, flag);
    else if (row < 192) v = ldv(Wc1, (row - 64) * 144 + k, flag);
    else if (row < 384) {
      const int ro = row - 192;
      v = (ro < 64) ? ldv(We1, ro * 144 + 64 + k, flag)
                    : ldv(Wc1, (ro - 64) * 144 + 64 + k, flag);
    } else              v = ldv(Wqm, (row - 384) * 64 + k, flag);
    gw1[row * 68 + k] = (f16)v;
  }
  if (t < 400) {
    float v = (t < 64) ? ldv(be1, t, flag)
            : (t < 192) ? ldv(bc1, t - 64, flag)
            : (t < 384) ? 0.f : ldv(bqm, t - 384, flag);
    ws[WS_B400 + t] = v;
  }
  f16* h16 = scratchHA(outv, flag) + 2048 * 384;
  for (int idx = t; idx < 131072; idx += STR) h16[idx] = (f16)ldv(h, idx, flag);
  for (int idx = t; idx < 98304; idx += STR) {  // coord^T [b][cd][n]
    const int bq = idx / 12288, rem = idx - bq * 12288;
    const int cd = rem >> 8, n = rem & 255;
    ws[WS_CT + idx] = ldv(coord, (bq * 256 + n) * 48 + cd, flag);
  }
  f16* gwd  = (f16*)(ws + WS_GWD);
  f16* gwe2 = (f16*)(ws + WS_GWE2);
  f16* gwc2 = (f16*)(ws + WS_GWC2);
  f16* gwf1 = (f16*)(ws + WS_GWF1);
  f16* gwf2 = (f16*)(ws + WS_GWF2);
  for (int idx = t; idx < 3072; idx += STR) {  // [o'][c] <- cols 128..143
    const int o = idx >> 4, c = idx & 15;
    const void* src = (o < 64) ? We1 : Wc1;
    const int row = (o < 64) ? o : (o - 64);
    gwd[idx] = (f16)ldv(src, row * 144 + 128 + c, flag);
  }
  for (int idx = t; idx < 4096; idx += STR) gwe2[idx] = (f16)ldv(We2, idx, flag);
  for (int idx = t; idx < 2048; idx += STR) gwc2[idx] = (f16)ldv(Wc2, idx, flag);
  if (t < 256) { gwf1[t] = (f16)ldv(Wf1, t, flag); gwf2[t] = (f16)ldv(Wf2, t, flag); }
  // node-model f16 tables (row-major copies)
  f16* gwn1 = (f16*)(ws + WS_GWN1);
  f16* gwn2 = (f16*)(ws + WS_GWN2);
  for (int idx = t; idx < 8192; idx += STR) gwn1[idx] = (f16)ldv(Wn1, idx, flag);
  for (int idx = t; idx < 4096; idx += STR) gwn2[idx] = (f16)ldv(Wn2, idx, flag);
  if (t < 64)  ws[WS_BN1 + t] = ldv(bn1, t, flag);
  if (t >= 64 && t < 128) ws[WS_BN2 + t - 64] = ldv(bn2, t - 64, flag);
  if (t >= 128 && t < 192) ws[WS_BIAS + t - 128] = ldv(be2, t - 128, flag);
  if (t >= 192 && t < 224) ws[WS_BIAS + 64 + t - 192] = ldv(bc2, t - 192, flag);
  if (t >= 224 && t < 240) ws[WS_BIAS + 96 + t - 224] = ldv(bf1, t - 224, flag);
  if (t >= 240 && t < 256) ws[WS_BIAS + 112 + t - 240] = ldv(bf2, t - 240, flag);
}

// ---------------- K0b: layer-1 MFMA GEMM -> HA/HBJ/ATT (160 x 256) ----------
__global__ __launch_bounds__(256) void k_gemm(float* __restrict__ ws,
                                              void* __restrict__ outv) {
  const int flag = ((const int*)ws)[WS_FLAG];
  const int nt = blockIdx.x / 5, grp = blockIdx.x % 5;
  const int tid = threadIdx.x, w = tid >> 6, lane = tid & 63;
  const int q = lane >> 4, l15 = lane & 15;
  f16* HA16 = scratchHA(outv, flag);
  f16* HBJ  = HA16 + 2048 * 192;
  const f16* h16 = HA16 + 2048 * 384;
  __shared__ __align__(16) f16 sW[80 * 68];
  __shared__ float sBias[80];
  const u32* gw1 = (const u32*)(ws + WS_GW1);
  for (int idx = tid; idx < 2720; idx += 256) {
    const int r = idx / 34, c = idx - r * 34;
    *(u32*)&sW[r * 68 + c * 2] = gw1[(grp * 80 + r) * 34 + c];
  }
  if (tid < 80) sBias[tid] = ws[WS_B400 + grp * 80 + tid];
  __syncthreads();
  const int nodeA = nt * 64 + w * 16 + l15;
  f16x4 Af[4];
#pragma unroll
  for (int ks = 0; ks < 4; ++ks)
    Af[ks] = *(const f16x4*)(h16 + nodeA * 64 + ks * 16 + q * 4);
#pragma unroll
  for (int ot = 0; ot < 5; ++ot) {
    const float bv = sBias[ot * 16 + l15];
    f32x4 acc = (f32x4){bv, bv, bv, bv};
#pragma unroll
    for (int ks = 0; ks < 4; ++ks) {
      const f16x4 Bf = *(const f16x4*)&sW[(ot * 16 + l15) * 68 + ks * 16 + q * 4];
      acc = __builtin_amdgcn_mfma_f32_16x16x16f16(Af[ks], Bf, acc, 0, 0, 0);
    }
    const int out = grp * 80 + ot * 16 + l15;
    const int nodeD = nt * 64 + w * 16 + q * 4;
#pragma unroll
    for (int r = 0; r < 4; ++r) {
      const int node = nodeD + r;
      if (out < 192)      HA16[node * 192 + out] = (f16)acc[r];
      else if (out < 384) HBJ[node * 192 + out - 192] = (f16)acc[r];
      else                ws[WS_ATT + node * 16 + out - 384] = fmaxf(acc[r], 0.f);
    }
  }
}

// ---------------- K1: MFMA edge kernel (2048 blocks x 256) ------------------
// XCD swizzle: b = blk&7 so each XCD's L2 caches exactly one batch's HBJ/cT.
__global__ __launch_bounds__(256, 3) void k_edge(const void* __restrict__ cat,
                                                 float* __restrict__ ws,
                                                 void* __restrict__ outv) {
  const int node = ((blockIdx.x & 7) << 8) | (blockIdx.x >> 3);
  const int b = node >> 8, i = node & 255;
  const int tid = threadIdx.x;
  const int w = tid >> 6, lane = tid & 63, q = lane >> 4, l15 = lane & 15;
  const int flag = ((const int*)ws)[WS_FLAG];
  const f16* HA16 = scratchHA(outv, flag);
  const f16* HBJ  = HA16 + 2048 * 192;
  const float* __restrict__ cTb = ws + WS_CT + b * 48 * 256;

  __shared__ __align__(16) f16 sWd[192 * 20];
  __shared__ __align__(16) f16 sWe2[64 * 76];
  __shared__ __align__(16) f16 sWc2[32 * 76];
  __shared__ __align__(16) f16 sWf1[16 * 20];
  __shared__ __align__(16) f16 sWf2[16 * 20];
  __shared__ __align__(16) f16 distS[256 * 20];
  __shared__ float sHa[192];
  __shared__ float sB[128];
  __shared__ __align__(16) float red[256];

  {  // stage weight tables
    const u32* gwd = (const u32*)(ws + WS_GWD);
    for (int idx = tid; idx < 1536; idx += 256) {
      const int r = idx >> 3, c = idx & 7;
      *(u32*)&sWd[r * 20 + c * 2] = gwd[idx];
    }
    const u32* gwe = (const u32*)(ws + WS_GWE2);
    for (int idx = tid; idx < 2048; idx += 256) {
      const int r = idx >> 5, c = idx & 31;
      *(u32*)&sWe2[r * 76 + c * 2] = gwe[idx];
    }
    const u32* gwc = (const u32*)(ws + WS_GWC2);
    for (int idx = tid; idx < 1024; idx += 256) {
      const int r = idx >> 5, c = idx & 31;
      *(u32*)&sWc2[r * 76 + c * 2] = gwc[idx];
    }
    if (tid < 128) {
      const int r = tid >> 3, c = tid & 7;
      *(u32*)&sWf1[r * 20 + c * 2] = ((const u32*)(ws + WS_GWF1))[tid];
      *(u32*)&sWf2[r * 20 + c * 2] = ((const u32*)(ws + WS_GWF2))[tid];
    }
    if (tid < 192) sHa[tid] = (float)HA16[node * 192 + tid];
    if (tid < 128) sB[tid] = ws[WS_BIAS + tid];
  }
  {  // distances
    float dr[16];
#pragma unroll
    for (int c = 0; c < 16; ++c) {
      float s = 0.f;
#pragma unroll
      for (int d = 0; d < 3; ++d) {
        const int cd = c * 3 + d;
        const float df = cTb[cd * 256 + i] - cTb[cd * 256 + tid];
        s += df * df;
      }
      dr[c] = sqrtf(s);
    }
#pragma unroll
    for (int kk = 0; kk < 4; ++kk)
      *(f16x4*)&distS[tid * 20 + kk * 4] =
          pack4(dr[4 * kk], dr[4 * kk + 1], dr[4 * kk + 2], dr[4 * kk + 3]);
  }
  __syncthreads();

  int jj[4]; float mjt[4]; f16x4 dfr[4];
#pragma unroll
  for (int jt = 0; jt < 4; ++jt) {
    jj[jt] = w * 64 + jt * 16 + l15;
    mjt[jt] = (jj[jt] == i) ? 0.f : 1.f;
    dfr[jt] = *(const f16x4*)&distS[jj[jt] * 20 + q * 4];
  }

  // ---- phase 1: e2 GEMM chain, C2[f][j] over K=64 ----
  f32x4 C2[4][4];
#pragma unroll
  for (int ft = 0; ft < 4; ++ft)
#pragma unroll
    for (int jt = 0; jt < 4; ++jt) C2[ft][jt] = (f32x4){0.f, 0.f, 0.f, 0.f};
#pragma unroll
  for (int og = 0; og < 4; ++og) {
    const f16x4 wd = *(const f16x4*)&sWd[(og * 16 + l15) * 20 + q * 4];
    f16x4 af[4];
#pragma unroll
    for (int jt = 0; jt < 4; ++jt) {
      const f16x4 hb = *(const f16x4*)(HBJ + (b * 256 + jj[jt]) * 192 + og * 16 + q * 4);
      f32x4 a;
#pragma unroll
      for (int r = 0; r < 4; ++r) a[r] = sHa[og * 16 + q * 4 + r] + (float)hb[r];
      a = __builtin_amdgcn_mfma_f32_16x16x16f16(wd, dfr[jt], a, 0, 0, 0);
      af[jt] = pack4(fmaxf(a[0], 0.f), fmaxf(a[1], 0.f), fmaxf(a[2], 0.f), fmaxf(a[3], 0.f));
    }
#pragma unroll
    for (int ft = 0; ft < 4; ++ft) {
      const f16x4 we = *(const f16x4*)&sWe2[(ft * 16 + l15) * 76 + og * 16 + q * 4];
#pragma unroll
      for (int jt = 0; jt < 4; ++jt)
        C2[ft][jt] = __builtin_amdgcn_mfma_f32_16x16x16f16(we, af[jt], C2[ft][jt], 0, 0, 0);
    }
  }
#pragma unroll
  for (int ft = 0; ft < 4; ++ft) {
    float s[4] = {0.f, 0.f, 0.f, 0.f};
#pragma unroll
    for (int jt = 0; jt < 4; ++jt)
#pragma unroll
      for (int r = 0; r < 4; ++r)
        s[r] += fmaxf(C2[ft][jt][r] + sB[ft * 16 + q * 4 + r], 0.f) * mjt[jt];
#pragma unroll
    for (int st = 1; st < 16; st <<= 1)
#pragma unroll
      for (int r = 0; r < 4; ++r) s[r] += __shfl_xor(s[r], st, 64);
    if (l15 == 0) {
#pragma unroll
      for (int r = 0; r < 4; ++r) red[w * 64 + ft * 16 + q * 4 + r] = s[r];
    }
  }
  __syncthreads();
  if (tid < 64)
    ws[WS_AGG + node * 64 + tid] = red[tid] + red[64 + tid] + red[128 + tid] + red[192 + tid];
  __syncthreads();

  // ---- phase 2: category chains -> factors ----
  float fac[4][4] = {};
#pragma unroll
  for (int m = 0; m < 2; ++m) {
    float cv[4];
#pragma unroll
    for (int jt = 0; jt < 4; ++jt) {
      if (flag) {
        const u32 p = ((const u32*)cat)[node * 256 + jj[jt]];
        cv[jt] = bfld((u16)(m ? (p >> 16) : (p & 0xFFFFu)));
      } else {
        cv[jt] = ((const float*)cat)[(node * 256 + jj[jt]) * 2 + m];
      }
    }
    f32x4 C3[4];
#pragma unroll
    for (int jt = 0; jt < 4; ++jt) C3[jt] = (f32x4){0.f, 0.f, 0.f, 0.f};
#pragma unroll
    for (int og2 = 0; og2 < 4; ++og2) {
      const int og = 4 + m * 4 + og2;
      const f16x4 wd = *(const f16x4*)&sWd[(og * 16 + l15) * 20 + q * 4];
      const f16x4 wc = *(const f16x4*)&sWc2[(m * 16 + l15) * 76 + og2 * 16 + q * 4];
#pragma unroll
      for (int jt = 0; jt < 4; ++jt) {
        const f16x4 hb = *(const f16x4*)(HBJ + (b * 256 + jj[jt]) * 192 + og * 16 + q * 4);
        f32x4 a;
#pragma unroll
        for (int r = 0; r < 4; ++r) a[r] = sHa[og * 16 + q * 4 + r] + (float)hb[r];
        a = __builtin_amdgcn_mfma_f32_16x16x16f16(wd, dfr[jt], a, 0, 0, 0);
        const f16x4 af = pack4(fmaxf(a[0], 0.f), fmaxf(a[1], 0.f),
                               fmaxf(a[2], 0.f), fmaxf(a[3], 0.f));
        C3[jt] = __builtin_amdgcn_mfma_f32_16x16x16f16(wc, af, C3[jt], 0, 0, 0);
      }
    }
#pragma unroll
    for (int jt = 0; jt < 4; ++jt)
#pragma unroll
      for (int r = 0; r < 4; ++r)
        fac[jt][r] += cv[jt] * fmaxf(C3[jt][r] + sB[64 + m * 16 + q * 4 + r], 0.f);
  }

  // ---- factors MLP ----
  const f16x4 w1 = *(const f16x4*)&sWf1[l15 * 20 + q * 4];
  const f16x4 w2 = *(const f16x4*)&sWf2[l15 * 20 + q * 4];
  float ffv[4][4];
#pragma unroll
  for (int jt = 0; jt < 4; ++jt) {
    const f16x4 fF = pack4(fac[jt][0], fac[jt][1], fac[jt][2], fac[jt][3]);
    const f32x4 z = {0.f, 0.f, 0.f, 0.f};
    f32x4 G = __builtin_amdgcn_mfma_f32_16x16x16f16(w1, fF, z, 0, 0, 0);
    const f16x4 gF = pack4(fmaxf(G[0] + sB[96 + q * 4 + 0], 0.f),
                           fmaxf(G[1] + sB[96 + q * 4 + 1], 0.f),
                           fmaxf(G[2] + sB[96 + q * 4 + 2], 0.f),
                           fmaxf(G[3] + sB[96 + q * 4 + 3], 0.f));
    f32x4 F2 = __builtin_amdgcn_mfma_f32_16x16x16f16(w2, gF, z, 0, 0, 0);
#pragma unroll
    for (int r = 0; r < 4; ++r) ffv[jt][r] = fmaxf(F2[r] + sB[112 + q * 4 + r], 0.f);
  }

  // ---- coord aggregation ----
  float civ[12];
#pragma unroll
  for (int r = 0; r < 4; ++r)
#pragma unroll
    for (int d = 0; d < 3; ++d) civ[r * 3 + d] = cTb[(3 * (q * 4 + r) + d) * 256 + i];
  float ca[12] = {};
#pragma unroll
  for (int jt = 0; jt < 4; ++jt)
#pragma unroll
    for (int r = 0; r < 4; ++r) {
      const float fv = ffv[jt][r];
#pragma unroll
      for (int d = 0; d < 3; ++d) {
        const float cj = cTb[(3 * (q * 4 + r) + d) * 256 + jj[jt]];
        ca[r * 3 + d] += fv * (civ[r * 3 + d] - cj);
      }
    }
#pragma unroll
  for (int st = 1; st < 16; st <<= 1)
#pragma unroll
    for (int u = 0; u < 12; ++u) ca[u] += __shfl_xor(ca[u], st, 64);
  if (l15 == 0) {
#pragma unroll
    for (int u = 0; u < 12; ++u) red[w * 64 + q * 12 + u] = ca[u];
  }
  __syncthreads();
  if (tid < 48)
    ws[WS_CAC + node * 48 + tid] = red[tid] + red[64 + tid] + red[128 + tid] + red[192 + tid];
}

// ---------------- K2: node model as chained MFMA GEMMs (32 x 256) -----------
__global__ __launch_bounds__(256) void k_node(float* __restrict__ ws,
                                              void* __restrict__ outv) {
  const int flag = ((const int*)ws)[WS_FLAG];
  const int tid = threadIdx.x, w = tid >> 6, lane = tid & 63;
  const int q = lane >> 4, l15 = lane & 15;
  const f16* h16 = scratchHA(outv, flag) + 2048 * 384;
  __shared__ __align__(16) f16 sW1[64 * 132];  // [o][k] pad 132
  __shared__ __align__(16) f16 sW2[64 * 68];   // [f][o] pad 68
  __shared__ float sbn[128];
  {
    const u32* g1 = (const u32*)(ws + WS_GWN1);
    for (int idx = tid; idx < 4096; idx += 256) {
      const int o = idx >> 6, c = idx & 63;
      *(u32*)&sW1[o * 132 + c * 2] = g1[idx];
    }
    const u32* g2 = (const u32*)(ws + WS_GWN2);
    for (int idx = tid; idx < 2048; idx += 256) {
      const int o = idx >> 5, c = idx & 31;
      *(u32*)&sW2[o * 68 + c * 2] = g2[idx];
    }
    if (tid < 128) sbn[tid] = (tid < 64) ? ws[WS_BN1 + tid] : ws[WS_BN2 + tid - 64];
  }
  __syncthreads();
  const int node = blockIdx.x * 64 + w * 16 + l15;
  f16x4 xB[8];
#pragma unroll
  for (int kt = 0; kt < 4; ++kt)
    xB[kt] = *(const f16x4*)(h16 + node * 64 + kt * 16 + q * 4);
#pragma unroll
  for (int kt = 0; kt < 4; ++kt) {
    const float* ap = ws + WS_AGG + node * 64 + kt * 16 + q * 4;
    xB[4 + kt] = pack4(ap[0], ap[1], ap[2], ap[3]);
  }
  f16x4 hidB[4];
#pragma unroll
  for (int ot = 0; ot < 4; ++ot) {
    f32x4 acc;
#pragma unroll
    for (int r = 0; r < 4; ++r) acc[r] = sbn[ot * 16 + q * 4 + r];
#pragma unroll
    for (int kt = 0; kt < 8; ++kt) {
      const f16x4 a = *(const f16x4*)&sW1[(ot * 16 + l15) * 132 + kt * 16 + q * 4];
      acc = __builtin_amdgcn_mfma_f32_16x16x16f16(a, xB[kt], acc, 0, 0, 0);
    }
    hidB[ot] = pack4(fmaxf(acc[0], 0.f), fmaxf(acc[1], 0.f),
                     fmaxf(acc[2], 0.f), fmaxf(acc[3], 0.f));
  }
#pragma unroll
  for (int ft = 0; ft < 4; ++ft) {
    const f16x4 hl = *(const f16x4*)(h16 + node * 64 + ft * 16 + q * 4);
    f32x4 acc;
#pragma unroll
    for (int r = 0; r < 4; ++r) acc[r] = sbn[64 + ft * 16 + q * 4 + r] + (float)hl[r];
#pragma unroll
    for (int ot = 0; ot < 4; ++ot) {
      const f16x4 a = *(const f16x4*)&sW2[(ft * 16 + l15) * 68 + ot * 16 + q * 4];
      acc = __builtin_amdgcn_mfma_f32_16x16x16f16(a, hidB[ot], acc, 0, 0, 0);
    }
#pragma unroll
    for (int r = 0; r < 4; ++r)
      stv(outv, node * 64 + ft * 16 + q * 4 + r, acc[r], flag);
  }
}

// ---------------- K3: coord pipeline (8 x 256) ------------------------------
__global__ __launch_bounds__(256) void k_coord(const void* __restrict__ coord,
                                               const void* __restrict__ vel,
                                               const void* __restrict__ Wcv,
                                               const void* __restrict__ Wql,
                                               const void* __restrict__ Wkl,
                                               const float* __restrict__ ws,
                                               void* __restrict__ outv) {
  const int b = blockIdx.x;
  const int n = threadIdx.x, node = b * 256 + n;
  const int wave = n >> 6, lane = n & 63;
  const int flag = ((const int*)ws)[WS_FLAG];
  __shared__ float wcv[256], wql[256], wkl[256];
  __shared__ float redm[16];
  wcv[n] = ldv(Wcv, n, flag);
  wql[n] = ldv(Wql, n, flag);
  wkl[n] = ldv(Wkl, n, flag);
  float cf[48];
  load48(coord, node, flag, cf);
  float s0 = 0.f, s1 = 0.f, s2 = 0.f;
#pragma unroll
  for (int c = 0; c < 16; ++c) { s0 += cf[c*3]; s1 += cf[c*3+1]; s2 += cf[c*3+2]; }
  for (int s = 1; s < 64; s <<= 1) {
    s0 += __shfl_xor(s0, s, 64); s1 += __shfl_xor(s1, s, 64); s2 += __shfl_xor(s2, s, 64);
  }
  if (lane == 0) { redm[wave*4] = s0; redm[wave*4+1] = s1; redm[wave*4+2] = s2; }
  __syncthreads();
  const float m0 = (redm[0]+redm[4]+redm[8]+redm[12]) * (1.f/4096.f);
  const float m1 = (redm[1]+redm[5]+redm[9]+redm[13]) * (1.f/4096.f);
  const float m2 = (redm[2]+redm[6]+redm[10]+redm[14]) * (1.f/4096.f);
  __syncthreads();
  float velf[48];
  load48(vel, node, flag, velf);
  float c3[48];
#pragma unroll
  for (int c = 0; c < 16; ++c) {
    const float at = ws[WS_ATT + node * 16 + c];
#pragma unroll
    for (int d = 0; d < 3; ++d) {
      const int cd = c * 3 + d;
      const float md = (d == 0) ? m0 : ((d == 1) ? m1 : m2);
      float cc = at * (cf[cd] - md) + cf[cd];
      cc += ws[WS_CAC + node * 48 + cd];
      float a = cc;
#pragma unroll
      for (int cp = 0; cp < 16; ++cp) a += velf[cp * 3 + d] * wcv[c * 16 + cp];
      c3[cd] = a;
    }
  }
  float t0 = 0.f, t1 = 0.f, t2 = 0.f;
#pragma unroll
  for (int c = 0; c < 16; ++c) { t0 += c3[c*3]; t1 += c3[c*3+1]; t2 += c3[c*3+2]; }
  for (int s = 1; s < 64; s <<= 1) {
    t0 += __shfl_xor(t0, s, 64); t1 += __shfl_xor(t1, s, 64); t2 += __shfl_xor(t2, s, 64);
  }
  if (lane == 0) { redm[wave*4] = t0; redm[wave*4+1] = t1; redm[wave*4+2] = t2; }
  __syncthreads();
  const float cm0 = (redm[0]+redm[4]+redm[8]+redm[12]) * (1.f/4096.f);
  const float cm1 = (redm[1]+redm[5]+redm[9]+redm[13]) * (1.f/4096.f);
  const float cm2 = (redm[2]+redm[6]+redm[10]+redm[14]) * (1.f/4096.f);
  float cc[48];
#pragma unroll
  for (int c = 0; c < 16; ++c) {
    cc[c*3]   = c3[c*3]   - cm0;
    cc[c*3+1] = c3[c*3+1] - cm1;
    cc[c*3+2] = c3[c*3+2] - cm2;
  }
#pragma unroll
  for (int o = 0; o < 16; ++o) {
    float qv[3], kv[3];
#pragma unroll
    for (int d = 0; d < 3; ++d) {
      float sq = 0.f, sk = 0.f;
#pragma unroll
      for (int cp = 0; cp < 16; ++cp) {
        sq += cc[cp * 3 + d] * wql[o * 16 + cp];
        sk += cc[cp * 3 + d] * wkl[o * 16 + cp];
      }
      qv[d] = sq; kv[d] = sk;
    }
    const float prod = qv[0]*kv[0] + qv[1]*kv[1] + qv[2]*kv[2];
    const float kns  = kv[0]*kv[0] + kv[1]*kv[1] + kv[2]*kv[2];
    const float wq = prod / (kns + EPSV);
#pragma unroll
    for (int d = 0; d < 3; ++d) {
      const float cmd = (d == 0) ? cm0 : ((d == 1) ? cm1 : cm2);
      const float val = (prod >= 0.f) ? qv[d] : (qv[d] - wq * kv[d]);
      stv(outv, 131072 + node * 48 + o * 3 + d, val + cmd, flag);
    }
  }
}

// ---------------- K4: category passthrough, last (512 x 256) ----------------
__global__ void k_copycat(const void* __restrict__ cat, const float* __restrict__ ws,
                          void* __restrict__ outv) {
  const int flag = ((const int*)ws)[WS_FLAG];
  const int idx = blockIdx.x * 256 + threadIdx.x;  // 131072 threads
  if (flag) {
    ((uint4*)((char*)outv + 458752))[idx] = ((const uint4*)cat)[idx];
  } else {
    ((uint4*)((char*)outv + 917504))[idx] = ((const uint4*)cat)[idx];
    ((uint4*)((char*)outv + 917504))[idx + 131072] = ((const uint4*)cat)[idx + 131072];
  }
}

// ---------------- launch ----------------------------------------------------
extern "C" void kernel_launch(void* const* d_in, const int* in_sizes, int n_in,
                              void* d_out, int out_size, void* d_ws, size_t ws_size,
                              hipStream_t stream) {
  (void)in_sizes; (void)n_in; (void)out_size; (void)ws_size;
  const void* h    = d_in[0];
  const void* coord= d_in[1];
  const void* vel  = d_in[2];
  const void* cat  = d_in[3];
  const void* Wcv  = d_in[4];
  const void* We1  = d_in[5];
  const void* be1  = d_in[6];
  const void* We2  = d_in[7];
  const void* be2  = d_in[8];
  const void* Wc1  = d_in[9];
  const void* bc1  = d_in[10];
  const void* Wc2  = d_in[11];
  const void* bc2  = d_in[12];
  const void* Wf1  = d_in[13];
  const void* bf1v = d_in[14];
  const void* Wf2  = d_in[15];
  const void* bf2v = d_in[16];
  const void* Wn1  = d_in[17];
  const void* bn1  = d_in[18];
  const void* Wn2  = d_in[19];
  const void* bn2  = d_in[20];
  const void* Wql  = d_in[21];
  const void* Wkl  = d_in[22];
  const void* Wqm  = d_in[23];
  const void* bqm  = d_in[24];
  float* ws = (float*)d_ws;

  k_prep_w<<<256, 256, 0, stream>>>(h, coord, We1, Wc1, We2, Wc2, Wf1, Wf2,
                                    Wn1, Wn2, Wqm, be1, bc1, bqm, be2, bc2,
                                    bf1v, bf2v, bn1, bn2, ws, d_out);
  k_gemm<<<160, 256, 0, stream>>>(ws, d_out);
  k_edge<<<2048, 256, 0, stream>>>(cat, ws, d_out);
  k_node<<<32, 256, 0, stream>>>(ws, d_out);          // reads h16+agg (scratch)
  k_coord<<<8, 256, 0, stream>>>(coord, vel, Wcv, Wql, Wkl, ws, d_out);
  k_copycat<<<512, 256, 0, stream>>>(cat, ws, d_out); // overwrites scratch last
}

// Round 16
// 213.369 us; speedup vs baseline: 1.7477x; 1.0184x over previous
//
#include <hip/hip_runtime.h>

typedef unsigned short u16;
typedef unsigned int u32;
typedef _Float16 f16;
typedef __attribute__((ext_vector_type(2))) _Float16 f16x2;
typedef __attribute__((ext_vector_type(4))) _Float16 f16x4;
typedef __attribute__((ext_vector_type(4))) float f32x4;

// Problem constants: B=8, N=256, F=64, C=16, K=2
#define EPSV 1e-4f

// Output element offsets: h_out [0,131072) coord_out [131072,229376) category [229376,1277952)
// Category out-region is scratch: HA[2048*192] | HBJ[2048*192] (f16) until the
// epilogue's copycat blocks overwrite it (safe: only k_edge reads scratch).

// ---------------- ws layout (fp32 slots) -----------------------------------
// HARD CAP: max offset <= 391872 (round 9 overflow corrupted adjacent alloc).
// f16 tables: slot count = f16_elements / 2 (round 12 aliasing bug).
static constexpr int WS_FLAG = 0;                     // +16
static constexpr int WS_ATT  = 16;                    // [2048][16]
static constexpr int WS_CT   = 32784;                 // [8][48][256] coord^T fp32
static constexpr int WS_AGG  = 131088;                // [2048][64]
static constexpr int WS_CAC  = 262160;                // [2048][48]  (ends 360464)
static constexpr int WS_GWN1 = 360464;                // f16 [64 o][128 k] = 4096 slots (ends 364560)
static constexpr int WS_GWN2 = 364560;                // f16 [64 f][64 o]  = 2048 slots (ends 366608)
static constexpr int WS_BN1  = 372752;                // [64]
static constexpr int WS_BN2  = 372816;                // [64]
static constexpr int WS_BIAS = 372880;                // be2[64]|bc2[32]|bf1[16]|bf2[16]
static constexpr int WS_GWD  = 373008;                // f16 [192 o'][16 c]   (1536 slots)
static constexpr int WS_GWE2 = 374544;                // f16 [64 f][64 o]     (2048)
static constexpr int WS_GWC2 = 376592;                // f16 [32 mc][64 o]    (1024)
static constexpr int WS_GWF1 = 377616;                // f16 [16][16]         (128)
static constexpr int WS_GWF2 = 377744;                // f16 [16][16]         (128)
static constexpr int WS_GW1  = 377872;                // f16 [400 out][68 k]  (13600 slots)
static constexpr int WS_B400 = 391472;                // [400] layer-1 bias (ends 391872)

static __device__ __forceinline__ float bfld(u16 v) {
  return __uint_as_float(((unsigned)v) << 16);
}
static __device__ __forceinline__ u16 f2b(float x) {  // RNE
  unsigned u = __float_as_uint(x);
  u += 0x7FFFu + ((u >> 16) & 1u);
  return (u16)(u >> 16);
}
static __device__ __forceinline__ float ldv(const void* p, int i, int flag) {
  return flag ? bfld(((const u16*)p)[i]) : ((const float*)p)[i];
}
static __device__ __forceinline__ void stv(void* p, int i, float v, int flag) {
  if (flag) ((u16*)p)[i] = f2b(v);
  else      ((float*)p)[i] = v;
}
static __device__ __forceinline__ f16* scratchHA(void* outv, int flag) {
  return (f16*)((char*)outv + (size_t)229376 * (flag ? 2 : 4));
}
static __device__ __forceinline__ int sniff_flag(const void* h) {
  const u16* hu = (const u16*)h;
  int cnt = 0;
  for (int i = 0; i < 128; ++i) {
    unsigned e = (hu[i] >> 7) & 0xFFu;
    if ((e >= 100u && e <= 150u) || hu[i] == 0) ++cnt;
  }
  return (cnt >= 112) ? 1 : 0;
}
static __device__ __forceinline__ f16x4 pack4(float a, float b, float c, float d) {
  const f16x2 lo = __builtin_bit_cast(f16x2, __builtin_amdgcn_cvt_pkrtz(a, b));
  const f16x2 hi = __builtin_bit_cast(f16x2, __builtin_amdgcn_cvt_pkrtz(c, d));
  f16x4 r; r[0] = lo[0]; r[1] = lo[1]; r[2] = hi[0]; r[3] = hi[1]; return r;
}
// 48 contiguous input elements -> fp32, vectorized
static __device__ __forceinline__ void load48(const void* p, int node, int flag,
                                              float* dst) {
  if (flag) {
    const uint4* q4 = (const uint4*)((const u16*)p + node * 48);
#pragma unroll
    for (int c = 0; c < 6; ++c) {
      const uint4 v = q4[c];
      const u32 a[4] = {v.x, v.y, v.z, v.w};
#pragma unroll
      for (int e = 0; e < 4; ++e) {
        dst[c * 8 + e * 2]     = bfld((u16)(a[e] & 0xFFFFu));
        dst[c * 8 + e * 2 + 1] = bfld((u16)(a[e] >> 16));
      }
    }
  } else {
    const float4* q4 = (const float4*)((const float*)p + node * 48);
#pragma unroll
    for (int c = 0; c < 12; ++c) {
      const float4 v = q4[c];
      dst[c * 4] = v.x; dst[c * 4 + 1] = v.y; dst[c * 4 + 2] = v.z; dst[c * 4 + 3] = v.w;
    }
  }
}

// ---------------- K0: table builds, fully parallel (256 x 256) --------------
__global__ __launch_bounds__(256) void k_prep_w(
    const void* __restrict__ h, const void* __restrict__ coord,
    const void* __restrict__ We1, const void* __restrict__ Wc1,
    const void* __restrict__ We2, const void* __restrict__ Wc2,
    const void* __restrict__ Wf1, const void* __restrict__ Wf2,
    const void* __restrict__ Wn1, const void* __restrict__ Wn2,
    const void* __restrict__ Wqm,
    const void* __restrict__ be1, const void* __restrict__ bc1,
    const void* __restrict__ bqm, const void* __restrict__ be2,
    const void* __restrict__ bc2, const void* __restrict__ bf1,
    const void* __restrict__ bf2, const void* __restrict__ bn1,
    const void* __restrict__ bn2,
    float* __restrict__ ws) {
  const int t = blockIdx.x * 256 + threadIdx.x;
  const int STR = 65536;
  __shared__ int sflag;
  if (threadIdx.x == 0) {
    sflag = sniff_flag(h);
    if (blockIdx.x == 0) ((int*)ws)[WS_FLAG] = sflag;
  }
  __syncthreads();
  const int flag = sflag;

  // GW1: stacked layer-1 weights as [400 out][68 k] f16
  f16* gw1 = (f16*)(ws + WS_GW1);
  for (int idx = t; idx < 25600; idx += STR) {
    const int row = idx >> 6, k = idx & 63;
    float v;
    if (row < 64)       v = ldv(We1, row * 144 + k, flag);
    else if (row < 192) v = ldv(Wc1, (row - 64) * 144 + k, flag);
    else if (row < 384) {
      const int ro = row - 192;
      v = (ro < 64) ? ldv(We1, ro * 144 + 64 + k, flag)
                    : ldv(Wc1, (ro - 64) * 144 + 64 + k, flag);
    } else              v = ldv(Wqm, (row - 384) * 64 + k, flag);
    gw1[row * 68 + k] = (f16)v;
  }
  if (t < 400) {
    float v = (t < 64) ? ldv(be1, t, flag)
            : (t < 192) ? ldv(bc1, t - 64, flag)
            : (t < 384) ? 0.f : ldv(bqm, t - 384, flag);
    ws[WS_B400 + t] = v;
  }
  for (int idx = t; idx < 98304; idx += STR) {  // coord^T [b][cd][n]
    const int bq = idx / 12288, rem = idx - bq * 12288;
    const int cd = rem >> 8, n = rem & 255;
    ws[WS_CT + idx] = ldv(coord, (bq * 256 + n) * 48 + cd, flag);
  }
  f16* gwd  = (f16*)(ws + WS_GWD);
  f16* gwe2 = (f16*)(ws + WS_GWE2);
  f16* gwc2 = (f16*)(ws + WS_GWC2);
  f16* gwf1 = (f16*)(ws + WS_GWF1);
  f16* gwf2 = (f16*)(ws + WS_GWF2);
  for (int idx = t; idx < 3072; idx += STR) {  // [o'][c] <- cols 128..143
    const int o = idx >> 4, c = idx & 15;
    const void* src = (o < 64) ? We1 : Wc1;
    const int row = (o < 64) ? o : (o - 64);
    gwd[idx] = (f16)ldv(src, row * 144 + 128 + c, flag);
  }
  for (int idx = t; idx < 4096; idx += STR) gwe2[idx] = (f16)ldv(We2, idx, flag);
  for (int idx = t; idx < 2048; idx += STR) gwc2[idx] = (f16)ldv(Wc2, idx, flag);
  if (t < 256) { gwf1[t] = (f16)ldv(Wf1, t, flag); gwf2[t] = (f16)ldv(Wf2, t, flag); }
  f16* gwn1 = (f16*)(ws + WS_GWN1);
  f16* gwn2 = (f16*)(ws + WS_GWN2);
  for (int idx = t; idx < 8192; idx += STR) gwn1[idx] = (f16)ldv(Wn1, idx, flag);
  for (int idx = t; idx < 4096; idx += STR) gwn2[idx] = (f16)ldv(Wn2, idx, flag);
  if (t < 64)  ws[WS_BN1 + t] = ldv(bn1, t, flag);
  if (t >= 64 && t < 128) ws[WS_BN2 + t - 64] = ldv(bn2, t - 64, flag);
  if (t >= 128 && t < 192) ws[WS_BIAS + t - 128] = ldv(be2, t - 128, flag);
  if (t >= 192 && t < 224) ws[WS_BIAS + 64 + t - 192] = ldv(bc2, t - 192, flag);
  if (t >= 224 && t < 240) ws[WS_BIAS + 96 + t - 224] = ldv(bf1, t - 224, flag);
  if (t >= 240 && t < 256) ws[WS_BIAS + 112 + t - 240] = ldv(bf2, t - 240, flag);
}

// ---------------- K0b: layer-1 MFMA GEMM -> HA/HBJ/ATT (160 x 256) ----------
// h staged through LDS (coalesced + bf16->f16 convert inline; no h16 round-trip).
__global__ __launch_bounds__(256) void k_gemm(const void* __restrict__ h,
                                              float* __restrict__ ws,
                                              void* __restrict__ outv) {
  const int flag = ((const int*)ws)[WS_FLAG];
  const int nt = blockIdx.x / 5, grp = blockIdx.x % 5;
  const int tid = threadIdx.x, w = tid >> 6, lane = tid & 63;
  const int q = lane >> 4, l15 = lane & 15;
  f16* HA16 = scratchHA(outv, flag);
  f16* HBJ  = HA16 + 2048 * 192;
  __shared__ __align__(16) f16 sW[80 * 68];
  __shared__ __align__(16) f16 sH[64 * 68];
  __shared__ float sBias[80];
  const u32* gw1 = (const u32*)(ws + WS_GW1);
  for (int idx = tid; idx < 2720; idx += 256) {
    const int r = idx / 34, c = idx - r * 34;
    *(u32*)&sW[r * 68 + c * 2] = gw1[(grp * 80 + r) * 34 + c];
  }
  const int hbase = nt * 64 * 64;
  for (int e = tid; e < 4096; e += 256)
    sH[(e >> 6) * 68 + (e & 63)] = (f16)ldv(h, hbase + e, flag);
  if (tid < 80) sBias[tid] = ws[WS_B400 + grp * 80 + tid];
  __syncthreads();
  f16x4 Af[4];
#pragma unroll
  for (int ks = 0; ks < 4; ++ks)
    Af[ks] = *(const f16x4*)&sH[(w * 16 + l15) * 68 + ks * 16 + q * 4];
#pragma unroll
  for (int ot = 0; ot < 5; ++ot) {
    const float bv = sBias[ot * 16 + l15];
    f32x4 acc = (f32x4){bv, bv, bv, bv};
#pragma unroll
    for (int ks = 0; ks < 4; ++ks) {
      const f16x4 Bf = *(const f16x4*)&sW[(ot * 16 + l15) * 68 + ks * 16 + q * 4];
      acc = __builtin_amdgcn_mfma_f32_16x16x16f16(Af[ks], Bf, acc, 0, 0, 0);
    }
    const int out = grp * 80 + ot * 16 + l15;
    const int nodeD = nt * 64 + w * 16 + q * 4;
#pragma unroll
    for (int r = 0; r < 4; ++r) {
      const int node = nodeD + r;
      if (out < 192)      HA16[node * 192 + out] = (f16)acc[r];
      else if (out < 384) HBJ[node * 192 + out - 192] = (f16)acc[r];
      else                ws[WS_ATT + node * 16 + out - 384] = fmaxf(acc[r], 0.f);
    }
  }
}

// ---------------- K1: MFMA edge kernel (2048 blocks x 256) ------------------
// XCD swizzle (b = blk&7). Single mid-kernel barrier: agg partials ride in
// registers; agg+cacc cross-wave sums happen together at the end.
__global__ __launch_bounds__(256, 3) void k_edge(const void* __restrict__ cat,
                                                 float* __restrict__ ws,
                                                 void* __restrict__ outv) {
  const int node = ((blockIdx.x & 7) << 8) | (blockIdx.x >> 3);
  const int b = node >> 8, i = node & 255;
  const int tid = threadIdx.x;
  const int w = tid >> 6, lane = tid & 63, q = lane >> 4, l15 = lane & 15;
  const int flag = ((const int*)ws)[WS_FLAG];
  const f16* HA16 = scratchHA(outv, flag);
  const f16* HBJ  = HA16 + 2048 * 192;
  const float* __restrict__ cTb = ws + WS_CT + b * 48 * 256;

  __shared__ __align__(16) f16 sWd[192 * 20];
  __shared__ __align__(16) f16 sWe2[64 * 76];
  __shared__ __align__(16) f16 sWc2[32 * 76];
  __shared__ __align__(16) f16 sWf1[16 * 20];
  __shared__ __align__(16) f16 sWf2[16 * 20];
  __shared__ __align__(16) f16 distS[256 * 20];
  __shared__ float sHa[192];
  __shared__ float sB[128];
  __shared__ __align__(16) float red[448];  // [0,256) agg, [256,448) cacc

  {  // stage weight tables
    const u32* gwd = (const u32*)(ws + WS_GWD);
    for (int idx = tid; idx < 1536; idx += 256) {
      const int r = idx >> 3, c = idx & 7;
      *(u32*)&sWd[r * 20 + c * 2] = gwd[idx];
    }
    const u32* gwe = (const u32*)(ws + WS_GWE2);
    for (int idx = tid; idx < 2048; idx += 256) {
      const int r = idx >> 5, c = idx & 31;
      *(u32*)&sWe2[r * 76 + c * 2] = gwe[idx];
    }
    const u32* gwc = (const u32*)(ws + WS_GWC2);
    for (int idx = tid; idx < 1024; idx += 256) {
      const int r = idx >> 5, c = idx & 31;
      *(u32*)&sWc2[r * 76 + c * 2] = gwc[idx];
    }
    if (tid < 128) {
      const int r = tid >> 3, c = tid & 7;
      *(u32*)&sWf1[r * 20 + c * 2] = ((const u32*)(ws + WS_GWF1))[tid];
      *(u32*)&sWf2[r * 20 + c * 2] = ((const u32*)(ws + WS_GWF2))[tid];
    }
    if (tid < 192) sHa[tid] = (float)HA16[node * 192 + tid];
    if (tid < 128) sB[tid] = ws[WS_BIAS + tid];
  }
  {  // distances
    float dr[16];
#pragma unroll
    for (int c = 0; c < 16; ++c) {
      float s = 0.f;
#pragma unroll
      for (int d = 0; d < 3; ++d) {
        const int cd = c * 3 + d;
        const float df = cTb[cd * 256 + i] - cTb[cd * 256 + tid];
        s += df * df;
      }
      dr[c] = sqrtf(s);
    }
#pragma unroll
    for (int kk = 0; kk < 4; ++kk)
      *(f16x4*)&distS[tid * 20 + kk * 4] =
          pack4(dr[4 * kk], dr[4 * kk + 1], dr[4 * kk + 2], dr[4 * kk + 3]);
  }
  __syncthreads();

  int jj[4]; float mjt[4]; f16x4 dfr[4];
#pragma unroll
  for (int jt = 0; jt < 4; ++jt) {
    jj[jt] = w * 64 + jt * 16 + l15;
    mjt[jt] = (jj[jt] == i) ? 0.f : 1.f;
    dfr[jt] = *(const f16x4*)&distS[jj[jt] * 20 + q * 4];
  }

  // ---- phase 1: e2 GEMM chain, C2[f][j] over K=64 ----
  f32x4 C2[4][4];
#pragma unroll
  for (int ft = 0; ft < 4; ++ft)
#pragma unroll
    for (int jt = 0; jt < 4; ++jt) C2[ft][jt] = (f32x4){0.f, 0.f, 0.f, 0.f};
#pragma unroll
  for (int og = 0; og < 4; ++og) {
    const f16x4 wd = *(const f16x4*)&sWd[(og * 16 + l15) * 20 + q * 4];
    f16x4 af[4];
#pragma unroll
    for (int jt = 0; jt < 4; ++jt) {
      const f16x4 hb = *(const f16x4*)(HBJ + (b * 256 + jj[jt]) * 192 + og * 16 + q * 4);
      f32x4 a;
#pragma unroll
      for (int r = 0; r < 4; ++r) a[r] = sHa[og * 16 + q * 4 + r] + (float)hb[r];
      a = __builtin_amdgcn_mfma_f32_16x16x16f16(wd, dfr[jt], a, 0, 0, 0);
      af[jt] = pack4(fmaxf(a[0], 0.f), fmaxf(a[1], 0.f), fmaxf(a[2], 0.f), fmaxf(a[3], 0.f));
    }
#pragma unroll
    for (int ft = 0; ft < 4; ++ft) {
      const f16x4 we = *(const f16x4*)&sWe2[(ft * 16 + l15) * 76 + og * 16 + q * 4];
#pragma unroll
      for (int jt = 0; jt < 4; ++jt)
        C2[ft][jt] = __builtin_amdgcn_mfma_f32_16x16x16f16(we, af[jt], C2[ft][jt], 0, 0, 0);
    }
  }
  // per-wave agg partials -> registers (all-reduce butterfly over 16 lanes)
  float sagg[4][4];
#pragma unroll
  for (int ft = 0; ft < 4; ++ft) {
#pragma unroll
    for (int r = 0; r < 4; ++r) {
      float s = 0.f;
#pragma unroll
      for (int jt = 0; jt < 4; ++jt)
        s += fmaxf(C2[ft][jt][r] + sB[ft * 16 + q * 4 + r], 0.f) * mjt[jt];
      sagg[ft][r] = s;
    }
#pragma unroll
    for (int st = 1; st < 16; st <<= 1)
#pragma unroll
      for (int r = 0; r < 4; ++r) sagg[ft][r] += __shfl_xor(sagg[ft][r], st, 64);
  }

  // ---- phase 2: category chains -> factors ----
  float fac[4][4] = {};
#pragma unroll
  for (int m = 0; m < 2; ++m) {
    float cv[4];
#pragma unroll
    for (int jt = 0; jt < 4; ++jt) {
      if (flag) {
        const u32 p = ((const u32*)cat)[node * 256 + jj[jt]];
        cv[jt] = bfld((u16)(m ? (p >> 16) : (p & 0xFFFFu)));
      } else {
        cv[jt] = ((const float*)cat)[(node * 256 + jj[jt]) * 2 + m];
      }
    }
    f32x4 C3[4];
#pragma unroll
    for (int jt = 0; jt < 4; ++jt) C3[jt] = (f32x4){0.f, 0.f, 0.f, 0.f};
#pragma unroll
    for (int og2 = 0; og2 < 4; ++og2) {
      const int og = 4 + m * 4 + og2;
      const f16x4 wd = *(const f16x4*)&sWd[(og * 16 + l15) * 20 + q * 4];
      const f16x4 wc = *(const f16x4*)&sWc2[(m * 16 + l15) * 76 + og2 * 16 + q * 4];
#pragma unroll
      for (int jt = 0; jt < 4; ++jt) {
        const f16x4 hb = *(const f16x4*)(HBJ + (b * 256 + jj[jt]) * 192 + og * 16 + q * 4);
        f32x4 a;
#pragma unroll
        for (int r = 0; r < 4; ++r) a[r] = sHa[og * 16 + q * 4 + r] + (float)hb[r];
        a = __builtin_amdgcn_mfma_f32_16x16x16f16(wd, dfr[jt], a, 0, 0, 0);
        const f16x4 af = pack4(fmaxf(a[0], 0.f), fmaxf(a[1], 0.f),
                               fmaxf(a[2], 0.f), fmaxf(a[3], 0.f));
        C3[jt] = __builtin_amdgcn_mfma_f32_16x16x16f16(wc, af, C3[jt], 0, 0, 0);
      }
    }
#pragma unroll
    for (int jt = 0; jt < 4; ++jt)
#pragma unroll
      for (int r = 0; r < 4; ++r)
        fac[jt][r] += cv[jt] * fmaxf(C3[jt][r] + sB[64 + m * 16 + q * 4 + r], 0.f);
  }

  // ---- factors MLP ----
  const f16x4 w1 = *(const f16x4*)&sWf1[l15 * 20 + q * 4];
  const f16x4 w2 = *(const f16x4*)&sWf2[l15 * 20 + q * 4];
  float ffv[4][4];
#pragma unroll
  for (int jt = 0; jt < 4; ++jt) {
    const f16x4 fF = pack4(fac[jt][0], fac[jt][1], fac[jt][2], fac[jt][3]);
    const f32x4 z = {0.f, 0.f, 0.f, 0.f};
    f32x4 G = __builtin_amdgcn_mfma_f32_16x16x16f16(w1, fF, z, 0, 0, 0);
    const f16x4 gF = pack4(fmaxf(G[0] + sB[96 + q * 4 + 0], 0.f),
                           fmaxf(G[1] + sB[96 + q * 4 + 1], 0.f),
                           fmaxf(G[2] + sB[96 + q * 4 + 2], 0.f),
                           fmaxf(G[3] + sB[96 + q * 4 + 3], 0.f));
    f32x4 F2 = __builtin_amdgcn_mfma_f32_16x16x16f16(w2, gF, z, 0, 0, 0);
#pragma unroll
    for (int r = 0; r < 4; ++r) ffv[jt][r] = fmaxf(F2[r] + sB[112 + q * 4 + r], 0.f);
  }

  // ---- coord aggregation ----
  float civ[12];
#pragma unroll
  for (int r = 0; r < 4; ++r)
#pragma unroll
    for (int d = 0; d < 3; ++d) civ[r * 3 + d] = cTb[(3 * (q * 4 + r) + d) * 256 + i];
  float ca[12] = {};
#pragma unroll
  for (int jt = 0; jt < 4; ++jt)
#pragma unroll
    for (int r = 0; r < 4; ++r) {
      const float fv = ffv[jt][r];
#pragma unroll
      for (int d = 0; d < 3; ++d) {
        const float cj = cTb[(3 * (q * 4 + r) + d) * 256 + jj[jt]];
        ca[r * 3 + d] += fv * (civ[r * 3 + d] - cj);
      }
    }
#pragma unroll
  for (int st = 1; st < 16; st <<= 1)
#pragma unroll
    for (int u = 0; u < 12; ++u) ca[u] += __shfl_xor(ca[u], st, 64);

  // ---- single combined block reduction ----
  if (l15 == 0) {
#pragma unroll
    for (int ft = 0; ft < 4; ++ft)
#pragma unroll
      for (int r = 0; r < 4; ++r) red[w * 64 + ft * 16 + q * 4 + r] = sagg[ft][r];
#pragma unroll
    for (int u = 0; u < 12; ++u) red[256 + w * 48 + q * 12 + u] = ca[u];
  }
  __syncthreads();
  if (tid < 64) {
    ws[WS_AGG + node * 64 + tid] = red[tid] + red[64 + tid] + red[128 + tid] + red[192 + tid];
  } else if (tid < 112) {
    const int u = tid - 64;
    ws[WS_CAC + node * 48 + u] =
        red[256 + u] + red[256 + 48 + u] + red[256 + 96 + u] + red[256 + 144 + u];
  }
}

// ---------------- K2: fused epilogue (552 x 256) ----------------------------
// blk 0..31: node model (MFMA); 32..39: coord pipeline; 40..551: copycat.
__global__ __launch_bounds__(256) void k_epi(const void* __restrict__ h,
                                             const void* __restrict__ coord,
                                             const void* __restrict__ vel,
                                             const void* __restrict__ cat,
                                             const void* __restrict__ Wcv,
                                             const void* __restrict__ Wql,
                                             const void* __restrict__ Wkl,
                                             const float* __restrict__ ws,
                                             void* __restrict__ outv) {
  const int blk = blockIdx.x, tid = threadIdx.x;
  const int flag = ((const int*)ws)[WS_FLAG];
  if (blk < 32) {  // ---- node model: 64 nodes/block, chained MFMA GEMMs ----
    const int w = tid >> 6, lane = tid & 63;
    const int q = lane >> 4, l15 = lane & 15;
    __shared__ __align__(16) f16 sW1[64 * 132];
    __shared__ __align__(16) f16 sW2[64 * 68];
    __shared__ __align__(16) f16 sH[64 * 68];
    __shared__ float sbn[128];
    {
      const u32* g1 = (const u32*)(ws + WS_GWN1);
      for (int idx = tid; idx < 4096; idx += 256) {
        const int o = idx >> 6, c = idx & 63;
        *(u32*)&sW1[o * 132 + c * 2] = g1[idx];
      }
      const u32* g2 = (const u32*)(ws + WS_GWN2);
      for (int idx = tid; idx < 2048; idx += 256) {
        const int o = idx >> 5, c = idx & 31;
        *(u32*)&sW2[o * 68 + c * 2] = g2[idx];
      }
      const int hbase = blk * 64 * 64;
      for (int e = tid; e < 4096; e += 256)
        sH[(e >> 6) * 68 + (e & 63)] = (f16)ldv(h, hbase + e, flag);
      if (tid < 128) sbn[tid] = (tid < 64) ? ws[WS_BN1 + tid] : ws[WS_BN2 + tid - 64];
    }
    __syncthreads();
    const int node = blk * 64 + w * 16 + l15;
    const int lrow = w * 16 + l15;
    f16x4 xB[8];
#pragma unroll
    for (int kt = 0; kt < 4; ++kt)
      xB[kt] = *(const f16x4*)&sH[lrow * 68 + kt * 16 + q * 4];
#pragma unroll
    for (int kt = 0; kt < 4; ++kt) {
      const float* ap = ws + WS_AGG + node * 64 + kt * 16 + q * 4;
      xB[4 + kt] = pack4(ap[0], ap[1], ap[2], ap[3]);
    }
    f16x4 hidB[4];
#pragma unroll
    for (int ot = 0; ot < 4; ++ot) {
      f32x4 acc;
#pragma unroll
      for (int r = 0; r < 4; ++r) acc[r] = sbn[ot * 16 + q * 4 + r];
#pragma unroll
      for (int kt = 0; kt < 8; ++kt) {
        const f16x4 a = *(const f16x4*)&sW1[(ot * 16 + l15) * 132 + kt * 16 + q * 4];
        acc = __builtin_amdgcn_mfma_f32_16x16x16f16(a, xB[kt], acc, 0, 0, 0);
      }
      hidB[ot] = pack4(fmaxf(acc[0], 0.f), fmaxf(acc[1], 0.f),
                       fmaxf(acc[2], 0.f), fmaxf(acc[3], 0.f));
    }
#pragma unroll
    for (int ft = 0; ft < 4; ++ft) {
      const f16x4 hl = *(const f16x4*)&sH[lrow * 68 + ft * 16 + q * 4];
      f32x4 acc;
#pragma unroll
      for (int r = 0; r < 4; ++r) acc[r] = sbn[64 + ft * 16 + q * 4 + r] + (float)hl[r];
#pragma unroll
      for (int ot = 0; ot < 4; ++ot) {
        const f16x4 a = *(const f16x4*)&sW2[(ft * 16 + l15) * 68 + ot * 16 + q * 4];
        acc = __builtin_amdgcn_mfma_f32_16x16x16f16(a, hidB[ot], acc, 0, 0, 0);
      }
#pragma unroll
      for (int r = 0; r < 4; ++r)
        stv(outv, node * 64 + ft * 16 + q * 4 + r, acc[r], flag);
    }
  } else if (blk < 40) {  // ---- coord pipeline, b = blk-32 ----
    const int b = blk - 32;
    const int n = tid, node = b * 256 + n;
    const int wave = n >> 6, lane = n & 63;
    __shared__ float wcv[256], wql[256], wkl[256];
    __shared__ float redm[16];
    wcv[n] = ldv(Wcv, n, flag);
    wql[n] = ldv(Wql, n, flag);
    wkl[n] = ldv(Wkl, n, flag);
    float cf[48];
    load48(coord, node, flag, cf);
    float s0 = 0.f, s1 = 0.f, s2 = 0.f;
#pragma unroll
    for (int c = 0; c < 16; ++c) { s0 += cf[c*3]; s1 += cf[c*3+1]; s2 += cf[c*3+2]; }
    for (int s = 1; s < 64; s <<= 1) {
      s0 += __shfl_xor(s0, s, 64); s1 += __shfl_xor(s1, s, 64); s2 += __shfl_xor(s2, s, 64);
    }
    if (lane == 0) { redm[wave*4] = s0; redm[wave*4+1] = s1; redm[wave*4+2] = s2; }
    __syncthreads();
    const float m0 = (redm[0]+redm[4]+redm[8]+redm[12]) * (1.f/4096.f);
    const float m1 = (redm[1]+redm[5]+redm[9]+redm[13]) * (1.f/4096.f);
    const float m2 = (redm[2]+redm[6]+redm[10]+redm[14]) * (1.f/4096.f);
    __syncthreads();
    float velf[48];
    load48(vel, node, flag, velf);
    float att[16];
    {
      const float4* ap = (const float4*)(ws + WS_ATT + node * 16);
#pragma unroll
      for (int c4 = 0; c4 < 4; ++c4) {
        const float4 v = ap[c4];
        att[c4*4] = v.x; att[c4*4+1] = v.y; att[c4*4+2] = v.z; att[c4*4+3] = v.w;
      }
    }
    float cac[48];
    {
      const float4* cp = (const float4*)(ws + WS_CAC + node * 48);
#pragma unroll
      for (int c4 = 0; c4 < 12; ++c4) {
        const float4 v = cp[c4];
        cac[c4*4] = v.x; cac[c4*4+1] = v.y; cac[c4*4+2] = v.z; cac[c4*4+3] = v.w;
      }
    }
    float c3[48];
#pragma unroll
    for (int c = 0; c < 16; ++c) {
      const float at = att[c];
#pragma unroll
      for (int d = 0; d < 3; ++d) {
        const int cd = c * 3 + d;
        const float md = (d == 0) ? m0 : ((d == 1) ? m1 : m2);
        float cc = at * (cf[cd] - md) + cf[cd];
        cc += cac[cd];
        float a = cc;
#pragma unroll
        for (int cp = 0; cp < 16; ++cp) a += velf[cp * 3 + d] * wcv[c * 16 + cp];
        c3[cd] = a;
      }
    }
    float t0 = 0.f, t1 = 0.f, t2 = 0.f;
#pragma unroll
    for (int c = 0; c < 16; ++c) { t0 += c3[c*3]; t1 += c3[c*3+1]; t2 += c3[c*3+2]; }
    for (int s = 1; s < 64; s <<= 1) {
      t0 += __shfl_xor(t0, s, 64); t1 += __shfl_xor(t1, s, 64); t2 += __shfl_xor(t2, s, 64);
    }
    if (lane == 0) { redm[wave*4] = t0; redm[wave*4+1] = t1; redm[wave*4+2] = t2; }
    __syncthreads();
    const float cm0 = (redm[0]+redm[4]+redm[8]+redm[12]) * (1.f/4096.f);
    const float cm1 = (redm[1]+redm[5]+redm[9]+redm[13]) * (1.f/4096.f);
    const float cm2 = (redm[2]+redm[6]+redm[10]+redm[14]) * (1.f/4096.f);
    float cc[48];
#pragma unroll
    for (int c = 0; c < 16; ++c) {
      cc[c*3]   = c3[c*3]   - cm0;
      cc[c*3+1] = c3[c*3+1] - cm1;
      cc[c*3+2] = c3[c*3+2] - cm2;
    }
#pragma unroll
    for (int o = 0; o < 16; ++o) {
      float qv[3], kv[3];
#pragma unroll
      for (int d = 0; d < 3; ++d) {
        float sq = 0.f, sk = 0.f;
#pragma unroll
        for (int cp = 0; cp < 16; ++cp) {
          sq += cc[cp * 3 + d] * wql[o * 16 + cp];
          sk += cc[cp * 3 + d] * wkl[o * 16 + cp];
        }
        qv[d] = sq; kv[d] = sk;
      }
      const float prod = qv[0]*kv[0] + qv[1]*kv[1] + qv[2]*kv[2];
      const float kns  = kv[0]*kv[0] + kv[1]*kv[1] + kv[2]*kv[2];
      const float wq = prod / (kns + EPSV);
#pragma unroll
      for (int d = 0; d < 3; ++d) {
        const float cmd = (d == 0) ? cm0 : ((d == 1) ? cm1 : cm2);
        const float val = (prod >= 0.f) ? qv[d] : (qv[d] - wq * kv[d]);
        stv(outv, 131072 + node * 48 + o * 3 + d, val + cmd, flag);
      }
    }
  } else {  // ---- category passthrough (overwrites scratch; no reader left) ----
    const int idx = (blk - 40) * 256 + tid;  // 131072 total
    if (flag) {
      ((uint4*)((char*)outv + 458752))[idx] = ((const uint4*)cat)[idx];
    } else {
      ((uint4*)((char*)outv + 917504))[idx] = ((const uint4*)cat)[idx];
      ((uint4*)((char*)outv + 917504))[idx + 131072] = ((const uint4*)cat)[idx + 131072];
    }
  }
}

// ---------------- launch ----------------------------------------------------
extern "C" void kernel_launch(void* const* d_in, const int* in_sizes, int n_in,
                              void* d_out, int out_size, void* d_ws, size_t ws_size,
                              hipStream_t stream) {
  (void)in_sizes; (void)n_in; (void)out_size; (void)ws_size;
  const void* h    = d_in[0];
  const void* coord= d_in[1];
  const void* vel  = d_in[2];
  const void* cat  = d_in[3];
  const void* Wcv  = d_in[4];
  const void* We1  = d_in[5];
  const void* be1  = d_in[6];
  const void* We2  = d_in[7];
  const void* be2  = d_in[8];
  const void* Wc1  = d_in[9];
  const void* bc1  = d_in[10];
  const void* Wc2  = d_in[11];
  const void* bc2  = d_in[12];
  const void* Wf1  = d_in[13];
  const void* bf1v = d_in[14];
  const void* Wf2  = d_in[15];
  const void* bf2v = d_in[16];
  const void* Wn1  = d_in[17];
  const void* bn1  = d_in[18];
  const void* Wn2  = d_in[19];
  const void* bn2  = d_in[20];
  const void* Wql  = d_in[21];
  const void* Wkl  = d_in[22];
  const void* Wqm  = d_in[23];
  const void* bqm  = d_in[24];
  float* ws = (float*)d_ws;

  k_prep_w<<<256, 256, 0, stream>>>(h, coord, We1, Wc1, We2, Wc2, Wf1, Wf2,
                                    Wn1, Wn2, Wqm, be1, bc1, bqm, be2, bc2,
                                    bf1v, bf2v, bn1, bn2, ws);
  k_gemm<<<160, 256, 0, stream>>>(h, ws, d_out);
  k_edge<<<2048, 256, 0, stream>>>(cat, ws, d_out);
  k_epi<<<552, 256, 0, stream>>>(h, coord, vel, cat, Wcv, Wql, Wkl, ws, d_out);
}

// Round 17
// 195.084 us; speedup vs baseline: 1.9115x; 1.0937x over previous
//
#include <hip/hip_runtime.h>

typedef unsigned short u16;
typedef unsigned int u32;
typedef _Float16 f16;
typedef __attribute__((ext_vector_type(2))) _Float16 f16x2;
typedef __attribute__((ext_vector_type(4))) _Float16 f16x4;
typedef __attribute__((ext_vector_type(4))) float f32x4;

// Problem constants: B=8, N=256, F=64, C=16, K=2
#define EPSV 1e-4f

// Output element offsets: h_out [0,131072) coord_out [131072,229376) category [229376,1277952)
// Category out-region is scratch: HA[2048*192] | HBJ[8][48][256][4] (f16) until
// the epilogue's copycat blocks overwrite it (only k_edge reads scratch).
// HBJ is K-MAJOR: element (b, j, o') lives at ((b*48 + (o'>>4)*4 + ((o'&15)>>2))*256 + j)*4 + (o'&3)
// so a 16-lane MFMA quad load (consecutive j, fixed o'-quad) is one 128B transaction.

// ---------------- ws layout (fp32 slots) -----------------------------------
// HARD CAP: max offset <= 391872 (round 9 overflow corrupted adjacent alloc).
// f16 tables: slot count = f16_elements / 2 (round 12 aliasing bug).
static constexpr int WS_FLAG = 0;                     // +16
static constexpr int WS_ATT  = 16;                    // [2048][16]
static constexpr int WS_CT   = 32784;                 // [8][48][256] coord^T fp32
static constexpr int WS_AGG  = 131088;                // [2048][64]
static constexpr int WS_CAC  = 262160;                // [2048][48]  (ends 360464)
static constexpr int WS_GWN1 = 360464;                // f16 [64 o][128 k] = 4096 slots (ends 364560)
static constexpr int WS_GWN2 = 364560;                // f16 [64 f][64 o]  = 2048 slots (ends 366608)
static constexpr int WS_BN1  = 372752;                // [64]
static constexpr int WS_BN2  = 372816;                // [64]
static constexpr int WS_BIAS = 372880;                // be2[64]|bc2[32]|bf1[16]|bf2[16]
static constexpr int WS_GWD  = 373008;                // f16 [192 o'][16 c]   (1536 slots)
static constexpr int WS_GWE2 = 374544;                // f16 [64 f][64 o]     (2048)
static constexpr int WS_GWC2 = 376592;                // f16 [32 mc][64 o]    (1024)
static constexpr int WS_GWF1 = 377616;                // f16 [16][16]         (128)
static constexpr int WS_GWF2 = 377744;                // f16 [16][16]         (128)
static constexpr int WS_GW1  = 377872;                // f16 [400 out][68 k]  (13600 slots)
static constexpr int WS_B400 = 391472;                // [400] layer-1 bias (ends 391872)

static __device__ __forceinline__ float bfld(u16 v) {
  return __uint_as_float(((unsigned)v) << 16);
}
static __device__ __forceinline__ u16 f2b(float x) {  // RNE
  unsigned u = __float_as_uint(x);
  u += 0x7FFFu + ((u >> 16) & 1u);
  return (u16)(u >> 16);
}
static __device__ __forceinline__ float ldv(const void* p, int i, int flag) {
  return flag ? bfld(((const u16*)p)[i]) : ((const float*)p)[i];
}
static __device__ __forceinline__ void stv(void* p, int i, float v, int flag) {
  if (flag) ((u16*)p)[i] = f2b(v);
  else      ((float*)p)[i] = v;
}
static __device__ __forceinline__ f16* scratchHA(void* outv, int flag) {
  return (f16*)((char*)outv + (size_t)229376 * (flag ? 2 : 4));
}
static __device__ __forceinline__ int sniff_flag(const void* h) {
  const u16* hu = (const u16*)h;
  int cnt = 0;
  for (int i = 0; i < 128; ++i) {
    unsigned e = (hu[i] >> 7) & 0xFFu;
    if ((e >= 100u && e <= 150u) || hu[i] == 0) ++cnt;
  }
  return (cnt >= 112) ? 1 : 0;
}
static __device__ __forceinline__ f16x4 pack4(float a, float b, float c, float d) {
  const f16x2 lo = __builtin_bit_cast(f16x2, __builtin_amdgcn_cvt_pkrtz(a, b));
  const f16x2 hi = __builtin_bit_cast(f16x2, __builtin_amdgcn_cvt_pkrtz(c, d));
  f16x4 r; r[0] = lo[0]; r[1] = lo[1]; r[2] = hi[0]; r[3] = hi[1]; return r;
}
// 48 contiguous input elements -> fp32, vectorized
static __device__ __forceinline__ void load48(const void* p, int node, int flag,
                                              float* dst) {
  if (flag) {
    const uint4* q4 = (const uint4*)((const u16*)p + node * 48);
#pragma unroll
    for (int c = 0; c < 6; ++c) {
      const uint4 v = q4[c];
      const u32 a[4] = {v.x, v.y, v.z, v.w};
#pragma unroll
      for (int e = 0; e < 4; ++e) {
        dst[c * 8 + e * 2]     = bfld((u16)(a[e] & 0xFFFFu));
        dst[c * 8 + e * 2 + 1] = bfld((u16)(a[e] >> 16));
      }
    }
  } else {
    const float4* q4 = (const float4*)((const float*)p + node * 48);
#pragma unroll
    for (int c = 0; c < 12; ++c) {
      const float4 v = q4[c];
      dst[c * 4] = v.x; dst[c * 4 + 1] = v.y; dst[c * 4 + 2] = v.z; dst[c * 4 + 3] = v.w;
    }
  }
}

// ---------------- K0: table builds, fully parallel (256 x 256) --------------
__global__ __launch_bounds__(256) void k_prep_w(
    const void* __restrict__ h, const void* __restrict__ coord,
    const void* __restrict__ We1, const void* __restrict__ Wc1,
    const void* __restrict__ We2, const void* __restrict__ Wc2,
    const void* __restrict__ Wf1, const void* __restrict__ Wf2,
    const void* __restrict__ Wn1, const void* __restrict__ Wn2,
    const void* __restrict__ Wqm,
    const void* __restrict__ be1, const void* __restrict__ bc1,
    const void* __restrict__ bqm, const void* __restrict__ be2,
    const void* __restrict__ bc2, const void* __restrict__ bf1,
    const void* __restrict__ bf2, const void* __restrict__ bn1,
    const void* __restrict__ bn2,
    float* __restrict__ ws) {
  const int t = blockIdx.x * 256 + threadIdx.x;
  const int STR = 65536;
  __shared__ int sflag;
  if (threadIdx.x == 0) {
    sflag = sniff_flag(h);
    if (blockIdx.x == 0) ((int*)ws)[WS_FLAG] = sflag;
  }
  __syncthreads();
  const int flag = sflag;

  // GW1: stacked layer-1 weights as [400 out][68 k] f16
  f16* gw1 = (f16*)(ws + WS_GW1);
  for (int idx = t; idx < 25600; idx += STR) {
    const int row = idx >> 6, k = idx & 63;
    float v;
    if (row < 64)       v = ldv(We1, row * 144 + k, flag);
    else if (row < 192) v = ldv(Wc1, (row - 64) * 144 + k, flag);
    else if (row < 384) {
      const int ro = row - 192;
      v = (ro < 64) ? ldv(We1, ro * 144 + 64 + k, flag)
                    : ldv(Wc1, (ro - 64) * 144 + 64 + k, flag);
    } else              v = ldv(Wqm, (row - 384) * 64 + k, flag);
    gw1[row * 68 + k] = (f16)v;
  }
  if (t < 400) {
    float v = (t < 64) ? ldv(be1, t, flag)
            : (t < 192) ? ldv(bc1, t - 64, flag)
            : (t < 384) ? 0.f : ldv(bqm, t - 384, flag);
    ws[WS_B400 + t] = v;
  }
  for (int idx = t; idx < 98304; idx += STR) {  // coord^T [b][cd][n]
    const int bq = idx / 12288, rem = idx - bq * 12288;
    const int cd = rem >> 8, n = rem & 255;
    ws[WS_CT + idx] = ldv(coord, (bq * 256 + n) * 48 + cd, flag);
  }
  f16* gwd  = (f16*)(ws + WS_GWD);
  f16* gwe2 = (f16*)(ws + WS_GWE2);
  f16* gwc2 = (f16*)(ws + WS_GWC2);
  f16* gwf1 = (f16*)(ws + WS_GWF1);
  f16* gwf2 = (f16*)(ws + WS_GWF2);
  for (int idx = t; idx < 3072; idx += STR) {  // [o'][c] <- cols 128..143
    const int o = idx >> 4, c = idx & 15;
    const void* src = (o < 64) ? We1 : Wc1;
    const int row = (o < 64) ? o : (o - 64);
    gwd[idx] = (f16)ldv(src, row * 144 + 128 + c, flag);
  }
  for (int idx = t; idx < 4096; idx += STR) gwe2[idx] = (f16)ldv(We2, idx, flag);
  for (int idx = t; idx < 2048; idx += STR) gwc2[idx] = (f16)ldv(Wc2, idx, flag);
  if (t < 256) { gwf1[t] = (f16)ldv(Wf1, t, flag); gwf2[t] = (f16)ldv(Wf2, t, flag); }
  f16* gwn1 = (f16*)(ws + WS_GWN1);
  f16* gwn2 = (f16*)(ws + WS_GWN2);
  for (int idx = t; idx < 8192; idx += STR) gwn1[idx] = (f16)ldv(Wn1, idx, flag);
  for (int idx = t; idx < 4096; idx += STR) gwn2[idx] = (f16)ldv(Wn2, idx, flag);
  if (t < 64)  ws[WS_BN1 + t] = ldv(bn1, t, flag);
  if (t >= 64 && t < 128) ws[WS_BN2 + t - 64] = ldv(bn2, t - 64, flag);
  if (t >= 128 && t < 192) ws[WS_BIAS + t - 128] = ldv(be2, t - 128, flag);
  if (t >= 192 && t < 224) ws[WS_BIAS + 64 + t - 192] = ldv(bc2, t - 192, flag);
  if (t >= 224 && t < 240) ws[WS_BIAS + 96 + t - 224] = ldv(bf1, t - 224, flag);
  if (t >= 240 && t < 256) ws[WS_BIAS + 112 + t - 240] = ldv(bf2, t - 240, flag);
}

// ---------------- K0b: layer-1 MFMA GEMM -> HA/HBJ/ATT (160 x 256) ----------
// h staged through LDS; HBJ written in K-major layout (see header comment).
__global__ __launch_bounds__(256) void k_gemm(const void* __restrict__ h,
                                              float* __restrict__ ws,
                                              void* __restrict__ outv) {
  const int flag = ((const int*)ws)[WS_FLAG];
  const int nt = blockIdx.x / 5, grp = blockIdx.x % 5;
  const int tid = threadIdx.x, w = tid >> 6, lane = tid & 63;
  const int q = lane >> 4, l15 = lane & 15;
  f16* HA16 = scratchHA(outv, flag);
  f16* HBJ  = HA16 + 2048 * 192;
  __shared__ __align__(16) f16 sW[80 * 68];
  __shared__ __align__(16) f16 sH[64 * 68];
  __shared__ float sBias[80];
  const u32* gw1 = (const u32*)(ws + WS_GW1);
  for (int idx = tid; idx < 2720; idx += 256) {
    const int r = idx / 34, c = idx - r * 34;
    *(u32*)&sW[r * 68 + c * 2] = gw1[(grp * 80 + r) * 34 + c];
  }
  const int hbase = nt * 64 * 64;
  for (int e = tid; e < 4096; e += 256)
    sH[(e >> 6) * 68 + (e & 63)] = (f16)ldv(h, hbase + e, flag);
  if (tid < 80) sBias[tid] = ws[WS_B400 + grp * 80 + tid];
  __syncthreads();
  f16x4 Af[4];
#pragma unroll
  for (int ks = 0; ks < 4; ++ks)
    Af[ks] = *(const f16x4*)&sH[(w * 16 + l15) * 68 + ks * 16 + q * 4];
#pragma unroll
  for (int ot = 0; ot < 5; ++ot) {
    const float bv = sBias[ot * 16 + l15];
    f32x4 acc = (f32x4){bv, bv, bv, bv};
#pragma unroll
    for (int ks = 0; ks < 4; ++ks) {
      const f16x4 Bf = *(const f16x4*)&sW[(ot * 16 + l15) * 68 + ks * 16 + q * 4];
      acc = __builtin_amdgcn_mfma_f32_16x16x16f16(Af[ks], Bf, acc, 0, 0, 0);
    }
    const int out = grp * 80 + ot * 16 + l15;
    const int nodeD = nt * 64 + w * 16 + q * 4;
#pragma unroll
    for (int r = 0; r < 4; ++r) {
      const int node = nodeD + r;
      if (out < 192) {
        HA16[node * 192 + out] = (f16)acc[r];
      } else if (out < 384) {
        const int ol = out - 192;  // K-major HBJ
        HBJ[(((node >> 8) * 48 + ((ol >> 4) << 2) + ((ol & 15) >> 2)) * 256 +
             (node & 255)) * 4 + (ol & 3)] = (f16)acc[r];
      } else {
        ws[WS_ATT + node * 16 + out - 384] = fmaxf(acc[r], 0.f);
      }
    }
  }
}

// ---------------- K1: MFMA edge kernel (2048 blocks x 256) ------------------
// XCD swizzle (b = blk&7). Single mid-kernel barrier. K-major HBJ loads:
// one 128B coalesced transaction per 16-lane quad.
__global__ __launch_bounds__(256, 3) void k_edge(const void* __restrict__ cat,
                                                 float* __restrict__ ws,
                                                 void* __restrict__ outv) {
  const int node = ((blockIdx.x & 7) << 8) | (blockIdx.x >> 3);
  const int b = node >> 8, i = node & 255;
  const int tid = threadIdx.x;
  const int w = tid >> 6, lane = tid & 63, q = lane >> 4, l15 = lane & 15;
  const int flag = ((const int*)ws)[WS_FLAG];
  const f16* HA16 = scratchHA(outv, flag);
  const f16* HBJ  = HA16 + 2048 * 192;
  const float* __restrict__ cTb = ws + WS_CT + b * 48 * 256;

  __shared__ __align__(16) f16 sWd[192 * 20];
  __shared__ __align__(16) f16 sWe2[64 * 76];
  __shared__ __align__(16) f16 sWc2[32 * 76];
  __shared__ __align__(16) f16 sWf1[16 * 20];
  __shared__ __align__(16) f16 sWf2[16 * 20];
  __shared__ __align__(16) f16 distS[256 * 20];
  __shared__ float sHa[192];
  __shared__ float sB[128];
  __shared__ __align__(16) float red[448];  // [0,256) agg, [256,448) cacc

  {  // stage weight tables
    const u32* gwd = (const u32*)(ws + WS_GWD);
    for (int idx = tid; idx < 1536; idx += 256) {
      const int r = idx >> 3, c = idx & 7;
      *(u32*)&sWd[r * 20 + c * 2] = gwd[idx];
    }
    const u32* gwe = (const u32*)(ws + WS_GWE2);
    for (int idx = tid; idx < 2048; idx += 256) {
      const int r = idx >> 5, c = idx & 31;
      *(u32*)&sWe2[r * 76 + c * 2] = gwe[idx];
    }
    const u32* gwc = (const u32*)(ws + WS_GWC2);
    for (int idx = tid; idx < 1024; idx += 256) {
      const int r = idx >> 5, c = idx & 31;
      *(u32*)&sWc2[r * 76 + c * 2] = gwc[idx];
    }
    if (tid < 128) {
      const int r = tid >> 3, c = tid & 7;
      *(u32*)&sWf1[r * 20 + c * 2] = ((const u32*)(ws + WS_GWF1))[tid];
      *(u32*)&sWf2[r * 20 + c * 2] = ((const u32*)(ws + WS_GWF2))[tid];
    }
    if (tid < 192) sHa[tid] = (float)HA16[node * 192 + tid];
    if (tid < 128) sB[tid] = ws[WS_BIAS + tid];
  }
  {  // distances
    float dr[16];
#pragma unroll
    for (int c = 0; c < 16; ++c) {
      float s = 0.f;
#pragma unroll
      for (int d = 0; d < 3; ++d) {
        const int cd = c * 3 + d;
        const float df = cTb[cd * 256 + i] - cTb[cd * 256 + tid];
        s += df * df;
      }
      dr[c] = sqrtf(s);
    }
#pragma unroll
    for (int kk = 0; kk < 4; ++kk)
      *(f16x4*)&distS[tid * 20 + kk * 4] =
          pack4(dr[4 * kk], dr[4 * kk + 1], dr[4 * kk + 2], dr[4 * kk + 3]);
  }
  __syncthreads();

  int jj[4]; float mjt[4]; f16x4 dfr[4];
#pragma unroll
  for (int jt = 0; jt < 4; ++jt) {
    jj[jt] = w * 64 + jt * 16 + l15;
    mjt[jt] = (jj[jt] == i) ? 0.f : 1.f;
    dfr[jt] = *(const f16x4*)&distS[jj[jt] * 20 + q * 4];
  }
  // K-major HBJ quad base for this thread's (b, q): row stride 4 per og
  const f16* hbq = HBJ + (size_t)(b * 48 + q) * 1024;  // +og*4096, +j*4

  // ---- phase 1: e2 GEMM chain, C2[f][j] over K=64 ----
  f32x4 C2[4][4];
#pragma unroll
  for (int ft = 0; ft < 4; ++ft)
#pragma unroll
    for (int jt = 0; jt < 4; ++jt) C2[ft][jt] = (f32x4){0.f, 0.f, 0.f, 0.f};
#pragma unroll
  for (int og = 0; og < 4; ++og) {
    const f16x4 wd = *(const f16x4*)&sWd[(og * 16 + l15) * 20 + q * 4];
    f16x4 af[4];
#pragma unroll
    for (int jt = 0; jt < 4; ++jt) {
      const f16x4 hb = *(const f16x4*)(hbq + og * 4096 + jj[jt] * 4);
      f32x4 a;
#pragma unroll
      for (int r = 0; r < 4; ++r) a[r] = sHa[og * 16 + q * 4 + r] + (float)hb[r];
      a = __builtin_amdgcn_mfma_f32_16x16x16f16(wd, dfr[jt], a, 0, 0, 0);
      af[jt] = pack4(fmaxf(a[0], 0.f), fmaxf(a[1], 0.f), fmaxf(a[2], 0.f), fmaxf(a[3], 0.f));
    }
#pragma unroll
    for (int ft = 0; ft < 4; ++ft) {
      const f16x4 we = *(const f16x4*)&sWe2[(ft * 16 + l15) * 76 + og * 16 + q * 4];
#pragma unroll
      for (int jt = 0; jt < 4; ++jt)
        C2[ft][jt] = __builtin_amdgcn_mfma_f32_16x16x16f16(we, af[jt], C2[ft][jt], 0, 0, 0);
    }
  }
  // per-wave agg partials -> registers (all-reduce butterfly over 16 lanes)
  float sagg[4][4];
#pragma unroll
  for (int ft = 0; ft < 4; ++ft) {
#pragma unroll
    for (int r = 0; r < 4; ++r) {
      float s = 0.f;
#pragma unroll
      for (int jt = 0; jt < 4; ++jt)
        s += fmaxf(C2[ft][jt][r] + sB[ft * 16 + q * 4 + r], 0.f) * mjt[jt];
      sagg[ft][r] = s;
    }
#pragma unroll
    for (int st = 1; st < 16; st <<= 1)
#pragma unroll
      for (int r = 0; r < 4; ++r) sagg[ft][r] += __shfl_xor(sagg[ft][r], st, 64);
  }

  // ---- phase 2: category chains -> factors ----
  float fac[4][4] = {};
#pragma unroll
  for (int m = 0; m < 2; ++m) {
    float cv[4];
#pragma unroll
    for (int jt = 0; jt < 4; ++jt) {
      if (flag) {
        const u32 p = ((const u32*)cat)[node * 256 + jj[jt]];
        cv[jt] = bfld((u16)(m ? (p >> 16) : (p & 0xFFFFu)));
      } else {
        cv[jt] = ((const float*)cat)[(node * 256 + jj[jt]) * 2 + m];
      }
    }
    f32x4 C3[4];
#pragma unroll
    for (int jt = 0; jt < 4; ++jt) C3[jt] = (f32x4){0.f, 0.f, 0.f, 0.f};
#pragma unroll
    for (int og2 = 0; og2 < 4; ++og2) {
      const int og = 4 + m * 4 + og2;
      const f16x4 wd = *(const f16x4*)&sWd[(og * 16 + l15) * 20 + q * 4];
      const f16x4 wc = *(const f16x4*)&sWc2[(m * 16 + l15) * 76 + og2 * 16 + q * 4];
#pragma unroll
      for (int jt = 0; jt < 4; ++jt) {
        const f16x4 hb = *(const f16x4*)(hbq + og * 4096 + jj[jt] * 4);
        f32x4 a;
#pragma unroll
        for (int r = 0; r < 4; ++r) a[r] = sHa[og * 16 + q * 4 + r] + (float)hb[r];
        a = __builtin_amdgcn_mfma_f32_16x16x16f16(wd, dfr[jt], a, 0, 0, 0);
        const f16x4 af = pack4(fmaxf(a[0], 0.f), fmaxf(a[1], 0.f),
                               fmaxf(a[2], 0.f), fmaxf(a[3], 0.f));
        C3[jt] = __builtin_amdgcn_mfma_f32_16x16x16f16(wc, af, C3[jt], 0, 0, 0);
      }
    }
#pragma unroll
    for (int jt = 0; jt < 4; ++jt)
#pragma unroll
      for (int r = 0; r < 4; ++r)
        fac[jt][r] += cv[jt] * fmaxf(C3[jt][r] + sB[64 + m * 16 + q * 4 + r], 0.f);
  }

  // ---- factors MLP ----
  const f16x4 w1 = *(const f16x4*)&sWf1[l15 * 20 + q * 4];
  const f16x4 w2 = *(const f16x4*)&sWf2[l15 * 20 + q * 4];
  float ffv[4][4];
#pragma unroll
  for (int jt = 0; jt < 4; ++jt) {
    const f16x4 fF = pack4(fac[jt][0], fac[jt][1], fac[jt][2], fac[jt][3]);
    const f32x4 z = {0.f, 0.f, 0.f, 0.f};
    f32x4 G = __builtin_amdgcn_mfma_f32_16x16x16f16(w1, fF, z, 0, 0, 0);
    const f16x4 gF = pack4(fmaxf(G[0] + sB[96 + q * 4 + 0], 0.f),
                           fmaxf(G[1] + sB[96 + q * 4 + 1], 0.f),
                           fmaxf(G[2] + sB[96 + q * 4 + 2], 0.f),
                           fmaxf(G[3] + sB[96 + q * 4 + 3], 0.f));
    f32x4 F2 = __builtin_amdgcn_mfma_f32_16x16x16f16(w2, gF, z, 0, 0, 0);
#pragma unroll
    for (int r = 0; r < 4; ++r) ffv[jt][r] = fmaxf(F2[r] + sB[112 + q * 4 + r], 0.f);
  }

  // ---- coord aggregation ----
  float civ[12];
#pragma unroll
  for (int r = 0; r < 4; ++r)
#pragma unroll
    for (int d = 0; d < 3; ++d) civ[r * 3 + d] = cTb[(3 * (q * 4 + r) + d) * 256 + i];
  float ca[12] = {};
#pragma unroll
  for (int jt = 0; jt < 4; ++jt)
#pragma unroll
    for (int r = 0; r < 4; ++r) {
      const float fv = ffv[jt][r];
#pragma unroll
      for (int d = 0; d < 3; ++d) {
        const float cj = cTb[(3 * (q * 4 + r) + d) * 256 + jj[jt]];
        ca[r * 3 + d] += fv * (civ[r * 3 + d] - cj);
      }
    }
#pragma unroll
  for (int st = 1; st < 16; st <<= 1)
#pragma unroll
    for (int u = 0; u < 12; ++u) ca[u] += __shfl_xor(ca[u], st, 64);

  // ---- single combined block reduction ----
  if (l15 == 0) {
#pragma unroll
    for (int ft = 0; ft < 4; ++ft)
#pragma unroll
      for (int r = 0; r < 4; ++r) red[w * 64 + ft * 16 + q * 4 + r] = sagg[ft][r];
#pragma unroll
    for (int u = 0; u < 12; ++u) red[256 + w * 48 + q * 12 + u] = ca[u];
  }
  __syncthreads();
  if (tid < 64) {
    ws[WS_AGG + node * 64 + tid] = red[tid] + red[64 + tid] + red[128 + tid] + red[192 + tid];
  } else if (tid < 112) {
    const int u = tid - 64;
    ws[WS_CAC + node * 48 + u] =
        red[256 + u] + red[256 + 48 + u] + red[256 + 96 + u] + red[256 + 144 + u];
  }
}

// ---------------- K2: fused epilogue (552 x 256) ----------------------------
// blk 0..31: node model (MFMA); 32..39: coord pipeline; 40..551: copycat.
__global__ __launch_bounds__(256) void k_epi(const void* __restrict__ h,
                                             const void* __restrict__ coord,
                                             const void* __restrict__ vel,
                                             const void* __restrict__ cat,
                                             const void* __restrict__ Wcv,
                                             const void* __restrict__ Wql,
                                             const void* __restrict__ Wkl,
                                             const float* __restrict__ ws,
                                             void* __restrict__ outv) {
  const int blk = blockIdx.x, tid = threadIdx.x;
  const int flag = ((const int*)ws)[WS_FLAG];
  if (blk < 32) {  // ---- node model: 64 nodes/block, chained MFMA GEMMs ----
    const int w = tid >> 6, lane = tid & 63;
    const int q = lane >> 4, l15 = lane & 15;
    __shared__ __align__(16) f16 sW1[64 * 132];
    __shared__ __align__(16) f16 sW2[64 * 68];
    __shared__ __align__(16) f16 sH[64 * 68];
    __shared__ float sbn[128];
    {
      const u32* g1 = (const u32*)(ws + WS_GWN1);
      for (int idx = tid; idx < 4096; idx += 256) {
        const int o = idx >> 6, c = idx & 63;
        *(u32*)&sW1[o * 132 + c * 2] = g1[idx];
      }
      const u32* g2 = (const u32*)(ws + WS_GWN2);
      for (int idx = tid; idx < 2048; idx += 256) {
        const int o = idx >> 5, c = idx & 31;
        *(u32*)&sW2[o * 68 + c * 2] = g2[idx];
      }
      const int hbase = blk * 64 * 64;
      for (int e = tid; e < 4096; e += 256)
        sH[(e >> 6) * 68 + (e & 63)] = (f16)ldv(h, hbase + e, flag);
      if (tid < 128) sbn[tid] = (tid < 64) ? ws[WS_BN1 + tid] : ws[WS_BN2 + tid - 64];
    }
    __syncthreads();
    const int node = blk * 64 + w * 16 + l15;
    const int lrow = w * 16 + l15;
    f16x4 xB[8];
#pragma unroll
    for (int kt = 0; kt < 4; ++kt)
      xB[kt] = *(const f16x4*)&sH[lrow * 68 + kt * 16 + q * 4];
#pragma unroll
    for (int kt = 0; kt < 4; ++kt) {
      const float* ap = ws + WS_AGG + node * 64 + kt * 16 + q * 4;
      xB[4 + kt] = pack4(ap[0], ap[1], ap[2], ap[3]);
    }
    f16x4 hidB[4];
#pragma unroll
    for (int ot = 0; ot < 4; ++ot) {
      f32x4 acc;
#pragma unroll
      for (int r = 0; r < 4; ++r) acc[r] = sbn[ot * 16 + q * 4 + r];
#pragma unroll
      for (int kt = 0; kt < 8; ++kt) {
        const f16x4 a = *(const f16x4*)&sW1[(ot * 16 + l15) * 132 + kt * 16 + q * 4];
        acc = __builtin_amdgcn_mfma_f32_16x16x16f16(a, xB[kt], acc, 0, 0, 0);
      }
      hidB[ot] = pack4(fmaxf(acc[0], 0.f), fmaxf(acc[1], 0.f),
                       fmaxf(acc[2], 0.f), fmaxf(acc[3], 0.f));
    }
#pragma unroll
    for (int ft = 0; ft < 4; ++ft) {
      const f16x4 hl = *(const f16x4*)&sH[lrow * 68 + ft * 16 + q * 4];
      f32x4 acc;
#pragma unroll
      for (int r = 0; r < 4; ++r) acc[r] = sbn[64 + ft * 16 + q * 4 + r] + (float)hl[r];
#pragma unroll
      for (int ot = 0; ot < 4; ++ot) {
        const f16x4 a = *(const f16x4*)&sW2[(ft * 16 + l15) * 68 + ot * 16 + q * 4];
        acc = __builtin_amdgcn_mfma_f32_16x16x16f16(a, hidB[ot], acc, 0, 0, 0);
      }
#pragma unroll
      for (int r = 0; r < 4; ++r)
        stv(outv, node * 64 + ft * 16 + q * 4 + r, acc[r], flag);
    }
  } else if (blk < 40) {  // ---- coord pipeline, b = blk-32 ----
    const int b = blk - 32;
    const int n = tid, node = b * 256 + n;
    const int wave = n >> 6, lane = n & 63;
    __shared__ float wcv[256], wql[256], wkl[256];
    __shared__ float redm[16];
    wcv[n] = ldv(Wcv, n, flag);
    wql[n] = ldv(Wql, n, flag);
    wkl[n] = ldv(Wkl, n, flag);
    float cf[48];
    load48(coord, node, flag, cf);
    float s0 = 0.f, s1 = 0.f, s2 = 0.f;
#pragma unroll
    for (int c = 0; c < 16; ++c) { s0 += cf[c*3]; s1 += cf[c*3+1]; s2 += cf[c*3+2]; }
    for (int s = 1; s < 64; s <<= 1) {
      s0 += __shfl_xor(s0, s, 64); s1 += __shfl_xor(s1, s, 64); s2 += __shfl_xor(s2, s, 64);
    }
    if (lane == 0) { redm[wave*4] = s0; redm[wave*4+1] = s1; redm[wave*4+2] = s2; }
    __syncthreads();
    const float m0 = (redm[0]+redm[4]+redm[8]+redm[12]) * (1.f/4096.f);
    const float m1 = (redm[1]+redm[5]+redm[9]+redm[13]) * (1.f/4096.f);
    const float m2 = (redm[2]+redm[6]+redm[10]+redm[14]) * (1.f/4096.f);
    __syncthreads();
    float velf[48];
    load48(vel, node, flag, velf);
    float att[16];
    {
      const float4* ap = (const float4*)(ws + WS_ATT + node * 16);
#pragma unroll
      for (int c4 = 0; c4 < 4; ++c4) {
        const float4 v = ap[c4];
        att[c4*4] = v.x; att[c4*4+1] = v.y; att[c4*4+2] = v.z; att[c4*4+3] = v.w;
      }
    }
    float cac[48];
    {
      const float4* cp = (const float4*)(ws + WS_CAC + node * 48);
#pragma unroll
      for (int c4 = 0; c4 < 12; ++c4) {
        const float4 v = cp[c4];
        cac[c4*4] = v.x; cac[c4*4+1] = v.y; cac[c4*4+2] = v.z; cac[c4*4+3] = v.w;
      }
    }
    float c3[48];
#pragma unroll
    for (int c = 0; c < 16; ++c) {
      const float at = att[c];
#pragma unroll
      for (int d = 0; d < 3; ++d) {
        const int cd = c * 3 + d;
        const float md = (d == 0) ? m0 : ((d == 1) ? m1 : m2);
        float cc = at * (cf[cd] - md) + cf[cd];
        cc += cac[cd];
        float a = cc;
#pragma unroll
        for (int cp = 0; cp < 16; ++cp) a += velf[cp * 3 + d] * wcv[c * 16 + cp];
        c3[cd] = a;
      }
    }
    float t0 = 0.f, t1 = 0.f, t2 = 0.f;
#pragma unroll
    for (int c = 0; c < 16; ++c) { t0 += c3[c*3]; t1 += c3[c*3+1]; t2 += c3[c*3+2]; }
    for (int s = 1; s < 64; s <<= 1) {
      t0 += __shfl_xor(t0, s, 64); t1 += __shfl_xor(t1, s, 64); t2 += __shfl_xor(t2, s, 64);
    }
    if (lane == 0) { redm[wave*4] = t0; redm[wave*4+1] = t1; redm[wave*4+2] = t2; }
    __syncthreads();
    const float cm0 = (redm[0]+redm[4]+redm[8]+redm[12]) * (1.f/4096.f);
    const float cm1 = (redm[1]+redm[5]+redm[9]+redm[13]) * (1.f/4096.f);
    const float cm2 = (redm[2]+redm[6]+redm[10]+redm[14]) * (1.f/4096.f);
    float cc[48];
#pragma unroll
    for (int c = 0; c < 16; ++c) {
      cc[c*3]   = c3[c*3]   - cm0;
      cc[c*3+1] = c3[c*3+1] - cm1;
      cc[c*3+2] = c3[c*3+2] - cm2;
    }
#pragma unroll
    for (int o = 0; o < 16; ++o) {
      float qv[3], kv[3];
#pragma unroll
      for (int d = 0; d < 3; ++d) {
        float sq = 0.f, sk = 0.f;
#pragma unroll
        for (int cp = 0; cp < 16; ++cp) {
          sq += cc[cp * 3 + d] * wql[o * 16 + cp];
          sk += cc[cp * 3 + d] * wkl[o * 16 + cp];
        }
        qv[d] = sq; kv[d] = sk;
      }
      const float prod = qv[0]*kv[0] + qv[1]*kv[1] + qv[2]*kv[2];
      const float kns  = kv[0]*kv[0] + kv[1]*kv[1] + kv[2]*kv[2];
      const float wq = prod / (kns + EPSV);
#pragma unroll
      for (int d = 0; d < 3; ++d) {
        const float cmd = (d == 0) ? cm0 : ((d == 1) ? cm1 : cm2);
        const float val = (prod >= 0.f) ? qv[d] : (qv[d] - wq * kv[d]);
        stv(outv, 131072 + node * 48 + o * 3 + d, val + cmd, flag);
      }
    }
  } else {  // ---- category passthrough (overwrites scratch; no reader left) ----
    const int idx = (blk - 40) * 256 + tid;  // 131072 total
    if (flag) {
      ((uint4*)((char*)outv + 458752))[idx] = ((const uint4*)cat)[idx];
    } else {
      ((uint4*)((char*)outv + 917504))[idx] = ((const uint4*)cat)[idx];
      ((uint4*)((char*)outv + 917504))[idx + 131072] = ((const uint4*)cat)[idx + 131072];
    }
  }
}

// ---------------- launch ----------------------------------------------------
extern "C" void kernel_launch(void* const* d_in, const int* in_sizes, int n_in,
                              void* d_out, int out_size, void* d_ws, size_t ws_size,
                              hipStream_t stream) {
  (void)in_sizes; (void)n_in; (void)out_size; (void)ws_size;
  const void* h    = d_in[0];
  const void* coord= d_in[1];
  const void* vel  = d_in[2];
  const void* cat  = d_in[3];
  const void* Wcv  = d_in[4];
  const void* We1  = d_in[5];
  const void* be1  = d_in[6];
  const void* We2  = d_in[7];
  const void* be2  = d_in[8];
  const void* Wc1  = d_in[9];
  const void* bc1  = d_in[10];
  const void* Wc2  = d_in[11];
  const void* bc2  = d_in[12];
  const void* Wf1  = d_in[13];
  const void* bf1v = d_in[14];
  const void* Wf2  = d_in[15];
  const void* bf2v = d_in[16];
  const void* Wn1  = d_in[17];
  const void* bn1  = d_in[18];
  const void* Wn2  = d_in[19];
  const void* bn2  = d_in[20];
  const void* Wql  = d_in[21];
  const void* Wkl  = d_in[22];
  const void* Wqm  = d_in[23];
  const void* bqm  = d_in[24];
  float* ws = (float*)d_ws;

  k_prep_w<<<256, 256, 0, stream>>>(h, coord, We1, Wc1, We2, Wc2, Wf1, Wf2,
                                    Wn1, Wn2, Wqm, be1, bc1, bqm, be2, bc2,
                                    bf1v, bf2v, bn1, bn2, ws);
  k_gemm<<<160, 256, 0, stream>>>(h, ws, d_out);
  k_edge<<<2048, 256, 0, stream>>>(cat, ws, d_out);
  k_epi<<<552, 256, 0, stream>>>(h, coord, vel, cat, Wcv, Wql, Wkl, ws, d_out);
}

// Round 18
// 194.051 us; speedup vs baseline: 1.9217x; 1.0053x over previous
//
#include <hip/hip_runtime.h>

typedef unsigned short u16;
typedef unsigned int u32;
typedef _Float16 f16;
typedef __attribute__((ext_vector_type(2))) _Float16 f16x2;
typedef __attribute__((ext_vector_type(4))) _Float16 f16x4;
typedef __attribute__((ext_vector_type(4))) float f32x4;

// Problem constants: B=8, N=256, F=64, C=16, K=2
#define EPSV 1e-4f

// Output element offsets: h_out [0,131072) coord_out [131072,229376) category [229376,1277952)
// Category out-region is scratch: HA[2048*192] | HBJ[8][48][256][4] (f16) until
// the epilogue's copycat blocks overwrite it (only k_edge reads scratch).
// HBJ is K-MAJOR: element (b, j, o') lives at ((b*48 + (o'>>4)*4 + ((o'&15)>>2))*256 + j)*4 + (o'&3)
// so a 16-lane MFMA quad load (consecutive j, fixed o'-quad) is one 128B transaction.

// ---------------- ws layout (fp32 slots) -----------------------------------
// HARD CAP: max offset <= 391872 (round 9 overflow corrupted adjacent alloc).
// f16 tables: slot count = f16_elements / 2 (round 12 aliasing bug).
static constexpr int WS_FLAG = 0;                     // +16
static constexpr int WS_ATT  = 16;                    // [2048][16]
static constexpr int WS_CT   = 32784;                 // [8][48][256] coord^T fp32
static constexpr int WS_AGG  = 131088;                // [2048][64]
static constexpr int WS_CAC  = 262160;                // [2048][48]  (ends 360464)
static constexpr int WS_GWN1 = 360464;                // f16 [64 o][128 k] = 4096 slots (ends 364560)
static constexpr int WS_GWN2 = 364560;                // f16 [64 f][64 o]  = 2048 slots (ends 366608)
static constexpr int WS_BN1  = 372752;                // [64]
static constexpr int WS_BN2  = 372816;                // [64]
static constexpr int WS_BIAS = 372880;                // be2[64]|bc2[32]|bf1[16]|bf2[16]
static constexpr int WS_GWD  = 373008;                // f16 [192 o'][16 c]   (1536 slots)
static constexpr int WS_GWE2 = 374544;                // f16 [64 f][64 o]     (2048)
static constexpr int WS_GWC2 = 376592;                // f16 [32 mc][64 o]    (1024)
static constexpr int WS_GWF1 = 377616;                // f16 [16][16]         (128)
static constexpr int WS_GWF2 = 377744;                // f16 [16][16]         (128)
static constexpr int WS_GW1  = 377872;                // f16 [400 out][68 k]  (13600 slots)
static constexpr int WS_B400 = 391472;                // [400] layer-1 bias (ends 391872)

static __device__ __forceinline__ float bfld(u16 v) {
  return __uint_as_float(((unsigned)v) << 16);
}
static __device__ __forceinline__ u16 f2b(float x) {  // RNE
  unsigned u = __float_as_uint(x);
  u += 0x7FFFu + ((u >> 16) & 1u);
  return (u16)(u >> 16);
}
static __device__ __forceinline__ float ldv(const void* p, int i, int flag) {
  return flag ? bfld(((const u16*)p)[i]) : ((const float*)p)[i];
}
static __device__ __forceinline__ void stv(void* p, int i, float v, int flag) {
  if (flag) ((u16*)p)[i] = f2b(v);
  else      ((float*)p)[i] = v;
}
static __device__ __forceinline__ f16* scratchHA(void* outv, int flag) {
  return (f16*)((char*)outv + (size_t)229376 * (flag ? 2 : 4));
}
static __device__ __forceinline__ int sniff_flag(const void* h) {
  const u16* hu = (const u16*)h;
  int cnt = 0;
  for (int i = 0; i < 128; ++i) {
    unsigned e = (hu[i] >> 7) & 0xFFu;
    if ((e >= 100u && e <= 150u) || hu[i] == 0) ++cnt;
  }
  return (cnt >= 112) ? 1 : 0;
}
static __device__ __forceinline__ f16x4 pack4(float a, float b, float c, float d) {
  const f16x2 lo = __builtin_bit_cast(f16x2, __builtin_amdgcn_cvt_pkrtz(a, b));
  const f16x2 hi = __builtin_bit_cast(f16x2, __builtin_amdgcn_cvt_pkrtz(c, d));
  f16x4 r; r[0] = lo[0]; r[1] = lo[1]; r[2] = hi[0]; r[3] = hi[1]; return r;
}
// 48 contiguous input elements -> fp32, vectorized
static __device__ __forceinline__ void load48(const void* p, int node, int flag,
                                              float* dst) {
  if (flag) {
    const uint4* q4 = (const uint4*)((const u16*)p + node * 48);
#pragma unroll
    for (int c = 0; c < 6; ++c) {
      const uint4 v = q4[c];
      const u32 a[4] = {v.x, v.y, v.z, v.w};
#pragma unroll
      for (int e = 0; e < 4; ++e) {
        dst[c * 8 + e * 2]     = bfld((u16)(a[e] & 0xFFFFu));
        dst[c * 8 + e * 2 + 1] = bfld((u16)(a[e] >> 16));
      }
    }
  } else {
    const float4* q4 = (const float4*)((const float*)p + node * 48);
#pragma unroll
    for (int c = 0; c < 12; ++c) {
      const float4 v = q4[c];
      dst[c * 4] = v.x; dst[c * 4 + 1] = v.y; dst[c * 4 + 2] = v.z; dst[c * 4 + 3] = v.w;
    }
  }
}

// ---------------- K0: table builds, fully parallel (256 x 256) --------------
__global__ __launch_bounds__(256) void k_prep_w(
    const void* __restrict__ h, const void* __restrict__ coord,
    const void* __restrict__ We1, const void* __restrict__ Wc1,
    const void* __restrict__ We2, const void* __restrict__ Wc2,
    const void* __restrict__ Wf1, const void* __restrict__ Wf2,
    const void* __restrict__ Wn1, const void* __restrict__ Wn2,
    const void* __restrict__ Wqm,
    const void* __restrict__ be1, const void* __restrict__ bc1,
    const void* __restrict__ bqm, const void* __restrict__ be2,
    const void* __restrict__ bc2, const void* __restrict__ bf1,
    const void* __restrict__ bf2, const void* __restrict__ bn1,
    const void* __restrict__ bn2,
    float* __restrict__ ws) {
  const int t = blockIdx.x * 256 + threadIdx.x;
  const int STR = 65536;
  __shared__ int sflag;
  if (threadIdx.x == 0) {
    sflag = sniff_flag(h);
    if (blockIdx.x == 0) ((int*)ws)[WS_FLAG] = sflag;
  }
  __syncthreads();
  const int flag = sflag;

  // GW1: stacked layer-1 weights as [400 out][68 k] f16
  f16* gw1 = (f16*)(ws + WS_GW1);
  for (int idx = t; idx < 25600; idx += STR) {
    const int row = idx >> 6, k = idx & 63;
    float v;
    if (row < 64)       v = ldv(We1, row * 144 + k, flag);
    else if (row < 192) v = ldv(Wc1, (row - 64) * 144 + k, flag);
    else if (row < 384) {
      const int ro = row - 192;
      v = (ro < 64) ? ldv(We1, ro * 144 + 64 + k, flag)
                    : ldv(Wc1, (ro - 64) * 144 + 64 + k, flag);
    } else              v = ldv(Wqm, (row - 384) * 64 + k, flag);
    gw1[row * 68 + k] = (f16)v;
  }
  if (t < 400) {
    float v = (t < 64) ? ldv(be1, t, flag)
            : (t < 192) ? ldv(bc1, t - 64, flag)
            : (t < 384) ? 0.f : ldv(bqm, t - 384, flag);
    ws[WS_B400 + t] = v;
  }
  // coord^T [b][cd][n]: SOURCE-LINEAR (coalesced reads, scattered writes)
  for (int idx = t; idx < 98304; idx += STR) {
    const int node = idx / 48, cd = idx - node * 48;
    ws[WS_CT + ((node >> 8) * 48 + cd) * 256 + (node & 255)] = ldv(coord, idx, flag);
  }
  f16* gwd  = (f16*)(ws + WS_GWD);
  f16* gwe2 = (f16*)(ws + WS_GWE2);
  f16* gwc2 = (f16*)(ws + WS_GWC2);
  f16* gwf1 = (f16*)(ws + WS_GWF1);
  f16* gwf2 = (f16*)(ws + WS_GWF2);
  for (int idx = t; idx < 3072; idx += STR) {  // [o'][c] <- cols 128..143
    const int o = idx >> 4, c = idx & 15;
    const void* src = (o < 64) ? We1 : Wc1;
    const int row = (o < 64) ? o : (o - 64);
    gwd[idx] = (f16)ldv(src, row * 144 + 128 + c, flag);
  }
  for (int idx = t; idx < 4096; idx += STR) gwe2[idx] = (f16)ldv(We2, idx, flag);
  for (int idx = t; idx < 2048; idx += STR) gwc2[idx] = (f16)ldv(Wc2, idx, flag);
  if (t < 256) { gwf1[t] = (f16)ldv(Wf1, t, flag); gwf2[t] = (f16)ldv(Wf2, t, flag); }
  f16* gwn1 = (f16*)(ws + WS_GWN1);
  f16* gwn2 = (f16*)(ws + WS_GWN2);
  for (int idx = t; idx < 8192; idx += STR) gwn1[idx] = (f16)ldv(Wn1, idx, flag);
  for (int idx = t; idx < 4096; idx += STR) gwn2[idx] = (f16)ldv(Wn2, idx, flag);
  if (t < 64)  ws[WS_BN1 + t] = ldv(bn1, t, flag);
  if (t >= 64 && t < 128) ws[WS_BN2 + t - 64] = ldv(bn2, t - 64, flag);
  if (t >= 128 && t < 192) ws[WS_BIAS + t - 128] = ldv(be2, t - 128, flag);
  if (t >= 192 && t < 224) ws[WS_BIAS + 64 + t - 192] = ldv(bc2, t - 192, flag);
  if (t >= 224 && t < 240) ws[WS_BIAS + 96 + t - 224] = ldv(bf1, t - 224, flag);
  if (t >= 240 && t < 256) ws[WS_BIAS + 112 + t - 240] = ldv(bf2, t - 240, flag);
}

// ---------------- K0b: layer-1 MFMA GEMM -> HA/HBJ/ATT (160 x 256) ----------
__global__ __launch_bounds__(256) void k_gemm(const void* __restrict__ h,
                                              float* __restrict__ ws,
                                              void* __restrict__ outv) {
  const int flag = ((const int*)ws)[WS_FLAG];
  const int nt = blockIdx.x / 5, grp = blockIdx.x % 5;
  const int tid = threadIdx.x, w = tid >> 6, lane = tid & 63;
  const int q = lane >> 4, l15 = lane & 15;
  f16* HA16 = scratchHA(outv, flag);
  f16* HBJ  = HA16 + 2048 * 192;
  __shared__ __align__(16) f16 sW[80 * 68];
  __shared__ __align__(16) f16 sH[64 * 68];
  __shared__ float sBias[80];
  const u32* gw1 = (const u32*)(ws + WS_GW1);
  for (int idx = tid; idx < 2720; idx += 256) {
    const int r = idx / 34, c = idx - r * 34;
    *(u32*)&sW[r * 68 + c * 2] = gw1[(grp * 80 + r) * 34 + c];
  }
  const int hbase = nt * 64 * 64;
  for (int e = tid; e < 4096; e += 256)
    sH[(e >> 6) * 68 + (e & 63)] = (f16)ldv(h, hbase + e, flag);
  if (tid < 80) sBias[tid] = ws[WS_B400 + grp * 80 + tid];
  __syncthreads();
  f16x4 Af[4];
#pragma unroll
  for (int ks = 0; ks < 4; ++ks)
    Af[ks] = *(const f16x4*)&sH[(w * 16 + l15) * 68 + ks * 16 + q * 4];
#pragma unroll
  for (int ot = 0; ot < 5; ++ot) {
    const float bv = sBias[ot * 16 + l15];
    f32x4 acc = (f32x4){bv, bv, bv, bv};
#pragma unroll
    for (int ks = 0; ks < 4; ++ks) {
      const f16x4 Bf = *(const f16x4*)&sW[(ot * 16 + l15) * 68 + ks * 16 + q * 4];
      acc = __builtin_amdgcn_mfma_f32_16x16x16f16(Af[ks], Bf, acc, 0, 0, 0);
    }
    const int out = grp * 80 + ot * 16 + l15;
    const int nodeD = nt * 64 + w * 16 + q * 4;
#pragma unroll
    for (int r = 0; r < 4; ++r) {
      const int node = nodeD + r;
      if (out < 192) {
        HA16[node * 192 + out] = (f16)acc[r];
      } else if (out < 384) {
        const int ol = out - 192;  // K-major HBJ
        HBJ[(((node >> 8) * 48 + ((ol >> 4) << 2) + ((ol & 15) >> 2)) * 256 +
             (node & 255)) * 4 + (ol & 3)] = (f16)acc[r];
      } else {
        ws[WS_ATT + node * 16 + out - 384] = fmaxf(acc[r], 0.f);
      }
    }
  }
}

// ---------------- K1: MFMA edge kernel (2048 blocks x 256) ------------------
// XCD swizzle (b = blk&7). Single mid-kernel barrier. K-major HBJ; all
// phase-1 HBJ fragments + cat prefetched into registers before the staging
// barrier so their L2 latency hides under staging + distance math.
__global__ __launch_bounds__(256, 3) void k_edge(const void* __restrict__ cat,
                                                 float* __restrict__ ws,
                                                 void* __restrict__ outv) {
  const int node = ((blockIdx.x & 7) << 8) | (blockIdx.x >> 3);
  const int b = node >> 8, i = node & 255;
  const int tid = threadIdx.x;
  const int w = tid >> 6, lane = tid & 63, q = lane >> 4, l15 = lane & 15;
  const int flag = ((const int*)ws)[WS_FLAG];
  const f16* HA16 = scratchHA(outv, flag);
  const f16* HBJ  = HA16 + 2048 * 192;
  const float* __restrict__ cTb = ws + WS_CT + b * 48 * 256;

  __shared__ __align__(16) f16 sWd[192 * 20];
  __shared__ __align__(16) f16 sWe2[64 * 76];
  __shared__ __align__(16) f16 sWc2[32 * 76];
  __shared__ __align__(16) f16 sWf1[16 * 20];
  __shared__ __align__(16) f16 sWf2[16 * 20];
  __shared__ __align__(16) f16 distS[256 * 20];
  __shared__ float sHa[192];
  __shared__ float sB[128];
  __shared__ __align__(16) float red[448];  // [0,256) agg, [256,448) cacc

  // ---- early address setup + phase-1 HBJ / cat prefetch (no LDS dep) ----
  int jj[4]; float mjt[4];
#pragma unroll
  for (int jt = 0; jt < 4; ++jt) {
    jj[jt] = w * 64 + jt * 16 + l15;
    mjt[jt] = (jj[jt] == i) ? 0.f : 1.f;
  }
  const f16* hbq = HBJ + (size_t)(b * 48 + q) * 1024;  // +og*4096, +j*4
  f16x4 hbP[4][4];
#pragma unroll
  for (int og = 0; og < 4; ++og)
#pragma unroll
    for (int jt = 0; jt < 4; ++jt)
      hbP[og][jt] = *(const f16x4*)(hbq + og * 4096 + jj[jt] * 4);
  float cv0[4], cv1[4];
#pragma unroll
  for (int jt = 0; jt < 4; ++jt) {
    if (flag) {
      const u32 p = ((const u32*)cat)[node * 256 + jj[jt]];
      cv0[jt] = bfld((u16)(p & 0xFFFFu));
      cv1[jt] = bfld((u16)(p >> 16));
    } else {
      const float2 p = ((const float2*)cat)[node * 256 + jj[jt]];
      cv0[jt] = p.x; cv1[jt] = p.y;
    }
  }

  {  // stage weight tables
    const u32* gwd = (const u32*)(ws + WS_GWD);
    for (int idx = tid; idx < 1536; idx += 256) {
      const int r = idx >> 3, c = idx & 7;
      *(u32*)&sWd[r * 20 + c * 2] = gwd[idx];
    }
    const u32* gwe = (const u32*)(ws + WS_GWE2);
    for (int idx = tid; idx < 2048; idx += 256) {
      const int r = idx >> 5, c = idx & 31;
      *(u32*)&sWe2[r * 76 + c * 2] = gwe[idx];
    }
    const u32* gwc = (const u32*)(ws + WS_GWC2);
    for (int idx = tid; idx < 1024; idx += 256) {
      const int r = idx >> 5, c = idx & 31;
      *(u32*)&sWc2[r * 76 + c * 2] = gwc[idx];
    }
    if (tid < 128) {
      const int r = tid >> 3, c = tid & 7;
      *(u32*)&sWf1[r * 20 + c * 2] = ((const u32*)(ws + WS_GWF1))[tid];
      *(u32*)&sWf2[r * 20 + c * 2] = ((const u32*)(ws + WS_GWF2))[tid];
    }
    if (tid < 192) sHa[tid] = (float)HA16[node * 192 + tid];
    if (tid < 128) sB[tid] = ws[WS_BIAS + tid];
  }
  {  // distances
    float dr[16];
#pragma unroll
    for (int c = 0; c < 16; ++c) {
      float s = 0.f;
#pragma unroll
      for (int d = 0; d < 3; ++d) {
        const int cd = c * 3 + d;
        const float df = cTb[cd * 256 + i] - cTb[cd * 256 + tid];
        s += df * df;
      }
      dr[c] = sqrtf(s);
    }
#pragma unroll
    for (int kk = 0; kk < 4; ++kk)
      *(f16x4*)&distS[tid * 20 + kk * 4] =
          pack4(dr[4 * kk], dr[4 * kk + 1], dr[4 * kk + 2], dr[4 * kk + 3]);
  }
  __syncthreads();

  f16x4 dfr[4];
#pragma unroll
  for (int jt = 0; jt < 4; ++jt)
    dfr[jt] = *(const f16x4*)&distS[jj[jt] * 20 + q * 4];

  // ---- phase 1: e2 GEMM chain, C2[f][j] over K=64 ----
  f32x4 C2[4][4];
#pragma unroll
  for (int ft = 0; ft < 4; ++ft)
#pragma unroll
    for (int jt = 0; jt < 4; ++jt) C2[ft][jt] = (f32x4){0.f, 0.f, 0.f, 0.f};
#pragma unroll
  for (int og = 0; og < 4; ++og) {
    const f16x4 wd = *(const f16x4*)&sWd[(og * 16 + l15) * 20 + q * 4];
    f16x4 af[4];
#pragma unroll
    for (int jt = 0; jt < 4; ++jt) {
      const f16x4 hb = hbP[og][jt];
      f32x4 a;
#pragma unroll
      for (int r = 0; r < 4; ++r) a[r] = sHa[og * 16 + q * 4 + r] + (float)hb[r];
      a = __builtin_amdgcn_mfma_f32_16x16x16f16(wd, dfr[jt], a, 0, 0, 0);
      af[jt] = pack4(fmaxf(a[0], 0.f), fmaxf(a[1], 0.f), fmaxf(a[2], 0.f), fmaxf(a[3], 0.f));
    }
#pragma unroll
    for (int ft = 0; ft < 4; ++ft) {
      const f16x4 we = *(const f16x4*)&sWe2[(ft * 16 + l15) * 76 + og * 16 + q * 4];
#pragma unroll
      for (int jt = 0; jt < 4; ++jt)
        C2[ft][jt] = __builtin_amdgcn_mfma_f32_16x16x16f16(we, af[jt], C2[ft][jt], 0, 0, 0);
    }
  }
  // per-wave agg partials -> registers (all-reduce butterfly over 16 lanes)
  float sagg[4][4];
#pragma unroll
  for (int ft = 0; ft < 4; ++ft) {
#pragma unroll
    for (int r = 0; r < 4; ++r) {
      float s = 0.f;
#pragma unroll
      for (int jt = 0; jt < 4; ++jt)
        s += fmaxf(C2[ft][jt][r] + sB[ft * 16 + q * 4 + r], 0.f) * mjt[jt];
      sagg[ft][r] = s;
    }
#pragma unroll
    for (int st = 1; st < 16; st <<= 1)
#pragma unroll
      for (int r = 0; r < 4; ++r) sagg[ft][r] += __shfl_xor(sagg[ft][r], st, 64);
  }

  // ---- phase 2: category chains -> factors ----
  float fac[4][4] = {};
#pragma unroll
  for (int m = 0; m < 2; ++m) {
    f32x4 C3[4];
#pragma unroll
    for (int jt = 0; jt < 4; ++jt) C3[jt] = (f32x4){0.f, 0.f, 0.f, 0.f};
#pragma unroll
    for (int og2 = 0; og2 < 4; ++og2) {
      const int og = 4 + m * 4 + og2;
      const f16x4 wd = *(const f16x4*)&sWd[(og * 16 + l15) * 20 + q * 4];
      const f16x4 wc = *(const f16x4*)&sWc2[(m * 16 + l15) * 76 + og2 * 16 + q * 4];
#pragma unroll
      for (int jt = 0; jt < 4; ++jt) {
        const f16x4 hb = *(const f16x4*)(hbq + og * 4096 + jj[jt] * 4);
        f32x4 a;
#pragma unroll
        for (int r = 0; r < 4; ++r) a[r] = sHa[og * 16 + q * 4 + r] + (float)hb[r];
        a = __builtin_amdgcn_mfma_f32_16x16x16f16(wd, dfr[jt], a, 0, 0, 0);
        const f16x4 af = pack4(fmaxf(a[0], 0.f), fmaxf(a[1], 0.f),
                               fmaxf(a[2], 0.f), fmaxf(a[3], 0.f));
        C3[jt] = __builtin_amdgcn_mfma_f32_16x16x16f16(wc, af, C3[jt], 0, 0, 0);
      }
    }
#pragma unroll
    for (int jt = 0; jt < 4; ++jt) {
      const float catv = m ? cv1[jt] : cv0[jt];
#pragma unroll
      for (int r = 0; r < 4; ++r)
        fac[jt][r] += catv * fmaxf(C3[jt][r] + sB[64 + m * 16 + q * 4 + r], 0.f);
    }
  }

  // ---- factors MLP ----
  const f16x4 w1 = *(const f16x4*)&sWf1[l15 * 20 + q * 4];
  const f16x4 w2 = *(const f16x4*)&sWf2[l15 * 20 + q * 4];
  float ffv[4][4];
#pragma unroll
  for (int jt = 0; jt < 4; ++jt) {
    const f16x4 fF = pack4(fac[jt][0], fac[jt][1], fac[jt][2], fac[jt][3]);
    const f32x4 z = {0.f, 0.f, 0.f, 0.f};
    f32x4 G = __builtin_amdgcn_mfma_f32_16x16x16f16(w1, fF, z, 0, 0, 0);
    const f16x4 gF = pack4(fmaxf(G[0] + sB[96 + q * 4 + 0], 0.f),
                           fmaxf(G[1] + sB[96 + q * 4 + 1], 0.f),
                           fmaxf(G[2] + sB[96 + q * 4 + 2], 0.f),
                           fmaxf(G[3] + sB[96 + q * 4 + 3], 0.f));
    f32x4 F2 = __builtin_amdgcn_mfma_f32_16x16x16f16(w2, gF, z, 0, 0, 0);
#pragma unroll
    for (int r = 0; r < 4; ++r) ffv[jt][r] = fmaxf(F2[r] + sB[112 + q * 4 + r], 0.f);
  }

  // ---- coord aggregation ----
  float civ[12];
#pragma unroll
  for (int r = 0; r < 4; ++r)
#pragma unroll
    for (int d = 0; d < 3; ++d) civ[r * 3 + d] = cTb[(3 * (q * 4 + r) + d) * 256 + i];
  float ca[12] = {};
#pragma unroll
  for (int jt = 0; jt < 4; ++jt)
#pragma unroll
    for (int r = 0; r < 4; ++r) {
      const float fv = ffv[jt][r];
#pragma unroll
      for (int d = 0; d < 3; ++d) {
        const float cj = cTb[(3 * (q * 4 + r) + d) * 256 + jj[jt]];
        ca[r * 3 + d] += fv * (civ[r * 3 + d] - cj);
      }
    }
#pragma unroll
  for (int st = 1; st < 16; st <<= 1)
#pragma unroll
    for (int u = 0; u < 12; ++u) ca[u] += __shfl_xor(ca[u], st, 64);

  // ---- single combined block reduction ----
  if (l15 == 0) {
#pragma unroll
    for (int ft = 0; ft < 4; ++ft)
#pragma unroll
      for (int r = 0; r < 4; ++r) red[w * 64 + ft * 16 + q * 4 + r] = sagg[ft][r];
#pragma unroll
    for (int u = 0; u < 12; ++u) red[256 + w * 48 + q * 12 + u] = ca[u];
  }
  __syncthreads();
  if (tid < 64) {
    ws[WS_AGG + node * 64 + tid] = red[tid] + red[64 + tid] + red[128 + tid] + red[192 + tid];
  } else if (tid < 112) {
    const int u = tid - 64;
    ws[WS_CAC + node * 48 + u] =
        red[256 + u] + red[256 + 48 + u] + red[256 + 96 + u] + red[256 + 144 + u];
  }
}

// ---------------- K2: fused epilogue (552 x 256) ----------------------------
// blk 0..31: node model (MFMA); 32..39: coord pipeline; 40..551: copycat.
__global__ __launch_bounds__(256) void k_epi(const void* __restrict__ h,
                                             const void* __restrict__ coord,
                                             const void* __restrict__ vel,
                                             const void* __restrict__ cat,
                                             const void* __restrict__ Wcv,
                                             const void* __restrict__ Wql,
                                             const void* __restrict__ Wkl,
                                             const float* __restrict__ ws,
                                             void* __restrict__ outv) {
  const int blk = blockIdx.x, tid = threadIdx.x;
  const int flag = ((const int*)ws)[WS_FLAG];
  if (blk < 32) {  // ---- node model: 64 nodes/block, chained MFMA GEMMs ----
    const int w = tid >> 6, lane = tid & 63;
    const int q = lane >> 4, l15 = lane & 15;
    __shared__ __align__(16) f16 sW1[64 * 132];
    __shared__ __align__(16) f16 sW2[64 * 68];
    __shared__ __align__(16) f16 sH[64 * 68];
    __shared__ float sbn[128];
    {
      const u32* g1 = (const u32*)(ws + WS_GWN1);
      for (int idx = tid; idx < 4096; idx += 256) {
        const int o = idx >> 6, c = idx & 63;
        *(u32*)&sW1[o * 132 + c * 2] = g1[idx];
      }
      const u32* g2 = (const u32*)(ws + WS_GWN2);
      for (int idx = tid; idx < 2048; idx += 256) {
        const int o = idx >> 5, c = idx & 31;
        *(u32*)&sW2[o * 68 + c * 2] = g2[idx];
      }
      const int hbase = blk * 64 * 64;
      for (int e = tid; e < 4096; e += 256)
        sH[(e >> 6) * 68 + (e & 63)] = (f16)ldv(h, hbase + e, flag);
      if (tid < 128) sbn[tid] = (tid < 64) ? ws[WS_BN1 + tid] : ws[WS_BN2 + tid - 64];
    }
    __syncthreads();
    const int node = blk * 64 + w * 16 + l15;
    const int lrow = w * 16 + l15;
    f16x4 xB[8];
#pragma unroll
    for (int kt = 0; kt < 4; ++kt)
      xB[kt] = *(const f16x4*)&sH[lrow * 68 + kt * 16 + q * 4];
#pragma unroll
    for (int kt = 0; kt < 4; ++kt) {
      const float* ap = ws + WS_AGG + node * 64 + kt * 16 + q * 4;
      xB[4 + kt] = pack4(ap[0], ap[1], ap[2], ap[3]);
    }
    f16x4 hidB[4];
#pragma unroll
    for (int ot = 0; ot < 4; ++ot) {
      f32x4 acc;
#pragma unroll
      for (int r = 0; r < 4; ++r) acc[r] = sbn[ot * 16 + q * 4 + r];
#pragma unroll
      for (int kt = 0; kt < 8; ++kt) {
        const f16x4 a = *(const f16x4*)&sW1[(ot * 16 + l15) * 132 + kt * 16 + q * 4];
        acc = __builtin_amdgcn_mfma_f32_16x16x16f16(a, xB[kt], acc, 0, 0, 0);
      }
      hidB[ot] = pack4(fmaxf(acc[0], 0.f), fmaxf(acc[1], 0.f),
                       fmaxf(acc[2], 0.f), fmaxf(acc[3], 0.f));
    }
#pragma unroll
    for (int ft = 0; ft < 4; ++ft) {
      const f16x4 hl = *(const f16x4*)&sH[lrow * 68 + ft * 16 + q * 4];
      f32x4 acc;
#pragma unroll
      for (int r = 0; r < 4; ++r) acc[r] = sbn[64 + ft * 16 + q * 4 + r] + (float)hl[r];
#pragma unroll
      for (int ot = 0; ot < 4; ++ot) {
        const f16x4 a = *(const f16x4*)&sW2[(ft * 16 + l15) * 68 + ot * 16 + q * 4];
        acc = __builtin_amdgcn_mfma_f32_16x16x16f16(a, hidB[ot], acc, 0, 0, 0);
      }
#pragma unroll
      for (int r = 0; r < 4; ++r)
        stv(outv, node * 64 + ft * 16 + q * 4 + r, acc[r], flag);
    }
  } else if (blk < 40) {  // ---- coord pipeline, b = blk-32 ----
    const int b = blk - 32;
    const int n = tid, node = b * 256 + n;
    const int wave = n >> 6, lane = n & 63;
    __shared__ float wcv[256], wql[256], wkl[256];
    __shared__ float redm[16];
    wcv[n] = ldv(Wcv, n, flag);
    wql[n] = ldv(Wql, n, flag);
    wkl[n] = ldv(Wkl, n, flag);
    float cf[48];
    load48(coord, node, flag, cf);
    float s0 = 0.f, s1 = 0.f, s2 = 0.f;
#pragma unroll
    for (int c = 0; c < 16; ++c) { s0 += cf[c*3]; s1 += cf[c*3+1]; s2 += cf[c*3+2]; }
    for (int s = 1; s < 64; s <<= 1) {
      s0 += __shfl_xor(s0, s, 64); s1 += __shfl_xor(s1, s, 64); s2 += __shfl_xor(s2, s, 64);
    }
    if (lane == 0) { redm[wave*4] = s0; redm[wave*4+1] = s1; redm[wave*4+2] = s2; }
    __syncthreads();
    const float m0 = (redm[0]+redm[4]+redm[8]+redm[12]) * (1.f/4096.f);
    const float m1 = (redm[1]+redm[5]+redm[9]+redm[13]) * (1.f/4096.f);
    const float m2 = (redm[2]+redm[6]+redm[10]+redm[14]) * (1.f/4096.f);
    __syncthreads();
    float velf[48];
    load48(vel, node, flag, velf);
    float att[16];
    {
      const float4* ap = (const float4*)(ws + WS_ATT + node * 16);
#pragma unroll
      for (int c4 = 0; c4 < 4; ++c4) {
        const float4 v = ap[c4];
        att[c4*4] = v.x; att[c4*4+1] = v.y; att[c4*4+2] = v.z; att[c4*4+3] = v.w;
      }
    }
    float cac[48];
    {
      const float4* cp = (const float4*)(ws + WS_CAC + node * 48);
#pragma unroll
      for (int c4 = 0; c4 < 12; ++c4) {
        const float4 v = cp[c4];
        cac[c4*4] = v.x; cac[c4*4+1] = v.y; cac[c4*4+2] = v.z; cac[c4*4+3] = v.w;
      }
    }
    float c3[48];
#pragma unroll
    for (int c = 0; c < 16; ++c) {
      const float at = att[c];
#pragma unroll
      for (int d = 0; d < 3; ++d) {
        const int cd = c * 3 + d;
        const float md = (d == 0) ? m0 : ((d == 1) ? m1 : m2);
        float cc = at * (cf[cd] - md) + cf[cd];
        cc += cac[cd];
        float a = cc;
#pragma unroll
        for (int cp = 0; cp < 16; ++cp) a += velf[cp * 3 + d] * wcv[c * 16 + cp];
        c3[cd] = a;
      }
    }
    float t0 = 0.f, t1 = 0.f, t2 = 0.f;
#pragma unroll
    for (int c = 0; c < 16; ++c) { t0 += c3[c*3]; t1 += c3[c*3+1]; t2 += c3[c*3+2]; }
    for (int s = 1; s < 64; s <<= 1) {
      t0 += __shfl_xor(t0, s, 64); t1 += __shfl_xor(t1, s, 64); t2 += __shfl_xor(t2, s, 64);
    }
    if (lane == 0) { redm[wave*4] = t0; redm[wave*4+1] = t1; redm[wave*4+2] = t2; }
    __syncthreads();
    const float cm0 = (redm[0]+redm[4]+redm[8]+redm[12]) * (1.f/4096.f);
    const float cm1 = (redm[1]+redm[5]+redm[9]+redm[13]) * (1.f/4096.f);
    const float cm2 = (redm[2]+redm[6]+redm[10]+redm[14]) * (1.f/4096.f);
    float cc[48];
#pragma unroll
    for (int c = 0; c < 16; ++c) {
      cc[c*3]   = c3[c*3]   - cm0;
      cc[c*3+1] = c3[c*3+1] - cm1;
      cc[c*3+2] = c3[c*3+2] - cm2;
    }
#pragma unroll
    for (int o = 0; o < 16; ++o) {
      float qv[3], kv[3];
#pragma unroll
      for (int d = 0; d < 3; ++d) {
        float sq = 0.f, sk = 0.f;
#pragma unroll
        for (int cp = 0; cp < 16; ++cp) {
          sq += cc[cp * 3 + d] * wql[o * 16 + cp];
          sk += cc[cp * 3 + d] * wkl[o * 16 + cp];
        }
        qv[d] = sq; kv[d] = sk;
      }
      const float prod = qv[0]*kv[0] + qv[1]*kv[1] + qv[2]*kv[2];
      const float kns  = kv[0]*kv[0] + kv[1]*kv[1] + kv[2]*kv[2];
      const float wq = prod / (kns + EPSV);
#pragma unroll
      for (int d = 0; d < 3; ++d) {
        const float cmd = (d == 0) ? cm0 : ((d == 1) ? cm1 : cm2);
        const float val = (prod >= 0.f) ? qv[d] : (qv[d] - wq * kv[d]);
        stv(outv, 131072 + node * 48 + o * 3 + d, val + cmd, flag);
      }
    }
  } else {  // ---- category passthrough (overwrites scratch; no reader left) ----
    const int idx = (blk - 40) * 256 + tid;  // 131072 total
    if (flag) {
      ((uint4*)((char*)outv + 458752))[idx] = ((const uint4*)cat)[idx];
    } else {
      ((uint4*)((char*)outv + 917504))[idx] = ((const uint4*)cat)[idx];
      ((uint4*)((char*)outv + 917504))[idx + 131072] = ((const uint4*)cat)[idx + 131072];
    }
  }
}

// ---------------- launch ----------------------------------------------------
extern "C" void kernel_launch(void* const* d_in, const int* in_sizes, int n_in,
                              void* d_out, int out_size, void* d_ws, size_t ws_size,
                              hipStream_t stream) {
  (void)in_sizes; (void)n_in; (void)out_size; (void)ws_size;
  const void* h    = d_in[0];
  const void* coord= d_in[1];
  const void* vel  = d_in[2];
  const void* cat  = d_in[3];
  const void* Wcv  = d_in[4];
  const void* We1  = d_in[5];
  const void* be1  = d_in[6];
  const void* We2  = d_in[7];
  const void* be2  = d_in[8];
  const void* Wc1  = d_in[9];
  const void* bc1  = d_in[10];
  const void* Wc2  = d_in[11];
  const void* bc2  = d_in[12];
  const void* Wf1  = d_in[13];
  const void* bf1v = d_in[14];
  const void* Wf2  = d_in[15];
  const void* bf2v = d_in[16];
  const void* Wn1  = d_in[17];
  const void* bn1  = d_in[18];
  const void* Wn2  = d_in[19];
  const void* bn2  = d_in[20];
  const void* Wql  = d_in[21];
  const void* Wkl  = d_in[22];
  const void* Wqm  = d_in[23];
  const void* bqm  = d_in[24];
  float* ws = (float*)d_ws;

  k_prep_w<<<256, 256, 0, stream>>>(h, coord, We1, Wc1, We2, Wc2, Wf1, Wf2,
                                    Wn1, Wn2, Wqm, be1, bc1, bqm, be2, bc2,
                                    bf1v, bf2v, bn1, bn2, ws);
  k_gemm<<<160, 256, 0, stream>>>(h, ws, d_out);
  k_edge<<<2048, 256, 0, stream>>>(cat, ws, d_out);
  k_epi<<<552, 256, 0, stream>>>(h, coord, vel, cat, Wcv, Wql, Wkl, ws, d_out);
}